// Round 7
// baseline (2984.604 us; speedup 1.0000x reference)
//
#include <hip/hip_runtime.h>
#include <math.h>

// ---------------------------------------------------------------------------
// Legacy direct conv (global loads + full-weight LDS) — conv1 (CIN=1, 1KB
// weights) and conv4 (1x1, 8KB). Thread owns 4 positions x CCH channels.
// ---------------------------------------------------------------------------
template<int CIN, int COUT, int K, int S, int PAD, int HIN, int WIN,
         int HOUT, int WOUT, bool RELU, int CCH>
__global__ __launch_bounds__(256, 3)
void conv_fwd(const float* __restrict__ x, const float* __restrict__ w,
              const float* __restrict__ bias, float* __restrict__ out) {
  constexpr int NPOS = HOUT * WOUT;
  constexpr int PTILES = NPOS / 1024;
  constexpr int NCH = COUT / CCH;
  constexpr int RSTEP = 256 / WOUT;
  constexpr int ROWS_PER_TILE = 1024 / WOUT;
  static_assert(NPOS % 1024 == 0, "pos tiling");

  int bid = blockIdx.x;
  int cchunk = bid % NCH;
  int ptile = (bid / NCH) % PTILES;
  int n = bid / (NCH * PTILES);
  int co0 = cchunk * CCH;

  __shared__ float wl[CIN * K * K][CCH];
  for (int i = threadIdx.x; i < CIN * K * K * CCH; i += 256) {
    int cc = i % CCH;
    int tap = i / CCH;
    wl[tap][cc] = w[(size_t)(co0 + cc) * (CIN * K * K) + tap];
  }
  __syncthreads();

  int t = threadIdx.x;
  int sx = t % WOUT;
  int syb = ptile * ROWS_PER_TILE + t / WOUT;

  float acc[4][CCH];
#pragma unroll
  for (int j = 0; j < 4; j++)
#pragma unroll
    for (int c = 0; c < CCH; c++) acc[j][c] = 0.f;

  const float* xn = x + (size_t)n * CIN * HIN * WIN;
  int ix0 = sx * S - PAD;

  for (int ci = 0; ci < CIN; ci++) {
    const float* xc = xn + (size_t)ci * HIN * WIN;
#pragma unroll
    for (int ky = 0; ky < K; ky++) {
#pragma unroll
      for (int kx = 0; kx < K; kx++) {
        int ix = ix0 + kx;
        bool xok = (unsigned)ix < WIN;
        float xv[4];
#pragma unroll
        for (int j = 0; j < 4; j++) {
          int iy = (syb + j * RSTEP) * S - PAD + ky;
          bool ok = xok && ((unsigned)iy < HIN);
          xv[j] = ok ? xc[iy * WIN + ix] : 0.f;
        }
        const float* wr = &wl[ci * K * K + ky * K + kx][0];
#pragma unroll
        for (int c = 0; c < CCH; c += 4) {
          float4 wv = *(const float4*)(wr + c);
#pragma unroll
          for (int j = 0; j < 4; j++) {
            acc[j][c + 0] = fmaf(xv[j], wv.x, acc[j][c + 0]);
            acc[j][c + 1] = fmaf(xv[j], wv.y, acc[j][c + 1]);
            acc[j][c + 2] = fmaf(xv[j], wv.z, acc[j][c + 2]);
            acc[j][c + 3] = fmaf(xv[j], wv.w, acc[j][c + 3]);
          }
        }
      }
    }
  }

#pragma unroll
  for (int j = 0; j < 4; j++) {
    int sy = syb + j * RSTEP;
    float* op = out + (((size_t)n * COUT + co0) * HOUT + sy) * WOUT + sx;
#pragma unroll
    for (int c = 0; c < CCH; c++) {
      float v = acc[j][c] + bias[co0 + c];
      if (RELU) v = fmaxf(v, 0.f);
      op[(size_t)c * HOUT * WOUT] = v;
    }
  }
}

// ---------------------------------------------------------------------------
// conv2: 4x4 s=2 p=1 ReLU, 64x64 -> 32x32. Per channel-group staging of BOTH
// input (CSTG=2 ch, 32KB) and weight slice (2KB) -> LDS 34KB -> 4 blocks/CU.
// Chain order ci -> ky -> kx (bitwise-stable vs rounds 4-6).
// grid = NB * (COUT/CCH).
// ---------------------------------------------------------------------------
template<int CIN, int COUT, int CCH>
__global__ __launch_bounds__(256, 4)
void conv4x4s2_cg(const float* __restrict__ x, const float* __restrict__ w,
                  const float* __restrict__ bias, float* __restrict__ out) {
  constexpr int NCH = COUT / CCH;
  int bid = blockIdx.x;
  int cchunk = bid % NCH;
  int n = bid / NCH;
  int co0 = cchunk * CCH;

  __shared__ float xs[2 * 4096];
  __shared__ float wl[2 * 16][CCH];

  int t = threadIdx.x;
  int sx = t & 31;
  int sy0 = t >> 5;
  int ix0 = 2 * sx - 1;

  float acc[4][CCH];
#pragma unroll
  for (int j = 0; j < 4; j++)
#pragma unroll
    for (int c = 0; c < CCH; c++) acc[j][c] = 0.f;

  const float* xn = x + (size_t)n * CIN * 4096;

  for (int cg = 0; cg < CIN / 2; cg++) {
    __syncthreads();
#pragma unroll
    for (int k = 0; k < 8; k++)
      *(float4*)(xs + k * 1024 + t * 4) =
          *(const float4*)(xn + (size_t)cg * 2 * 4096 + k * 1024 + t * 4);
    for (int i = t; i < 2 * 16 * CCH; i += 256) {
      int cc = i % CCH;
      int row = i / CCH;                  // c4*16 + kk
      int c4 = row >> 4, kk = row & 15;
      wl[row][cc] = w[(size_t)(co0 + cc) * (CIN * 16) + (cg * 2 + c4) * 16 + kk];
    }
    __syncthreads();

#pragma unroll
    for (int c4 = 0; c4 < 2; c4++) {
      const float* xc = xs + c4 * 4096;
#pragma unroll
      for (int ky = 0; ky < 4; ky++) {
#pragma unroll
        for (int kx = 0; kx < 4; kx++) {
          int ix = ix0 + kx;
          bool xok = (unsigned)ix < 64;
          float xv[4];
#pragma unroll
          for (int j = 0; j < 4; j++) {
            int iy = 2 * (sy0 + j * 8) - 1 + ky;
            bool ok = xok && ((unsigned)iy < 64);
            float v = xc[ok ? iy * 64 + ix : 0];
            xv[j] = ok ? v : 0.f;
          }
          const float* wr = &wl[c4 * 16 + ky * 4 + kx][0];
#pragma unroll
          for (int c = 0; c < CCH; c += 4) {
            float4 wv = *(const float4*)(wr + c);
#pragma unroll
            for (int j = 0; j < 4; j++) {
              acc[j][c + 0] = fmaf(xv[j], wv.x, acc[j][c + 0]);
              acc[j][c + 1] = fmaf(xv[j], wv.y, acc[j][c + 1]);
              acc[j][c + 2] = fmaf(xv[j], wv.z, acc[j][c + 2]);
              acc[j][c + 3] = fmaf(xv[j], wv.w, acc[j][c + 3]);
            }
          }
        }
      }
    }
  }

#pragma unroll
  for (int j = 0; j < 4; j++) {
    int sy = sy0 + j * 8;
    float* op = out + (((size_t)n * COUT + co0) * 32 + sy) * 32 + sx;
#pragma unroll
    for (int c = 0; c < CCH; c++) {
      float v = acc[j][c] + bias[co0 + c];
      v = fmaxf(v, 0.f);
      op[(size_t)c * 1024] = v;
    }
  }
}

// ---------------------------------------------------------------------------
// conv3/dec1: 3x3 s=1 p=1 ReLU on 32x32. CSTG=4 input channels (16KB) +
// weight slice (2.25KB) per barrier round -> LDS 18.3KB -> 5 blocks/CU.
// Row-strip: thread owns rows 4rg..4rg+3 at col sx -> xv[6][3] (18 reads/ci).
// Chain order ci -> ky -> kx. grid = NB * (COUT/CCH).
// ---------------------------------------------------------------------------
template<int CIN, int COUT, int CCH>
__global__ __launch_bounds__(256, 5)
void conv3x3_cg(const float* __restrict__ x, const float* __restrict__ w,
                const float* __restrict__ bias, float* __restrict__ out) {
  constexpr int NCH = COUT / CCH;
  int bid = blockIdx.x;
  int cchunk = bid % NCH;
  int n = bid / NCH;
  int co0 = cchunk * CCH;

  __shared__ float xs[4 * 1024];
  __shared__ float wl[4 * 9][CCH];

  int t = threadIdx.x;
  int sx = t & 31;
  int rg = t >> 5;

  float acc[4][CCH];
#pragma unroll
  for (int j = 0; j < 4; j++)
#pragma unroll
    for (int c = 0; c < CCH; c++) acc[j][c] = 0.f;

  const float* xn = x + (size_t)n * CIN * 1024;

  for (int cg = 0; cg < CIN / 4; cg++) {
    __syncthreads();
#pragma unroll
    for (int k = 0; k < 4; k++)
      *(float4*)(xs + k * 1024 + t * 4) =
          *(const float4*)(xn + (size_t)(cg * 4 + k) * 1024 + t * 4);
    for (int i = t; i < 4 * 9 * CCH; i += 256) {
      int cc = i % CCH;
      int row = i / CCH;                  // c4*9 + kk
      int c4 = row / 9, kk = row % 9;
      wl[row][cc] = w[(size_t)(co0 + cc) * (CIN * 9) + (cg * 4 + c4) * 9 + kk];
    }
    __syncthreads();

#pragma unroll
    for (int c4 = 0; c4 < 4; c4++) {
      const float* xc = xs + c4 * 1024;
      float xv[6][3];
#pragma unroll
      for (int r = 0; r < 6; r++) {
        int iy = 4 * rg - 1 + r;
        bool yok = (unsigned)iy < 32;
#pragma unroll
        for (int cx = 0; cx < 3; cx++) {
          int ix = sx - 1 + cx;
          bool ok = yok && ((unsigned)ix < 32);
          float v = xc[ok ? iy * 32 + ix : 0];
          xv[r][cx] = ok ? v : 0.f;
        }
      }
#pragma unroll
      for (int ky = 0; ky < 3; ky++) {
#pragma unroll
        for (int kx = 0; kx < 3; kx++) {
          const float* wr = &wl[c4 * 9 + ky * 3 + kx][0];
#pragma unroll
          for (int c = 0; c < CCH; c += 4) {
            float4 wv = *(const float4*)(wr + c);
#pragma unroll
            for (int j = 0; j < 4; j++) {
              float xx = xv[j + ky][kx];
              acc[j][c + 0] = fmaf(xx, wv.x, acc[j][c + 0]);
              acc[j][c + 1] = fmaf(xx, wv.y, acc[j][c + 1]);
              acc[j][c + 2] = fmaf(xx, wv.z, acc[j][c + 2]);
              acc[j][c + 3] = fmaf(xx, wv.w, acc[j][c + 3]);
            }
          }
        }
      }
    }
  }

#pragma unroll
  for (int j = 0; j < 4; j++) {
    int sy = 4 * rg + j;
    float* op = out + (((size_t)n * COUT + co0) * 32 + sy) * 32 + sx;
#pragma unroll
    for (int c = 0; c < CCH; c++) {
      float v = acc[j][c] + bias[co0 + c];
      v = fmaxf(v, 0.f);
      op[(size_t)c * 1024] = v;
    }
  }
}

// ---------------------------------------------------------------------------
// dect1: transposed conv k=4 s=2 p=1 ReLU, parity-decomposed. CSTG=4 input
// channels (16KB) + live 4-tap weight slice (1KB) -> LDS 17KB -> 5 blocks/CU.
// Row-strip xv[5][2] (10 reads/ci). Chain order ci -> kyi -> kxi.
// grid = NB * 4 * (COUT/CCH). in 32x32, out 64x64. w torch [Cin,Cout,4,4].
// ---------------------------------------------------------------------------
template<int CIN, int COUT, int CCH>
__global__ __launch_bounds__(256, 5)
void convt_cg(const float* __restrict__ x, const float* __restrict__ w,
              const float* __restrict__ bias, float* __restrict__ out) {
  constexpr int NCH = COUT / CCH;
  int bid = blockIdx.x;
  int cchunk = bid % NCH;
  int par = (bid / NCH) & 3;
  int n = bid / (NCH * 4);
  int py = par >> 1, px = par & 1;
  int co0 = cchunk * CCH;
  int ky0 = (py + 1) & 1, kx0 = (px + 1) & 1;
  int ay = (py + 1 - ky0) >> 1;
  int ax = (px + 1 - kx0) >> 1;

  __shared__ float xs[4 * 1024];
  __shared__ float wl[4 * 4][CCH];

  int t = threadIdx.x;
  int sx = t & 31;
  int rg = t >> 5;

  float acc[4][CCH];
#pragma unroll
  for (int j = 0; j < 4; j++)
#pragma unroll
    for (int c = 0; c < CCH; c++) acc[j][c] = 0.f;

  const float* xn = x + (size_t)n * CIN * 1024;

  for (int cg = 0; cg < CIN / 4; cg++) {
    __syncthreads();
#pragma unroll
    for (int k = 0; k < 4; k++)
      *(float4*)(xs + k * 1024 + t * 4) =
          *(const float4*)(xn + (size_t)(cg * 4 + k) * 1024 + t * 4);
    for (int i = t; i < 4 * 4 * CCH; i += 256) {
      int cc = i % CCH;
      int row = i / CCH;                  // c4*4 + kyi*2 + kxi
      int c4 = row >> 2;
      int kyi = (row >> 1) & 1, kxi = row & 1;
      int ky = ky0 + 2 * kyi, kx = kx0 + 2 * kxi;
      wl[row][cc] =
          w[((size_t)(cg * 4 + c4) * COUT + (co0 + cc)) * 16 + ky * 4 + kx];
    }
    __syncthreads();

#pragma unroll
    for (int c4 = 0; c4 < 4; c4++) {
      const float* xc = xs + c4 * 1024;
      float xv[5][2];
#pragma unroll
      for (int r = 0; r < 5; r++) {
        int iy = 4 * rg + ay - 1 + r;
        bool yok = (unsigned)iy < 32;
#pragma unroll
        for (int cx = 0; cx < 2; cx++) {
          int ix = sx + ax - 1 + cx;
          bool ok = yok && ((unsigned)ix < 32);
          float v = xc[ok ? iy * 32 + ix : 0];
          xv[r][cx] = ok ? v : 0.f;
        }
      }
#pragma unroll
      for (int kyi = 0; kyi < 2; kyi++) {
#pragma unroll
        for (int kxi = 0; kxi < 2; kxi++) {
          const float* wr = &wl[c4 * 4 + kyi * 2 + kxi][0];
#pragma unroll
          for (int c = 0; c < CCH; c += 4) {
            float4 wv = *(const float4*)(wr + c);
#pragma unroll
            for (int j = 0; j < 4; j++) {
              float xx = xv[j + 1 - kyi][1 - kxi];
              acc[j][c + 0] = fmaf(xx, wv.x, acc[j][c + 0]);
              acc[j][c + 1] = fmaf(xx, wv.y, acc[j][c + 1]);
              acc[j][c + 2] = fmaf(xx, wv.z, acc[j][c + 2]);
              acc[j][c + 3] = fmaf(xx, wv.w, acc[j][c + 3]);
            }
          }
        }
      }
    }
  }

#pragma unroll
  for (int j = 0; j < 4; j++) {
    int sy = 4 * rg + j;
    int oy = 2 * sy + py;
    int ox = 2 * sx + px;
    float* op = out + (((size_t)n * COUT + co0) * 64 + oy) * 64 + ox;
#pragma unroll
    for (int c = 0; c < CCH; c++) {
      float v = acc[j][c] + bias[co0 + c];
      v = fmaxf(v, 0.f);
      op[(size_t)c * 4096] = v;
    }
  }
}

// ---------------------------------------------------------------------------
// dect2: transposed conv k=4 s=2 p=1, CIN=32, COUT=1, sigmoid; all 4
// parities per thread (input read once). in 64x64 -> out 128x128.
// (Round-6 verified bitwise-stable.) grid = NB * 4 row-tiles.
// ---------------------------------------------------------------------------
__global__ __launch_bounds__(256, 5)
void dect2_full(const float* __restrict__ x, const float* __restrict__ w,
                const float* __restrict__ bias, float* __restrict__ out) {
  int ptile = blockIdx.x & 3;
  int n = blockIdx.x >> 2;
  int y0 = ptile * 16;

  __shared__ float xs[4][1152];      // rows y0-1..y0+16 (18) x 64 cols
  int t = threadIdx.x;
  int sx = t & 63;
  int r4 = t >> 6;

  float acc[4][4];
#pragma unroll
  for (int j = 0; j < 4; j++)
#pragma unroll
    for (int p = 0; p < 4; p++) acc[j][p] = 0.f;

  const float* xn = x + (size_t)n * 32 * 4096;

  for (int cg = 0; cg < 8; cg++) {
    __syncthreads();
    for (int idx = t; idx < 4 * 1152; idx += 256) {
      int ch = idx / 1152;
      int rem = idx % 1152;
      int iy = y0 - 1 + rem / 64;
      int ix = rem & 63;
      bool ok = (unsigned)iy < 64;
      xs[ch][rem] = ok ? xn[(size_t)(cg * 4 + ch) * 4096 + iy * 64 + ix] : 0.f;
    }
    __syncthreads();

#pragma unroll
    for (int c4 = 0; c4 < 4; c4++) {
      int ci = cg * 4 + c4;
      const float* xc = &xs[c4][0];
      float xv[6][3];
#pragma unroll
      for (int r = 0; r < 6; r++) {
        int srow = 4 * r4 + r;
#pragma unroll
        for (int cx = 0; cx < 3; cx++) {
          int ix = sx - 1 + cx;
          bool ok = (unsigned)ix < 64;
          float v = xc[ok ? srow * 64 + ix : 0];
          xv[r][cx] = ok ? v : 0.f;
        }
      }
      float w16[16];
#pragma unroll
      for (int q = 0; q < 4; q++) {
        float4 ww = *(const float4*)(w + ci * 16 + 4 * q);
        w16[4 * q + 0] = ww.x; w16[4 * q + 1] = ww.y;
        w16[4 * q + 2] = ww.z; w16[4 * q + 3] = ww.w;
      }
#pragma unroll
      for (int py = 0; py < 2; py++) {
#pragma unroll
        for (int px = 0; px < 2; px++) {
          int par = py * 2 + px;
          int ky0 = (py + 1) & 1, kx0 = (px + 1) & 1;
          int ay = (py + 1 - ky0) >> 1;
          int ax = (px + 1 - kx0) >> 1;
#pragma unroll
          for (int kyi = 0; kyi < 2; kyi++) {
#pragma unroll
            for (int kxi = 0; kxi < 2; kxi++) {
              float wv = w16[(ky0 + 2 * kyi) * 4 + (kx0 + 2 * kxi)];
#pragma unroll
              for (int j = 0; j < 4; j++) {
                float xx = xv[j + ay + 1 - kyi][ax + 1 - kxi];
                acc[j][par] = fmaf(xx, wv, acc[j][par]);
              }
            }
          }
        }
      }
    }
  }

  float b0 = bias[0];
#pragma unroll
  for (int j = 0; j < 4; j++) {
    int iy = y0 + 4 * r4 + j;
#pragma unroll
    for (int py = 0; py < 2; py++) {
      float v0 = acc[j][py * 2 + 0] + b0;
      float v1 = acc[j][py * 2 + 1] + b0;
      float2 o;
      o.x = 1.f / (1.f + expf(-v0));
      o.y = 1.f / (1.f + expf(-v1));
      int oy = 2 * iy + py;
      *(float2*)(out + (size_t)n * 16384 + oy * 128 + 2 * sx) = o;
    }
  }
}

// ---------------------------------------------------------------------------
__global__ void cbn_prep(const float* __restrict__ cb, float* __restrict__ cbn) {
#pragma clang fp contract(off)
  int k = blockIdx.x * 256 + threadIdx.x;
  if (k < 512) {
    float m[32];
#pragma unroll
    for (int d = 0; d < 32; d++) {
      float c = cb[k * 32 + d];
      m[d] = c * c;
    }
    float r[8];
#pragma unroll
    for (int j = 0; j < 8; j++)
      r[j] = ((m[j] + m[8 + j]) + m[16 + j]) + m[24 + j];
    cbn[k] = ((r[0] + r[1]) + (r[2] + r[3])) + ((r[4] + r[5]) + (r[6] + r[7]));
  }
}

// ---------------------------------------------------------------------------
// VQ: np-exact arithmetic, 1 px/thread, wave-uniform codebook loads.
// (Round-6 verified: zero argmin flips.)
// ---------------------------------------------------------------------------
__global__ __launch_bounds__(256)
void vq_kernel(const float* __restrict__ z, const float* __restrict__ cb,
               const float* __restrict__ cbn, float* __restrict__ qz,
               float* __restrict__ loss) {
  int tid = threadIdx.x;
  int n = blockIdx.x >> 2;
  int p = (blockIdx.x & 3) * 256 + tid;
  const float* zn = z + (size_t)n * 32768;

  float zv[32];
#pragma unroll
  for (int d = 0; d < 32; d++) zv[d] = zn[(size_t)d * 1024 + p];

  float zz;
  {
#pragma clang fp contract(off)
    float m[32];
#pragma unroll
    for (int d = 0; d < 32; d++) m[d] = zv[d] * zv[d];
    float r[8];
#pragma unroll
    for (int j = 0; j < 8; j++)
      r[j] = ((m[j] + m[8 + j]) + m[16 + j]) + m[24 + j];
    zz = ((r[0] + r[1]) + (r[2] + r[3])) + ((r[4] + r[5]) + (r[6] + r[7]));
  }

  float best = 3.4e38f;
  int bk = 0;
  for (int k4 = 0; k4 < 512; k4 += 4) {
    float4 cn = *(const float4*)(cbn + k4);
    float da[4];
#pragma unroll
    for (int u = 0; u < 4; u++) da[u] = 0.f;
#pragma unroll
    for (int d = 0; d < 32; d += 4) {
#pragma unroll
      for (int u = 0; u < 4; u++) {
        float4 c = *(const float4*)(cb + (size_t)(k4 + u) * 32 + d);
        float a = da[u];
        a = fmaf(zv[d + 0], c.x, a);
        a = fmaf(zv[d + 1], c.y, a);
        a = fmaf(zv[d + 2], c.z, a);
        a = fmaf(zv[d + 3], c.w, a);
        da[u] = a;
      }
    }
#pragma unroll
    for (int u = 0; u < 4; u++) {
      float cnu = (u == 0) ? cn.x : (u == 1) ? cn.y : (u == 2) ? cn.z : cn.w;
      float s;
      {
#pragma clang fp contract(off)
        s = (zz + cnu) - 2.f * da[u];
      }
      int k = k4 + u;
      if (s < best) { best = s; bk = k; }
    }
  }

  float lsum = 0.f;
  float* qn = qz + (size_t)n * 32768;
#pragma unroll
  for (int d = 0; d < 32; d += 4) {
#pragma clang fp contract(off)
    float4 q = *(const float4*)(cb + (size_t)bk * 32 + d);
    float e;
    e = q.x - zv[d + 0]; lsum = fmaf(e, e, lsum);
    e = q.y - zv[d + 1]; lsum = fmaf(e, e, lsum);
    e = q.z - zv[d + 2]; lsum = fmaf(e, e, lsum);
    e = q.w - zv[d + 3]; lsum = fmaf(e, e, lsum);
    qn[(size_t)(d + 0) * 1024 + p] = zv[d + 0] + (q.x - zv[d + 0]);
    qn[(size_t)(d + 1) * 1024 + p] = zv[d + 1] + (q.y - zv[d + 1]);
    qn[(size_t)(d + 2) * 1024 + p] = zv[d + 2] + (q.z - zv[d + 2]);
    qn[(size_t)(d + 3) * 1024 + p] = zv[d + 3] + (q.w - zv[d + 3]);
  }

#pragma unroll
  for (int off = 32; off; off >>= 1) lsum += __shfl_down(lsum, off, 64);
  if ((tid & 63) == 0) atomicAdd(loss, lsum);
}

__global__ void finalize_loss(const float* __restrict__ loss, float* __restrict__ out) {
  if (threadIdx.x == 0) {
    float m = loss[0] / 8388608.f;
    out[0] = m + 0.26f * m;
  }
}

// ---------------------------------------------------------------------------
// Workspace (floats): A = chunk*131072, B = chunk*65536, cbn 512, loss 1.
// Full batch = 201.3 MB; chunk count from ws_size (constant -> graph-safe).
// ---------------------------------------------------------------------------
extern "C" void kernel_launch(void* const* d_in, const int* in_sizes, int n_in,
                              void* d_out, int out_size, void* d_ws, size_t ws_size,
                              hipStream_t stream) {
  (void)in_sizes; (void)n_in; (void)out_size;
  const float* x   = (const float*)d_in[0];
  const float* ew1 = (const float*)d_in[1];
  const float* eb1 = (const float*)d_in[2];
  const float* ew2 = (const float*)d_in[3];
  const float* eb2 = (const float*)d_in[4];
  const float* ew3 = (const float*)d_in[5];
  const float* eb3 = (const float*)d_in[6];
  const float* ew4 = (const float*)d_in[7];
  const float* eb4 = (const float*)d_in[8];
  const float* cb  = (const float*)d_in[9];
  const float* dw1 = (const float*)d_in[10];
  const float* db1 = (const float*)d_in[11];
  const float* tw1 = (const float*)d_in[12];
  const float* tb1 = (const float*)d_in[13];
  const float* tw2 = (const float*)d_in[14];
  const float* tb2 = (const float*)d_in[15];
  float* out = (float*)d_out;

  auto need = [](size_t c) -> size_t { return (c * 196608 + 513) * 4; };
  int nchunks = 4;
  if (ws_size >= need(256)) nchunks = 1;
  else if (ws_size >= need(128)) nchunks = 2;
  int chunk = 256 / nchunks;

  float* ws = (float*)d_ws;
  float* A = ws;
  float* B = A + (size_t)chunk * 131072;
  float* cbn = B + (size_t)chunk * 65536;
  float* lossacc = cbn + 512;

  float* h1 = A;
  float* h2 = B;
  float* h3 = A;
  float* z  = A + (size_t)chunk * 65536;
  float* qz = A + (size_t)chunk * 98304;
  float* d1 = B;
  float* d2 = A;

  cbn_prep<<<2, 256, 0, stream>>>(cb, cbn);
  (void)hipMemsetAsync(lossacc, 0, 4, stream);

  for (int c = 0; c < nchunks; c++) {
    const float* xc = x + (size_t)c * chunk * 128 * 128;
    float* outc = out + (size_t)c * chunk * 128 * 128;

    conv_fwd<1, 32, 4, 2, 1, 128, 128, 64, 64, true, 16>
        <<<chunk * 4 * 2, 256, 0, stream>>>(xc, ew1, eb1, h1);
    conv4x4s2_cg<32, 64, 16>
        <<<chunk * 4, 256, 0, stream>>>(h1, ew2, eb2, h2);
    conv3x3_cg<64, 64, 16>
        <<<chunk * 4, 256, 0, stream>>>(h2, ew3, eb3, h3);
    conv_fwd<64, 32, 1, 1, 0, 32, 32, 32, 32, false, 16>
        <<<chunk * 2, 256, 0, stream>>>(h3, ew4, eb4, z);

    vq_kernel<<<chunk * 4, 256, 0, stream>>>(z, cb, cbn, qz, lossacc);

    conv3x3_cg<32, 64, 16>
        <<<chunk * 4, 256, 0, stream>>>(qz, dw1, db1, d1);
    convt_cg<64, 32, 16>
        <<<chunk * 4 * 2, 256, 0, stream>>>(d1, tw1, tb1, d2);
    dect2_full<<<chunk * 4, 256, 0, stream>>>(d2, tw2, tb2, outc);
  }

  finalize_loss<<<1, 64, 0, stream>>>(lossacc, out + 4194304);
}

// Round 8
// 2027.329 us; speedup vs baseline: 1.4722x; 1.4722x over previous
//
#include <hip/hip_runtime.h>
#include <math.h>

// ---------------------------------------------------------------------------
// Legacy direct conv (global loads + full-weight LDS) — conv1 (CIN=1, 1KB
// weights) and conv4 (1x1, 8KB). Thread owns 4 positions x CCH channels.
// ---------------------------------------------------------------------------
template<int CIN, int COUT, int K, int S, int PAD, int HIN, int WIN,
         int HOUT, int WOUT, bool RELU, int CCH>
__global__ __launch_bounds__(256, 3)
void conv_fwd(const float* __restrict__ x, const float* __restrict__ w,
              const float* __restrict__ bias, float* __restrict__ out) {
  constexpr int NPOS = HOUT * WOUT;
  constexpr int PTILES = NPOS / 1024;
  constexpr int NCH = COUT / CCH;
  constexpr int RSTEP = 256 / WOUT;
  constexpr int ROWS_PER_TILE = 1024 / WOUT;
  static_assert(NPOS % 1024 == 0, "pos tiling");

  int bid = blockIdx.x;
  int cchunk = bid % NCH;
  int ptile = (bid / NCH) % PTILES;
  int n = bid / (NCH * PTILES);
  int co0 = cchunk * CCH;

  __shared__ float wl[CIN * K * K][CCH];
  for (int i = threadIdx.x; i < CIN * K * K * CCH; i += 256) {
    int cc = i % CCH;
    int tap = i / CCH;
    wl[tap][cc] = w[(size_t)(co0 + cc) * (CIN * K * K) + tap];
  }
  __syncthreads();

  int t = threadIdx.x;
  int sx = t % WOUT;
  int syb = ptile * ROWS_PER_TILE + t / WOUT;

  float acc[4][CCH];
#pragma unroll
  for (int j = 0; j < 4; j++)
#pragma unroll
    for (int c = 0; c < CCH; c++) acc[j][c] = 0.f;

  const float* xn = x + (size_t)n * CIN * HIN * WIN;
  int ix0 = sx * S - PAD;

  for (int ci = 0; ci < CIN; ci++) {
    const float* xc = xn + (size_t)ci * HIN * WIN;
#pragma unroll
    for (int ky = 0; ky < K; ky++) {
#pragma unroll
      for (int kx = 0; kx < K; kx++) {
        int ix = ix0 + kx;
        bool xok = (unsigned)ix < WIN;
        float xv[4];
#pragma unroll
        for (int j = 0; j < 4; j++) {
          int iy = (syb + j * RSTEP) * S - PAD + ky;
          bool ok = xok && ((unsigned)iy < HIN);
          xv[j] = ok ? xc[iy * WIN + ix] : 0.f;
        }
        const float* wr = &wl[ci * K * K + ky * K + kx][0];
#pragma unroll
        for (int c = 0; c < CCH; c += 4) {
          float4 wv = *(const float4*)(wr + c);
#pragma unroll
          for (int j = 0; j < 4; j++) {
            acc[j][c + 0] = fmaf(xv[j], wv.x, acc[j][c + 0]);
            acc[j][c + 1] = fmaf(xv[j], wv.y, acc[j][c + 1]);
            acc[j][c + 2] = fmaf(xv[j], wv.z, acc[j][c + 2]);
            acc[j][c + 3] = fmaf(xv[j], wv.w, acc[j][c + 3]);
          }
        }
      }
    }
  }

#pragma unroll
  for (int j = 0; j < 4; j++) {
    int sy = syb + j * RSTEP;
    float* op = out + (((size_t)n * COUT + co0) * HOUT + sy) * WOUT + sx;
#pragma unroll
    for (int c = 0; c < CCH; c++) {
      float v = acc[j][c] + bias[co0 + c];
      if (RELU) v = fmaxf(v, 0.f);
      op[(size_t)c * HOUT * WOUT] = v;
    }
  }
}

// ---------------------------------------------------------------------------
// conv2: 4x4 s=2 p=1 ReLU, 64x64 -> 32x32. Per channel-group staging of
// input (2 ch, 32KB) + weight slice (2KB) -> 34KB LDS -> 4 blocks/CU.
// ---------------------------------------------------------------------------
template<int CIN, int COUT, int CCH>
__global__ __launch_bounds__(256, 4)
void conv4x4s2_cg(const float* __restrict__ x, const float* __restrict__ w,
                  const float* __restrict__ bias, float* __restrict__ out) {
  constexpr int NCH = COUT / CCH;
  int bid = blockIdx.x;
  int cchunk = bid % NCH;
  int n = bid / NCH;
  int co0 = cchunk * CCH;

  __shared__ float xs[2 * 4096];
  __shared__ float wl[2 * 16][CCH];

  int t = threadIdx.x;
  int sx = t & 31;
  int sy0 = t >> 5;
  int ix0 = 2 * sx - 1;

  float acc[4][CCH];
#pragma unroll
  for (int j = 0; j < 4; j++)
#pragma unroll
    for (int c = 0; c < CCH; c++) acc[j][c] = 0.f;

  const float* xn = x + (size_t)n * CIN * 4096;

  for (int cg = 0; cg < CIN / 2; cg++) {
    __syncthreads();
#pragma unroll
    for (int k = 0; k < 8; k++)
      *(float4*)(xs + k * 1024 + t * 4) =
          *(const float4*)(xn + (size_t)cg * 2 * 4096 + k * 1024 + t * 4);
    for (int i = t; i < 2 * 16 * CCH; i += 256) {
      int cc = i % CCH;
      int row = i / CCH;
      int c4 = row >> 4, kk = row & 15;
      wl[row][cc] = w[(size_t)(co0 + cc) * (CIN * 16) + (cg * 2 + c4) * 16 + kk];
    }
    __syncthreads();

#pragma unroll
    for (int c4 = 0; c4 < 2; c4++) {
      const float* xc = xs + c4 * 4096;
#pragma unroll
      for (int ky = 0; ky < 4; ky++) {
#pragma unroll
        for (int kx = 0; kx < 4; kx++) {
          int ix = ix0 + kx;
          bool xok = (unsigned)ix < 64;
          float xv[4];
#pragma unroll
          for (int j = 0; j < 4; j++) {
            int iy = 2 * (sy0 + j * 8) - 1 + ky;
            bool ok = xok && ((unsigned)iy < 64);
            float v = xc[ok ? iy * 64 + ix : 0];
            xv[j] = ok ? v : 0.f;
          }
          const float* wr = &wl[c4 * 16 + ky * 4 + kx][0];
#pragma unroll
          for (int c = 0; c < CCH; c += 4) {
            float4 wv = *(const float4*)(wr + c);
#pragma unroll
            for (int j = 0; j < 4; j++) {
              acc[j][c + 0] = fmaf(xv[j], wv.x, acc[j][c + 0]);
              acc[j][c + 1] = fmaf(xv[j], wv.y, acc[j][c + 1]);
              acc[j][c + 2] = fmaf(xv[j], wv.z, acc[j][c + 2]);
              acc[j][c + 3] = fmaf(xv[j], wv.w, acc[j][c + 3]);
            }
          }
        }
      }
    }
  }

#pragma unroll
  for (int j = 0; j < 4; j++) {
    int sy = sy0 + j * 8;
    float* op = out + (((size_t)n * COUT + co0) * 32 + sy) * 32 + sx;
#pragma unroll
    for (int c = 0; c < CCH; c++) {
      float v = acc[j][c] + bias[co0 + c];
      v = fmaxf(v, 0.f);
      op[(size_t)c * 1024] = v;
    }
  }
}

// ---------------------------------------------------------------------------
// conv3/dec1: 3x3 s=1 p=1 ReLU on 32x32. 4 input channels (16KB) + weight
// slice (2.25KB) per barrier round. (256,4): VGPR cap 128 — NO spill (the
// round-7 (256,5) cap of ~102 spilled the 64-float acc; VGPR_Count 48).
// ---------------------------------------------------------------------------
template<int CIN, int COUT, int CCH>
__global__ __launch_bounds__(256, 4)
void conv3x3_cg(const float* __restrict__ x, const float* __restrict__ w,
                const float* __restrict__ bias, float* __restrict__ out) {
  constexpr int NCH = COUT / CCH;
  int bid = blockIdx.x;
  int cchunk = bid % NCH;
  int n = bid / NCH;
  int co0 = cchunk * CCH;

  __shared__ float xs[4 * 1024];
  __shared__ float wl[4 * 9][CCH];

  int t = threadIdx.x;
  int sx = t & 31;
  int rg = t >> 5;

  float acc[4][CCH];
#pragma unroll
  for (int j = 0; j < 4; j++)
#pragma unroll
    for (int c = 0; c < CCH; c++) acc[j][c] = 0.f;

  const float* xn = x + (size_t)n * CIN * 1024;

  for (int cg = 0; cg < CIN / 4; cg++) {
    __syncthreads();
#pragma unroll
    for (int k = 0; k < 4; k++)
      *(float4*)(xs + k * 1024 + t * 4) =
          *(const float4*)(xn + (size_t)(cg * 4 + k) * 1024 + t * 4);
    for (int i = t; i < 4 * 9 * CCH; i += 256) {
      int cc = i % CCH;
      int row = i / CCH;
      int c4 = row / 9, kk = row % 9;
      wl[row][cc] = w[(size_t)(co0 + cc) * (CIN * 9) + (cg * 4 + c4) * 9 + kk];
    }
    __syncthreads();

#pragma unroll
    for (int c4 = 0; c4 < 4; c4++) {
      const float* xc = xs + c4 * 1024;
      float xv[6][3];
#pragma unroll
      for (int r = 0; r < 6; r++) {
        int iy = 4 * rg - 1 + r;
        bool yok = (unsigned)iy < 32;
#pragma unroll
        for (int cx = 0; cx < 3; cx++) {
          int ix = sx - 1 + cx;
          bool ok = yok && ((unsigned)ix < 32);
          float v = xc[ok ? iy * 32 + ix : 0];
          xv[r][cx] = ok ? v : 0.f;
        }
      }
#pragma unroll
      for (int ky = 0; ky < 3; ky++) {
#pragma unroll
        for (int kx = 0; kx < 3; kx++) {
          const float* wr = &wl[c4 * 9 + ky * 3 + kx][0];
#pragma unroll
          for (int c = 0; c < CCH; c += 4) {
            float4 wv = *(const float4*)(wr + c);
#pragma unroll
            for (int j = 0; j < 4; j++) {
              float xx = xv[j + ky][kx];
              acc[j][c + 0] = fmaf(xx, wv.x, acc[j][c + 0]);
              acc[j][c + 1] = fmaf(xx, wv.y, acc[j][c + 1]);
              acc[j][c + 2] = fmaf(xx, wv.z, acc[j][c + 2]);
              acc[j][c + 3] = fmaf(xx, wv.w, acc[j][c + 3]);
            }
          }
        }
      }
    }
  }

#pragma unroll
  for (int j = 0; j < 4; j++) {
    int sy = 4 * rg + j;
    float* op = out + (((size_t)n * COUT + co0) * 32 + sy) * 32 + sx;
#pragma unroll
    for (int c = 0; c < CCH; c++) {
      float v = acc[j][c] + bias[co0 + c];
      v = fmaxf(v, 0.f);
      op[(size_t)c * 1024] = v;
    }
  }
}

// ---------------------------------------------------------------------------
// dect1 QUAD: tconv k=4 s=2 p=1 ReLU, in [n,64,32,32] -> out [n,32,64,64].
// Thread owns ONE input position (sy,sx) and computes its full 2x2 output
// quad (all 4 parities) for CCH=16 channels -> float2 stores, lanes cover 64
// consecutive floats per row: fully coalesced, no RMW. (Round-7's per-parity
// scatter + spill moved 1.44 GB for a 201 MB layer.)
// Block = sample x 8-row tile x co-chunk. grid = NB * 4 * (COUT/CCH).
// ---------------------------------------------------------------------------
template<int CIN, int COUT, int CCH>
__global__ __launch_bounds__(256, 4)
void convt_quad(const float* __restrict__ x, const float* __restrict__ w,
                const float* __restrict__ bias, float* __restrict__ out) {
  constexpr int NCH = COUT / CCH;
  int bid = blockIdx.x;
  int cchunk = bid % NCH;
  int tile = (bid / NCH) & 3;
  int n = bid / (NCH * 4);
  int co0 = cchunk * CCH;
  int sy0 = tile * 8;

  __shared__ float xs[4][320];        // 10 rows (sy0-1..sy0+8) x 32 cols
  __shared__ float wl[4 * 16][CCH];   // [c4][kk][co]

  int t = threadIdx.x;
  int sx = t & 31;
  int syl = t >> 5;                   // 0..7
  int sy = sy0 + syl;

  float acc[2][2][CCH];
#pragma unroll
  for (int py = 0; py < 2; py++)
#pragma unroll
    for (int px = 0; px < 2; px++)
#pragma unroll
      for (int c = 0; c < CCH; c++) acc[py][px][c] = 0.f;

  const float* xn = x + (size_t)n * CIN * 1024;

  for (int cg = 0; cg < CIN / 4; cg++) {
    __syncthreads();
    for (int idx = t; idx < 4 * 320; idx += 256) {
      int ch = idx / 320;
      int rem = idx % 320;
      int gy = sy0 - 1 + rem / 32;
      int col = rem & 31;
      bool ok = (unsigned)gy < 32;
      xs[ch][rem] = ok ? xn[(size_t)(cg * 4 + ch) * 1024 + gy * 32 + col] : 0.f;
    }
    for (int idx = t; idx < 4 * 16 * CCH; idx += 256) {
      int c = idx % CCH;
      int row = idx / CCH;            // c4*16 + kk
      int c4 = row >> 4, kk = row & 15;
      wl[row][c] = w[((size_t)(cg * 4 + c4) * COUT + (co0 + c)) * 16 + kk];
    }
    __syncthreads();

#pragma unroll
    for (int c4 = 0; c4 < 4; c4++) {
      // xv[r][cx] = x[sy-1+r][sx-1+cx]; rows pre-guarded at staging.
      float xv[3][3];
#pragma unroll
      for (int r = 0; r < 3; r++) {
#pragma unroll
        for (int cx = 0; cx < 3; cx++) {
          int ix = sx - 1 + cx;
          bool ok = (unsigned)ix < 32;
          float v = xs[c4][(syl + r) * 32 + (ok ? ix : 0)];
          xv[r][cx] = ok ? v : 0.f;
        }
      }
#pragma unroll
      for (int py = 0; py < 2; py++) {
        int ky0 = (py + 1) & 1;
        int ay = (py + 1 - ky0) >> 1;
#pragma unroll
        for (int px = 0; px < 2; px++) {
          int kx0 = (px + 1) & 1;
          int ax = (px + 1 - kx0) >> 1;
#pragma unroll
          for (int kyi = 0; kyi < 2; kyi++) {
#pragma unroll
            for (int kxi = 0; kxi < 2; kxi++) {
              int kk = (ky0 + 2 * kyi) * 4 + (kx0 + 2 * kxi);
              float xx = xv[ay - kyi + 1][ax - kxi + 1];
              const float* wr = &wl[c4 * 16 + kk][0];
#pragma unroll
              for (int c = 0; c < CCH; c += 4) {
                float4 wv = *(const float4*)(wr + c);
                acc[py][px][c + 0] = fmaf(xx, wv.x, acc[py][px][c + 0]);
                acc[py][px][c + 1] = fmaf(xx, wv.y, acc[py][px][c + 1]);
                acc[py][px][c + 2] = fmaf(xx, wv.z, acc[py][px][c + 2]);
                acc[py][px][c + 3] = fmaf(xx, wv.w, acc[py][px][c + 3]);
              }
            }
          }
        }
      }
    }
  }

#pragma unroll
  for (int py = 0; py < 2; py++) {
    int oy = 2 * sy + py;
#pragma unroll
    for (int c = 0; c < CCH; c++) {
      float b = bias[co0 + c];
      float2 o;
      o.x = fmaxf(acc[py][0][c] + b, 0.f);
      o.y = fmaxf(acc[py][1][c] + b, 0.f);
      *(float2*)(out + ((size_t)(n * COUT + co0 + c) * 64 + oy) * 64 + 2 * sx) = o;
    }
  }
}

// ---------------------------------------------------------------------------
// dect2: tconv k=4 s=2 p=1, CIN=32, COUT=1, sigmoid; all 4 parities per
// thread. in 64x64 -> out 128x128. grid = NB * 4 row-tiles.
// ---------------------------------------------------------------------------
__global__ __launch_bounds__(256, 4)
void dect2_full(const float* __restrict__ x, const float* __restrict__ w,
                const float* __restrict__ bias, float* __restrict__ out) {
  int ptile = blockIdx.x & 3;
  int n = blockIdx.x >> 2;
  int y0 = ptile * 16;

  __shared__ float xs[4][1152];      // rows y0-1..y0+16 (18) x 64 cols
  int t = threadIdx.x;
  int sx = t & 63;
  int r4 = t >> 6;

  float acc[4][4];
#pragma unroll
  for (int j = 0; j < 4; j++)
#pragma unroll
    for (int p = 0; p < 4; p++) acc[j][p] = 0.f;

  const float* xn = x + (size_t)n * 32 * 4096;

  for (int cg = 0; cg < 8; cg++) {
    __syncthreads();
    for (int idx = t; idx < 4 * 1152; idx += 256) {
      int ch = idx / 1152;
      int rem = idx % 1152;
      int iy = y0 - 1 + rem / 64;
      int ix = rem & 63;
      bool ok = (unsigned)iy < 64;
      xs[ch][rem] = ok ? xn[(size_t)(cg * 4 + ch) * 4096 + iy * 64 + ix] : 0.f;
    }
    __syncthreads();

#pragma unroll
    for (int c4 = 0; c4 < 4; c4++) {
      int ci = cg * 4 + c4;
      const float* xc = &xs[c4][0];
      float xv[6][3];
#pragma unroll
      for (int r = 0; r < 6; r++) {
        int srow = 4 * r4 + r;
#pragma unroll
        for (int cx = 0; cx < 3; cx++) {
          int ix = sx - 1 + cx;
          bool ok = (unsigned)ix < 64;
          float v = xc[ok ? srow * 64 + ix : 0];
          xv[r][cx] = ok ? v : 0.f;
        }
      }
      float w16[16];
#pragma unroll
      for (int q = 0; q < 4; q++) {
        float4 ww = *(const float4*)(w + ci * 16 + 4 * q);
        w16[4 * q + 0] = ww.x; w16[4 * q + 1] = ww.y;
        w16[4 * q + 2] = ww.z; w16[4 * q + 3] = ww.w;
      }
#pragma unroll
      for (int py = 0; py < 2; py++) {
#pragma unroll
        for (int px = 0; px < 2; px++) {
          int par = py * 2 + px;
          int ky0 = (py + 1) & 1, kx0 = (px + 1) & 1;
          int ay = (py + 1 - ky0) >> 1;
          int ax = (px + 1 - kx0) >> 1;
#pragma unroll
          for (int kyi = 0; kyi < 2; kyi++) {
#pragma unroll
            for (int kxi = 0; kxi < 2; kxi++) {
              float wv = w16[(ky0 + 2 * kyi) * 4 + (kx0 + 2 * kxi)];
#pragma unroll
              for (int j = 0; j < 4; j++) {
                float xx = xv[j + ay + 1 - kyi][ax + 1 - kxi];
                acc[j][par] = fmaf(xx, wv, acc[j][par]);
              }
            }
          }
        }
      }
    }
  }

  float b0 = bias[0];
#pragma unroll
  for (int j = 0; j < 4; j++) {
    int iy = y0 + 4 * r4 + j;
#pragma unroll
    for (int py = 0; py < 2; py++) {
      float v0 = acc[j][py * 2 + 0] + b0;
      float v1 = acc[j][py * 2 + 1] + b0;
      float2 o;
      o.x = 1.f / (1.f + expf(-v0));
      o.y = 1.f / (1.f + expf(-v1));
      int oy = 2 * iy + py;
      *(float2*)(out + (size_t)n * 16384 + oy * 128 + 2 * sx) = o;
    }
  }
}

// ---------------------------------------------------------------------------
__global__ void cbn_prep(const float* __restrict__ cb, float* __restrict__ cbn) {
#pragma clang fp contract(off)
  int k = blockIdx.x * 256 + threadIdx.x;
  if (k < 512) {
    float m[32];
#pragma unroll
    for (int d = 0; d < 32; d++) {
      float c = cb[k * 32 + d];
      m[d] = c * c;
    }
    float r[8];
#pragma unroll
    for (int j = 0; j < 8; j++)
      r[j] = ((m[j] + m[8 + j]) + m[16 + j]) + m[24 + j];
    cbn[k] = ((r[0] + r[1]) + (r[2] + r[3])) + ((r[4] + r[5]) + (r[6] + r[7]));
  }
}

// ---------------------------------------------------------------------------
// VQ: np-exact arithmetic, 1 px/thread, wave-uniform codebook loads.
// ---------------------------------------------------------------------------
__global__ __launch_bounds__(256)
void vq_kernel(const float* __restrict__ z, const float* __restrict__ cb,
               const float* __restrict__ cbn, float* __restrict__ qz,
               float* __restrict__ loss) {
  int tid = threadIdx.x;
  int n = blockIdx.x >> 2;
  int p = (blockIdx.x & 3) * 256 + tid;
  const float* zn = z + (size_t)n * 32768;

  float zv[32];
#pragma unroll
  for (int d = 0; d < 32; d++) zv[d] = zn[(size_t)d * 1024 + p];

  float zz;
  {
#pragma clang fp contract(off)
    float m[32];
#pragma unroll
    for (int d = 0; d < 32; d++) m[d] = zv[d] * zv[d];
    float r[8];
#pragma unroll
    for (int j = 0; j < 8; j++)
      r[j] = ((m[j] + m[8 + j]) + m[16 + j]) + m[24 + j];
    zz = ((r[0] + r[1]) + (r[2] + r[3])) + ((r[4] + r[5]) + (r[6] + r[7]));
  }

  float best = 3.4e38f;
  int bk = 0;
  for (int k4 = 0; k4 < 512; k4 += 4) {
    float4 cn = *(const float4*)(cbn + k4);
    float da[4];
#pragma unroll
    for (int u = 0; u < 4; u++) da[u] = 0.f;
#pragma unroll
    for (int d = 0; d < 32; d += 4) {
#pragma unroll
      for (int u = 0; u < 4; u++) {
        float4 c = *(const float4*)(cb + (size_t)(k4 + u) * 32 + d);
        float a = da[u];
        a = fmaf(zv[d + 0], c.x, a);
        a = fmaf(zv[d + 1], c.y, a);
        a = fmaf(zv[d + 2], c.z, a);
        a = fmaf(zv[d + 3], c.w, a);
        da[u] = a;
      }
    }
#pragma unroll
    for (int u = 0; u < 4; u++) {
      float cnu = (u == 0) ? cn.x : (u == 1) ? cn.y : (u == 2) ? cn.z : cn.w;
      float s;
      {
#pragma clang fp contract(off)
        s = (zz + cnu) - 2.f * da[u];
      }
      int k = k4 + u;
      if (s < best) { best = s; bk = k; }
    }
  }

  float lsum = 0.f;
  float* qn = qz + (size_t)n * 32768;
#pragma unroll
  for (int d = 0; d < 32; d += 4) {
#pragma clang fp contract(off)
    float4 q = *(const float4*)(cb + (size_t)bk * 32 + d);
    float e;
    e = q.x - zv[d + 0]; lsum = fmaf(e, e, lsum);
    e = q.y - zv[d + 1]; lsum = fmaf(e, e, lsum);
    e = q.z - zv[d + 2]; lsum = fmaf(e, e, lsum);
    e = q.w - zv[d + 3]; lsum = fmaf(e, e, lsum);
    qn[(size_t)(d + 0) * 1024 + p] = zv[d + 0] + (q.x - zv[d + 0]);
    qn[(size_t)(d + 1) * 1024 + p] = zv[d + 1] + (q.y - zv[d + 1]);
    qn[(size_t)(d + 2) * 1024 + p] = zv[d + 2] + (q.z - zv[d + 2]);
    qn[(size_t)(d + 3) * 1024 + p] = zv[d + 3] + (q.w - zv[d + 3]);
  }

#pragma unroll
  for (int off = 32; off; off >>= 1) lsum += __shfl_down(lsum, off, 64);
  if ((tid & 63) == 0) atomicAdd(loss, lsum);
}

__global__ void finalize_loss(const float* __restrict__ loss, float* __restrict__ out) {
  if (threadIdx.x == 0) {
    float m = loss[0] / 8388608.f;
    out[0] = m + 0.26f * m;
  }
}

// ---------------------------------------------------------------------------
// Workspace (floats): A = chunk*131072, B = chunk*65536, cbn 512, loss 1.
// Full batch = 201.3 MB; chunk count from ws_size (constant -> graph-safe).
// ---------------------------------------------------------------------------
extern "C" void kernel_launch(void* const* d_in, const int* in_sizes, int n_in,
                              void* d_out, int out_size, void* d_ws, size_t ws_size,
                              hipStream_t stream) {
  (void)in_sizes; (void)n_in; (void)out_size;
  const float* x   = (const float*)d_in[0];
  const float* ew1 = (const float*)d_in[1];
  const float* eb1 = (const float*)d_in[2];
  const float* ew2 = (const float*)d_in[3];
  const float* eb2 = (const float*)d_in[4];
  const float* ew3 = (const float*)d_in[5];
  const float* eb3 = (const float*)d_in[6];
  const float* ew4 = (const float*)d_in[7];
  const float* eb4 = (const float*)d_in[8];
  const float* cb  = (const float*)d_in[9];
  const float* dw1 = (const float*)d_in[10];
  const float* db1 = (const float*)d_in[11];
  const float* tw1 = (const float*)d_in[12];
  const float* tb1 = (const float*)d_in[13];
  const float* tw2 = (const float*)d_in[14];
  const float* tb2 = (const float*)d_in[15];
  float* out = (float*)d_out;

  auto need = [](size_t c) -> size_t { return (c * 196608 + 513) * 4; };
  int nchunks = 4;
  if (ws_size >= need(256)) nchunks = 1;
  else if (ws_size >= need(128)) nchunks = 2;
  int chunk = 256 / nchunks;

  float* ws = (float*)d_ws;
  float* A = ws;
  float* B = A + (size_t)chunk * 131072;
  float* cbn = B + (size_t)chunk * 65536;
  float* lossacc = cbn + 512;

  float* h1 = A;
  float* h2 = B;
  float* h3 = A;
  float* z  = A + (size_t)chunk * 65536;
  float* qz = A + (size_t)chunk * 98304;
  float* d1 = B;
  float* d2 = A;

  cbn_prep<<<2, 256, 0, stream>>>(cb, cbn);
  (void)hipMemsetAsync(lossacc, 0, 4, stream);

  for (int c = 0; c < nchunks; c++) {
    const float* xc = x + (size_t)c * chunk * 128 * 128;
    float* outc = out + (size_t)c * chunk * 128 * 128;

    conv_fwd<1, 32, 4, 2, 1, 128, 128, 64, 64, true, 16>
        <<<chunk * 4 * 2, 256, 0, stream>>>(xc, ew1, eb1, h1);
    conv4x4s2_cg<32, 64, 16>
        <<<chunk * 4, 256, 0, stream>>>(h1, ew2, eb2, h2);
    conv3x3_cg<64, 64, 16>
        <<<chunk * 4, 256, 0, stream>>>(h2, ew3, eb3, h3);
    conv_fwd<64, 32, 1, 1, 0, 32, 32, 32, 32, false, 16>
        <<<chunk * 2, 256, 0, stream>>>(h3, ew4, eb4, z);

    vq_kernel<<<chunk * 4, 256, 0, stream>>>(z, cb, cbn, qz, lossacc);

    conv3x3_cg<32, 64, 16>
        <<<chunk * 4, 256, 0, stream>>>(qz, dw1, db1, d1);
    convt_quad<64, 32, 16>
        <<<chunk * 4 * 2, 256, 0, stream>>>(d1, tw1, tb1, d2);
    dect2_full<<<chunk * 4, 256, 0, stream>>>(d2, tw2, tb2, outc);
  }

  finalize_loss<<<1, 64, 0, stream>>>(lossacc, out + 4194304);
}

// Round 9
// 1584.750 us; speedup vs baseline: 1.8833x; 1.2793x over previous
//
#include <hip/hip_runtime.h>
#include <math.h>

// ---------------------------------------------------------------------------
// Legacy direct conv (global loads + full-weight LDS) — conv1 (CIN=1, 1KB
// weights) and conv4 (1x1, 8KB). Thread owns 4 positions x CCH channels.
// ---------------------------------------------------------------------------
template<int CIN, int COUT, int K, int S, int PAD, int HIN, int WIN,
         int HOUT, int WOUT, bool RELU, int CCH>
__global__ __launch_bounds__(256, 3)
void conv_fwd(const float* __restrict__ x, const float* __restrict__ w,
              const float* __restrict__ bias, float* __restrict__ out) {
  constexpr int NPOS = HOUT * WOUT;
  constexpr int PTILES = NPOS / 1024;
  constexpr int NCH = COUT / CCH;
  constexpr int RSTEP = 256 / WOUT;
  constexpr int ROWS_PER_TILE = 1024 / WOUT;
  static_assert(NPOS % 1024 == 0, "pos tiling");

  int bid = blockIdx.x;
  int cchunk = bid % NCH;
  int ptile = (bid / NCH) % PTILES;
  int n = bid / (NCH * PTILES);
  int co0 = cchunk * CCH;

  __shared__ float wl[CIN * K * K][CCH];
  for (int i = threadIdx.x; i < CIN * K * K * CCH; i += 256) {
    int cc = i % CCH;
    int tap = i / CCH;
    wl[tap][cc] = w[(size_t)(co0 + cc) * (CIN * K * K) + tap];
  }
  __syncthreads();

  int t = threadIdx.x;
  int sx = t % WOUT;
  int syb = ptile * ROWS_PER_TILE + t / WOUT;

  float acc[4][CCH];
#pragma unroll
  for (int j = 0; j < 4; j++)
#pragma unroll
    for (int c = 0; c < CCH; c++) acc[j][c] = 0.f;

  const float* xn = x + (size_t)n * CIN * HIN * WIN;
  int ix0 = sx * S - PAD;

  for (int ci = 0; ci < CIN; ci++) {
    const float* xc = xn + (size_t)ci * HIN * WIN;
#pragma unroll
    for (int ky = 0; ky < K; ky++) {
#pragma unroll
      for (int kx = 0; kx < K; kx++) {
        int ix = ix0 + kx;
        bool xok = (unsigned)ix < WIN;
        float xv[4];
#pragma unroll
        for (int j = 0; j < 4; j++) {
          int iy = (syb + j * RSTEP) * S - PAD + ky;
          bool ok = xok && ((unsigned)iy < HIN);
          xv[j] = ok ? xc[iy * WIN + ix] : 0.f;
        }
        const float* wr = &wl[ci * K * K + ky * K + kx][0];
#pragma unroll
        for (int c = 0; c < CCH; c += 4) {
          float4 wv = *(const float4*)(wr + c);
#pragma unroll
          for (int j = 0; j < 4; j++) {
            acc[j][c + 0] = fmaf(xv[j], wv.x, acc[j][c + 0]);
            acc[j][c + 1] = fmaf(xv[j], wv.y, acc[j][c + 1]);
            acc[j][c + 2] = fmaf(xv[j], wv.z, acc[j][c + 2]);
            acc[j][c + 3] = fmaf(xv[j], wv.w, acc[j][c + 3]);
          }
        }
      }
    }
  }

#pragma unroll
  for (int j = 0; j < 4; j++) {
    int sy = syb + j * RSTEP;
    float* op = out + (((size_t)n * COUT + co0) * HOUT + sy) * WOUT + sx;
#pragma unroll
    for (int c = 0; c < CCH; c++) {
      float v = acc[j][c] + bias[co0 + c];
      if (RELU) v = fmaxf(v, 0.f);
      op[(size_t)c * HOUT * WOUT] = v;
    }
  }
}

// ---------------------------------------------------------------------------
// conv2: 4x4 s=2 p=1 ReLU, 64x64 -> 32x32 (round-5 known-good structure).
// ALL weights staged once (32KB) + 1 input channel (16KB) per barrier round
// -> 48KB LDS -> 3 blocks/CU at (256,3); VGPR cap ~170 -> no acc spill.
// (Round-8's (256,4)+per-cg weights spilled: VGPR 64, WRITE 1.28GB vs 67MB.)
// grid = NB * (COUT/CCH).
// ---------------------------------------------------------------------------
template<int CIN, int COUT, int CCH>
__global__ __launch_bounds__(256, 3)
void conv4x4s2_lds(const float* __restrict__ x, const float* __restrict__ w,
                   const float* __restrict__ bias, float* __restrict__ out) {
  constexpr int NCH = COUT / CCH;
  int bid = blockIdx.x;
  int cchunk = bid % NCH;
  int n = bid / NCH;
  int co0 = cchunk * CCH;

  __shared__ float wl[CIN * 16][CCH];
  __shared__ float xs[4096];
  for (int i = threadIdx.x; i < CIN * 16 * CCH; i += 256) {
    int cc = i % CCH;
    int tap = i / CCH;
    wl[tap][cc] = w[(size_t)(co0 + cc) * (CIN * 16) + tap];
  }

  int t = threadIdx.x;
  int sx = t & 31;
  int sy0 = t >> 5;
  int ix0 = 2 * sx - 1;

  float acc[4][CCH];
#pragma unroll
  for (int j = 0; j < 4; j++)
#pragma unroll
    for (int c = 0; c < CCH; c++) acc[j][c] = 0.f;

  const float* xn = x + (size_t)n * CIN * 4096;

  for (int ci = 0; ci < CIN; ci++) {
    __syncthreads();
#pragma unroll
    for (int k = 0; k < 4; k++)
      *(float4*)(xs + k * 1024 + t * 4) =
          *(const float4*)(xn + (size_t)ci * 4096 + k * 1024 + t * 4);
    __syncthreads();

#pragma unroll
    for (int ky = 0; ky < 4; ky++) {
#pragma unroll
      for (int kx = 0; kx < 4; kx++) {
        int ix = ix0 + kx;
        bool xok = (unsigned)ix < 64;
        float xv[4];
#pragma unroll
        for (int j = 0; j < 4; j++) {
          int iy = 2 * (sy0 + j * 8) - 1 + ky;
          bool ok = xok && ((unsigned)iy < 64);
          float v = xs[ok ? iy * 64 + ix : 0];
          xv[j] = ok ? v : 0.f;
        }
        const float* wr = &wl[ci * 16 + ky * 4 + kx][0];
#pragma unroll
        for (int c = 0; c < CCH; c += 4) {
          float4 wv = *(const float4*)(wr + c);
#pragma unroll
          for (int j = 0; j < 4; j++) {
            acc[j][c + 0] = fmaf(xv[j], wv.x, acc[j][c + 0]);
            acc[j][c + 1] = fmaf(xv[j], wv.y, acc[j][c + 1]);
            acc[j][c + 2] = fmaf(xv[j], wv.z, acc[j][c + 2]);
            acc[j][c + 3] = fmaf(xv[j], wv.w, acc[j][c + 3]);
          }
        }
      }
    }
  }

#pragma unroll
  for (int j = 0; j < 4; j++) {
    int sy = sy0 + j * 8;
    float* op = out + (((size_t)n * COUT + co0) * 32 + sy) * 32 + sx;
#pragma unroll
    for (int c = 0; c < CCH; c++) {
      float v = acc[j][c] + bias[co0 + c];
      v = fmaxf(v, 0.f);
      op[(size_t)c * 1024] = v;
    }
  }
}

// ---------------------------------------------------------------------------
// conv3/dec1: 3x3 s=1 p=1 ReLU on 32x32. 4 input channels (16KB) + weight
// slice (2.25KB) per barrier round, (256,4). (Round-8: absent from top-5.)
// ---------------------------------------------------------------------------
template<int CIN, int COUT, int CCH>
__global__ __launch_bounds__(256, 4)
void conv3x3_cg(const float* __restrict__ x, const float* __restrict__ w,
                const float* __restrict__ bias, float* __restrict__ out) {
  constexpr int NCH = COUT / CCH;
  int bid = blockIdx.x;
  int cchunk = bid % NCH;
  int n = bid / NCH;
  int co0 = cchunk * CCH;

  __shared__ float xs[4 * 1024];
  __shared__ float wl[4 * 9][CCH];

  int t = threadIdx.x;
  int sx = t & 31;
  int rg = t >> 5;

  float acc[4][CCH];
#pragma unroll
  for (int j = 0; j < 4; j++)
#pragma unroll
    for (int c = 0; c < CCH; c++) acc[j][c] = 0.f;

  const float* xn = x + (size_t)n * CIN * 1024;

  for (int cg = 0; cg < CIN / 4; cg++) {
    __syncthreads();
#pragma unroll
    for (int k = 0; k < 4; k++)
      *(float4*)(xs + k * 1024 + t * 4) =
          *(const float4*)(xn + (size_t)(cg * 4 + k) * 1024 + t * 4);
    for (int i = t; i < 4 * 9 * CCH; i += 256) {
      int cc = i % CCH;
      int row = i / CCH;
      int c4 = row / 9, kk = row % 9;
      wl[row][cc] = w[(size_t)(co0 + cc) * (CIN * 9) + (cg * 4 + c4) * 9 + kk];
    }
    __syncthreads();

#pragma unroll
    for (int c4 = 0; c4 < 4; c4++) {
      const float* xc = xs + c4 * 1024;
      float xv[6][3];
#pragma unroll
      for (int r = 0; r < 6; r++) {
        int iy = 4 * rg - 1 + r;
        bool yok = (unsigned)iy < 32;
#pragma unroll
        for (int cx = 0; cx < 3; cx++) {
          int ix = sx - 1 + cx;
          bool ok = yok && ((unsigned)ix < 32);
          float v = xc[ok ? iy * 32 + ix : 0];
          xv[r][cx] = ok ? v : 0.f;
        }
      }
#pragma unroll
      for (int ky = 0; ky < 3; ky++) {
#pragma unroll
        for (int kx = 0; kx < 3; kx++) {
          const float* wr = &wl[c4 * 9 + ky * 3 + kx][0];
#pragma unroll
          for (int c = 0; c < CCH; c += 4) {
            float4 wv = *(const float4*)(wr + c);
#pragma unroll
            for (int j = 0; j < 4; j++) {
              float xx = xv[j + ky][kx];
              acc[j][c + 0] = fmaf(xx, wv.x, acc[j][c + 0]);
              acc[j][c + 1] = fmaf(xx, wv.y, acc[j][c + 1]);
              acc[j][c + 2] = fmaf(xx, wv.z, acc[j][c + 2]);
              acc[j][c + 3] = fmaf(xx, wv.w, acc[j][c + 3]);
            }
          }
        }
      }
    }
  }

#pragma unroll
  for (int j = 0; j < 4; j++) {
    int sy = 4 * rg + j;
    float* op = out + (((size_t)n * COUT + co0) * 32 + sy) * 32 + sx;
#pragma unroll
    for (int c = 0; c < CCH; c++) {
      float v = acc[j][c] + bias[co0 + c];
      v = fmaxf(v, 0.f);
      op[(size_t)c * 1024] = v;
    }
  }
}

// ---------------------------------------------------------------------------
// dect1 QUAD: tconv k=4 s=2 p=1 ReLU, in [n,64,32,32] -> out [n,32,64,64].
// Thread owns one input position, computes the full 2x2 output quad for
// CCH=16 channels -> float2 coalesced stores, no RMW. (Round-8: fixed the
// 1.44GB round-7 disaster; absent from top-5.)
// ---------------------------------------------------------------------------
template<int CIN, int COUT, int CCH>
__global__ __launch_bounds__(256, 4)
void convt_quad(const float* __restrict__ x, const float* __restrict__ w,
                const float* __restrict__ bias, float* __restrict__ out) {
  constexpr int NCH = COUT / CCH;
  int bid = blockIdx.x;
  int cchunk = bid % NCH;
  int tile = (bid / NCH) & 3;
  int n = bid / (NCH * 4);
  int co0 = cchunk * CCH;
  int sy0 = tile * 8;

  __shared__ float xs[4][320];        // 10 rows (sy0-1..sy0+8) x 32 cols
  __shared__ float wl[4 * 16][CCH];

  int t = threadIdx.x;
  int sx = t & 31;
  int syl = t >> 5;
  int sy = sy0 + syl;

  float acc[2][2][CCH];
#pragma unroll
  for (int py = 0; py < 2; py++)
#pragma unroll
    for (int px = 0; px < 2; px++)
#pragma unroll
      for (int c = 0; c < CCH; c++) acc[py][px][c] = 0.f;

  const float* xn = x + (size_t)n * CIN * 1024;

  for (int cg = 0; cg < CIN / 4; cg++) {
    __syncthreads();
    for (int idx = t; idx < 4 * 320; idx += 256) {
      int ch = idx / 320;
      int rem = idx % 320;
      int gy = sy0 - 1 + rem / 32;
      int col = rem & 31;
      bool ok = (unsigned)gy < 32;
      xs[ch][rem] = ok ? xn[(size_t)(cg * 4 + ch) * 1024 + gy * 32 + col] : 0.f;
    }
    for (int idx = t; idx < 4 * 16 * CCH; idx += 256) {
      int c = idx % CCH;
      int row = idx / CCH;
      int c4 = row >> 4, kk = row & 15;
      wl[row][c] = w[((size_t)(cg * 4 + c4) * COUT + (co0 + c)) * 16 + kk];
    }
    __syncthreads();

#pragma unroll
    for (int c4 = 0; c4 < 4; c4++) {
      float xv[3][3];
#pragma unroll
      for (int r = 0; r < 3; r++) {
#pragma unroll
        for (int cx = 0; cx < 3; cx++) {
          int ix = sx - 1 + cx;
          bool ok = (unsigned)ix < 32;
          float v = xs[c4][(syl + r) * 32 + (ok ? ix : 0)];
          xv[r][cx] = ok ? v : 0.f;
        }
      }
#pragma unroll
      for (int py = 0; py < 2; py++) {
        int ky0 = (py + 1) & 1;
        int ay = (py + 1 - ky0) >> 1;
#pragma unroll
        for (int px = 0; px < 2; px++) {
          int kx0 = (px + 1) & 1;
          int ax = (px + 1 - kx0) >> 1;
#pragma unroll
          for (int kyi = 0; kyi < 2; kyi++) {
#pragma unroll
            for (int kxi = 0; kxi < 2; kxi++) {
              int kk = (ky0 + 2 * kyi) * 4 + (kx0 + 2 * kxi);
              float xx = xv[ay - kyi + 1][ax - kxi + 1];
              const float* wr = &wl[c4 * 16 + kk][0];
#pragma unroll
              for (int c = 0; c < CCH; c += 4) {
                float4 wv = *(const float4*)(wr + c);
                acc[py][px][c + 0] = fmaf(xx, wv.x, acc[py][px][c + 0]);
                acc[py][px][c + 1] = fmaf(xx, wv.y, acc[py][px][c + 1]);
                acc[py][px][c + 2] = fmaf(xx, wv.z, acc[py][px][c + 2]);
                acc[py][px][c + 3] = fmaf(xx, wv.w, acc[py][px][c + 3]);
              }
            }
          }
        }
      }
    }
  }

#pragma unroll
  for (int py = 0; py < 2; py++) {
    int oy = 2 * sy + py;
#pragma unroll
    for (int c = 0; c < CCH; c++) {
      float b = bias[co0 + c];
      float2 o;
      o.x = fmaxf(acc[py][0][c] + b, 0.f);
      o.y = fmaxf(acc[py][1][c] + b, 0.f);
      *(float2*)(out + ((size_t)(n * COUT + co0 + c) * 64 + oy) * 64 + 2 * sx) = o;
    }
  }
}

// ---------------------------------------------------------------------------
// dect2: tconv k=4 s=2 p=1, CIN=32, COUT=1, sigmoid; all 4 parities per
// thread. in 64x64 -> out 128x128. grid = NB * 4 row-tiles.
// ---------------------------------------------------------------------------
__global__ __launch_bounds__(256, 4)
void dect2_full(const float* __restrict__ x, const float* __restrict__ w,
                const float* __restrict__ bias, float* __restrict__ out) {
  int ptile = blockIdx.x & 3;
  int n = blockIdx.x >> 2;
  int y0 = ptile * 16;

  __shared__ float xs[4][1152];      // rows y0-1..y0+16 (18) x 64 cols
  int t = threadIdx.x;
  int sx = t & 63;
  int r4 = t >> 6;

  float acc[4][4];
#pragma unroll
  for (int j = 0; j < 4; j++)
#pragma unroll
    for (int p = 0; p < 4; p++) acc[j][p] = 0.f;

  const float* xn = x + (size_t)n * 32 * 4096;

  for (int cg = 0; cg < 8; cg++) {
    __syncthreads();
    for (int idx = t; idx < 4 * 1152; idx += 256) {
      int ch = idx / 1152;
      int rem = idx % 1152;
      int iy = y0 - 1 + rem / 64;
      int ix = rem & 63;
      bool ok = (unsigned)iy < 64;
      xs[ch][rem] = ok ? xn[(size_t)(cg * 4 + ch) * 4096 + iy * 64 + ix] : 0.f;
    }
    __syncthreads();

#pragma unroll
    for (int c4 = 0; c4 < 4; c4++) {
      int ci = cg * 4 + c4;
      const float* xc = &xs[c4][0];
      float xv[6][3];
#pragma unroll
      for (int r = 0; r < 6; r++) {
        int srow = 4 * r4 + r;
#pragma unroll
        for (int cx = 0; cx < 3; cx++) {
          int ix = sx - 1 + cx;
          bool ok = (unsigned)ix < 64;
          float v = xc[ok ? srow * 64 + ix : 0];
          xv[r][cx] = ok ? v : 0.f;
        }
      }
      float w16[16];
#pragma unroll
      for (int q = 0; q < 4; q++) {
        float4 ww = *(const float4*)(w + ci * 16 + 4 * q);
        w16[4 * q + 0] = ww.x; w16[4 * q + 1] = ww.y;
        w16[4 * q + 2] = ww.z; w16[4 * q + 3] = ww.w;
      }
#pragma unroll
      for (int py = 0; py < 2; py++) {
#pragma unroll
        for (int px = 0; px < 2; px++) {
          int par = py * 2 + px;
          int ky0 = (py + 1) & 1, kx0 = (px + 1) & 1;
          int ay = (py + 1 - ky0) >> 1;
          int ax = (px + 1 - kx0) >> 1;
#pragma unroll
          for (int kyi = 0; kyi < 2; kyi++) {
#pragma unroll
            for (int kxi = 0; kxi < 2; kxi++) {
              float wv = w16[(ky0 + 2 * kyi) * 4 + (kx0 + 2 * kxi)];
#pragma unroll
              for (int j = 0; j < 4; j++) {
                float xx = xv[j + ay + 1 - kyi][ax + 1 - kxi];
                acc[j][par] = fmaf(xx, wv, acc[j][par]);
              }
            }
          }
        }
      }
    }
  }

  float b0 = bias[0];
#pragma unroll
  for (int j = 0; j < 4; j++) {
    int iy = y0 + 4 * r4 + j;
#pragma unroll
    for (int py = 0; py < 2; py++) {
      float v0 = acc[j][py * 2 + 0] + b0;
      float v1 = acc[j][py * 2 + 1] + b0;
      float2 o;
      o.x = 1.f / (1.f + expf(-v0));
      o.y = 1.f / (1.f + expf(-v1));
      int oy = 2 * iy + py;
      *(float2*)(out + (size_t)n * 16384 + oy * 128 + 2 * sx) = o;
    }
  }
}

// ---------------------------------------------------------------------------
__global__ void cbn_prep(const float* __restrict__ cb, float* __restrict__ cbn) {
#pragma clang fp contract(off)
  int k = blockIdx.x * 256 + threadIdx.x;
  if (k < 512) {
    float m[32];
#pragma unroll
    for (int d = 0; d < 32; d++) {
      float c = cb[k * 32 + d];
      m[d] = c * c;
    }
    float r[8];
#pragma unroll
    for (int j = 0; j < 8; j++)
      r[j] = ((m[j] + m[8 + j]) + m[16 + j]) + m[24 + j];
    cbn[k] = ((r[0] + r[1]) + (r[2] + r[3])) + ((r[4] + r[5]) + (r[6] + r[7]));
  }
}

// ---------------------------------------------------------------------------
// VQ: np-exact arithmetic, 1 px/thread, wave-uniform codebook loads.
// ---------------------------------------------------------------------------
__global__ __launch_bounds__(256)
void vq_kernel(const float* __restrict__ z, const float* __restrict__ cb,
               const float* __restrict__ cbn, float* __restrict__ qz,
               float* __restrict__ loss) {
  int tid = threadIdx.x;
  int n = blockIdx.x >> 2;
  int p = (blockIdx.x & 3) * 256 + tid;
  const float* zn = z + (size_t)n * 32768;

  float zv[32];
#pragma unroll
  for (int d = 0; d < 32; d++) zv[d] = zn[(size_t)d * 1024 + p];

  float zz;
  {
#pragma clang fp contract(off)
    float m[32];
#pragma unroll
    for (int d = 0; d < 32; d++) m[d] = zv[d] * zv[d];
    float r[8];
#pragma unroll
    for (int j = 0; j < 8; j++)
      r[j] = ((m[j] + m[8 + j]) + m[16 + j]) + m[24 + j];
    zz = ((r[0] + r[1]) + (r[2] + r[3])) + ((r[4] + r[5]) + (r[6] + r[7]));
  }

  float best = 3.4e38f;
  int bk = 0;
  for (int k4 = 0; k4 < 512; k4 += 4) {
    float4 cn = *(const float4*)(cbn + k4);
    float da[4];
#pragma unroll
    for (int u = 0; u < 4; u++) da[u] = 0.f;
#pragma unroll
    for (int d = 0; d < 32; d += 4) {
#pragma unroll
      for (int u = 0; u < 4; u++) {
        float4 c = *(const float4*)(cb + (size_t)(k4 + u) * 32 + d);
        float a = da[u];
        a = fmaf(zv[d + 0], c.x, a);
        a = fmaf(zv[d + 1], c.y, a);
        a = fmaf(zv[d + 2], c.z, a);
        a = fmaf(zv[d + 3], c.w, a);
        da[u] = a;
      }
    }
#pragma unroll
    for (int u = 0; u < 4; u++) {
      float cnu = (u == 0) ? cn.x : (u == 1) ? cn.y : (u == 2) ? cn.z : cn.w;
      float s;
      {
#pragma clang fp contract(off)
        s = (zz + cnu) - 2.f * da[u];
      }
      int k = k4 + u;
      if (s < best) { best = s; bk = k; }
    }
  }

  float lsum = 0.f;
  float* qn = qz + (size_t)n * 32768;
#pragma unroll
  for (int d = 0; d < 32; d += 4) {
#pragma clang fp contract(off)
    float4 q = *(const float4*)(cb + (size_t)bk * 32 + d);
    float e;
    e = q.x - zv[d + 0]; lsum = fmaf(e, e, lsum);
    e = q.y - zv[d + 1]; lsum = fmaf(e, e, lsum);
    e = q.z - zv[d + 2]; lsum = fmaf(e, e, lsum);
    e = q.w - zv[d + 3]; lsum = fmaf(e, e, lsum);
    qn[(size_t)(d + 0) * 1024 + p] = zv[d + 0] + (q.x - zv[d + 0]);
    qn[(size_t)(d + 1) * 1024 + p] = zv[d + 1] + (q.y - zv[d + 1]);
    qn[(size_t)(d + 2) * 1024 + p] = zv[d + 2] + (q.z - zv[d + 2]);
    qn[(size_t)(d + 3) * 1024 + p] = zv[d + 3] + (q.w - zv[d + 3]);
  }

#pragma unroll
  for (int off = 32; off; off >>= 1) lsum += __shfl_down(lsum, off, 64);
  if ((tid & 63) == 0) atomicAdd(loss, lsum);
}

__global__ void finalize_loss(const float* __restrict__ loss, float* __restrict__ out) {
  if (threadIdx.x == 0) {
    float m = loss[0] / 8388608.f;
    out[0] = m + 0.26f * m;
  }
}

// ---------------------------------------------------------------------------
// Workspace (floats): A = chunk*131072, B = chunk*65536, cbn 512, loss 1.
// Full batch = 201.3 MB; chunk count from ws_size (constant -> graph-safe).
// ---------------------------------------------------------------------------
extern "C" void kernel_launch(void* const* d_in, const int* in_sizes, int n_in,
                              void* d_out, int out_size, void* d_ws, size_t ws_size,
                              hipStream_t stream) {
  (void)in_sizes; (void)n_in; (void)out_size;
  const float* x   = (const float*)d_in[0];
  const float* ew1 = (const float*)d_in[1];
  const float* eb1 = (const float*)d_in[2];
  const float* ew2 = (const float*)d_in[3];
  const float* eb2 = (const float*)d_in[4];
  const float* ew3 = (const float*)d_in[5];
  const float* eb3 = (const float*)d_in[6];
  const float* ew4 = (const float*)d_in[7];
  const float* eb4 = (const float*)d_in[8];
  const float* cb  = (const float*)d_in[9];
  const float* dw1 = (const float*)d_in[10];
  const float* db1 = (const float*)d_in[11];
  const float* tw1 = (const float*)d_in[12];
  const float* tb1 = (const float*)d_in[13];
  const float* tw2 = (const float*)d_in[14];
  const float* tb2 = (const float*)d_in[15];
  float* out = (float*)d_out;

  auto need = [](size_t c) -> size_t { return (c * 196608 + 513) * 4; };
  int nchunks = 4;
  if (ws_size >= need(256)) nchunks = 1;
  else if (ws_size >= need(128)) nchunks = 2;
  int chunk = 256 / nchunks;

  float* ws = (float*)d_ws;
  float* A = ws;
  float* B = A + (size_t)chunk * 131072;
  float* cbn = B + (size_t)chunk * 65536;
  float* lossacc = cbn + 512;

  float* h1 = A;
  float* h2 = B;
  float* h3 = A;
  float* z  = A + (size_t)chunk * 65536;
  float* qz = A + (size_t)chunk * 98304;
  float* d1 = B;
  float* d2 = A;

  cbn_prep<<<2, 256, 0, stream>>>(cb, cbn);
  (void)hipMemsetAsync(lossacc, 0, 4, stream);

  for (int c = 0; c < nchunks; c++) {
    const float* xc = x + (size_t)c * chunk * 128 * 128;
    float* outc = out + (size_t)c * chunk * 128 * 128;

    conv_fwd<1, 32, 4, 2, 1, 128, 128, 64, 64, true, 16>
        <<<chunk * 4 * 2, 256, 0, stream>>>(xc, ew1, eb1, h1);
    conv4x4s2_lds<32, 64, 16>
        <<<chunk * 4, 256, 0, stream>>>(h1, ew2, eb2, h2);
    conv3x3_cg<64, 64, 16>
        <<<chunk * 4, 256, 0, stream>>>(h2, ew3, eb3, h3);
    conv_fwd<64, 32, 1, 1, 0, 32, 32, 32, 32, false, 16>
        <<<chunk * 2, 256, 0, stream>>>(h3, ew4, eb4, z);

    vq_kernel<<<chunk * 4, 256, 0, stream>>>(z, cb, cbn, qz, lossacc);

    conv3x3_cg<32, 64, 16>
        <<<chunk * 4, 256, 0, stream>>>(qz, dw1, db1, d1);
    convt_quad<64, 32, 16>
        <<<chunk * 4 * 2, 256, 0, stream>>>(d1, tw1, tb1, d2);
    dect2_full<<<chunk * 4, 256, 0, stream>>>(d2, tw2, tb2, outc);
  }

  finalize_loss<<<1, 64, 0, stream>>>(lossacc, out + 4194304);
}

// Round 10
// 1374.964 us; speedup vs baseline: 2.1707x; 1.1526x over previous
//
#include <hip/hip_runtime.h>
#include <math.h>

// ---------------------------------------------------------------------------
// Legacy direct conv (global loads + full-weight LDS) — conv4 (1x1, 8KB).
// ---------------------------------------------------------------------------
template<int CIN, int COUT, int K, int S, int PAD, int HIN, int WIN,
         int HOUT, int WOUT, bool RELU, int CCH>
__global__ __launch_bounds__(256, 3)
void conv_fwd(const float* __restrict__ x, const float* __restrict__ w,
              const float* __restrict__ bias, float* __restrict__ out) {
  constexpr int NPOS = HOUT * WOUT;
  constexpr int PTILES = NPOS / 1024;
  constexpr int NCH = COUT / CCH;
  constexpr int RSTEP = 256 / WOUT;
  constexpr int ROWS_PER_TILE = 1024 / WOUT;
  static_assert(NPOS % 1024 == 0, "pos tiling");

  int bid = blockIdx.x;
  int cchunk = bid % NCH;
  int ptile = (bid / NCH) % PTILES;
  int n = bid / (NCH * PTILES);
  int co0 = cchunk * CCH;

  __shared__ float wl[CIN * K * K][CCH];
  for (int i = threadIdx.x; i < CIN * K * K * CCH; i += 256) {
    int cc = i % CCH;
    int tap = i / CCH;
    wl[tap][cc] = w[(size_t)(co0 + cc) * (CIN * K * K) + tap];
  }
  __syncthreads();

  int t = threadIdx.x;
  int sx = t % WOUT;
  int syb = ptile * ROWS_PER_TILE + t / WOUT;

  float acc[4][CCH];
#pragma unroll
  for (int j = 0; j < 4; j++)
#pragma unroll
    for (int c = 0; c < CCH; c++) acc[j][c] = 0.f;

  const float* xn = x + (size_t)n * CIN * HIN * WIN;
  int ix0 = sx * S - PAD;

  for (int ci = 0; ci < CIN; ci++) {
    const float* xc = xn + (size_t)ci * HIN * WIN;
#pragma unroll
    for (int ky = 0; ky < K; ky++) {
#pragma unroll
      for (int kx = 0; kx < K; kx++) {
        int ix = ix0 + kx;
        bool xok = (unsigned)ix < WIN;
        float xv[4];
#pragma unroll
        for (int j = 0; j < 4; j++) {
          int iy = (syb + j * RSTEP) * S - PAD + ky;
          bool ok = xok && ((unsigned)iy < HIN);
          xv[j] = ok ? xc[iy * WIN + ix] : 0.f;
        }
        const float* wr = &wl[ci * K * K + ky * K + kx][0];
#pragma unroll
        for (int c = 0; c < CCH; c += 4) {
          float4 wv = *(const float4*)(wr + c);
#pragma unroll
          for (int j = 0; j < 4; j++) {
            acc[j][c + 0] = fmaf(xv[j], wv.x, acc[j][c + 0]);
            acc[j][c + 1] = fmaf(xv[j], wv.y, acc[j][c + 1]);
            acc[j][c + 2] = fmaf(xv[j], wv.z, acc[j][c + 2]);
            acc[j][c + 3] = fmaf(xv[j], wv.w, acc[j][c + 3]);
          }
        }
      }
    }
  }

#pragma unroll
  for (int j = 0; j < 4; j++) {
    int sy = syb + j * RSTEP;
    float* op = out + (((size_t)n * COUT + co0) * HOUT + sy) * WOUT + sx;
#pragma unroll
    for (int c = 0; c < CCH; c++) {
      float v = acc[j][c] + bias[co0 + c];
      if (RELU) v = fmaxf(v, 0.f);
      op[(size_t)c * HOUT * WOUT] = v;
    }
  }
}

// ---------------------------------------------------------------------------
// conv1: 4x4 s=2 p=1 ReLU, CIN=1, 128x128 -> 64x64, 32 ch. SINGLE barrier:
// stage 34-row input slab (17.4KB) + all 16x16 weights (1KB) once.
// Chain order ky -> kx identical to legacy conv_fwd -> h1 bitwise-identical.
// grid = NB * 4 row-tiles * 2 co-chunks.
// ---------------------------------------------------------------------------
__global__ __launch_bounds__(256, 4)
void conv1_lds(const float* __restrict__ x, const float* __restrict__ w,
               const float* __restrict__ bias, float* __restrict__ out) {
  int bid = blockIdx.x;
  int cchunk = bid & 1;
  int t4 = (bid >> 1) & 3;
  int n = bid >> 3;
  int co0 = cchunk * 16;
  int y0 = t4 * 16;               // out rows y0..y0+15
  int yi0 = 2 * y0 - 1;           // first input row staged

  __shared__ float xs[34 * 128];
  __shared__ float wl[16][16];    // [tap][co]

  int t = threadIdx.x;
  for (int idx = t; idx < 34 * 128; idx += 256) {
    int gy = yi0 + (idx >> 7);
    int gx = idx & 127;
    bool ok = (unsigned)gy < 128;
    xs[idx] = ok ? x[(size_t)n * 16384 + gy * 128 + gx] : 0.f;
  }
  {
    int cc = t & 15;
    int tap = t >> 4;
    wl[tap][cc] = w[(size_t)(co0 + cc) * 16 + tap];
  }
  __syncthreads();

  int sx = t & 63;
  int rg = t >> 6;                // rows y0 + 4*rg + j

  float acc[4][16];
#pragma unroll
  for (int j = 0; j < 4; j++)
#pragma unroll
    for (int c = 0; c < 16; c++) acc[j][c] = 0.f;

  int ix0 = 2 * sx - 1;
#pragma unroll
  for (int ky = 0; ky < 4; ky++) {
#pragma unroll
    for (int kx = 0; kx < 4; kx++) {
      int ix = ix0 + kx;
      bool xok = (unsigned)ix < 128;
      float xv[4];
#pragma unroll
      for (int j = 0; j < 4; j++) {
        int lrow = 2 * (4 * rg + j) + ky;   // = (2*oy-1+ky) - yi0
        float v = xs[lrow * 128 + (xok ? ix : 0)];
        xv[j] = xok ? v : 0.f;
      }
      const float* wr = &wl[ky * 4 + kx][0];
#pragma unroll
      for (int c = 0; c < 16; c += 4) {
        float4 wv = *(const float4*)(wr + c);
#pragma unroll
        for (int j = 0; j < 4; j++) {
          acc[j][c + 0] = fmaf(xv[j], wv.x, acc[j][c + 0]);
          acc[j][c + 1] = fmaf(xv[j], wv.y, acc[j][c + 1]);
          acc[j][c + 2] = fmaf(xv[j], wv.z, acc[j][c + 2]);
          acc[j][c + 3] = fmaf(xv[j], wv.w, acc[j][c + 3]);
        }
      }
    }
  }

#pragma unroll
  for (int j = 0; j < 4; j++) {
    int oy = y0 + 4 * rg + j;
    float* op = out + (((size_t)n * 32 + co0) * 64 + oy) * 64 + sx;
#pragma unroll
    for (int c = 0; c < 16; c++) {
      float v = acc[j][c] + bias[co0 + c];
      op[(size_t)c * 4096] = fmaxf(v, 0.f);
    }
  }
}

// ---------------------------------------------------------------------------
// conv2: 4x4 s=2 p=1 ReLU, 64x64 -> 32x32 (round-5/9 proven structure).
// ALL weights staged once (32KB) + 1 input channel per round; (256,3).
// ---------------------------------------------------------------------------
template<int CIN, int COUT, int CCH>
__global__ __launch_bounds__(256, 3)
void conv4x4s2_lds(const float* __restrict__ x, const float* __restrict__ w,
                   const float* __restrict__ bias, float* __restrict__ out) {
  constexpr int NCH = COUT / CCH;
  int bid = blockIdx.x;
  int cchunk = bid % NCH;
  int n = bid / NCH;
  int co0 = cchunk * CCH;

  __shared__ float wl[CIN * 16][CCH];
  __shared__ float xs[4096];
  for (int i = threadIdx.x; i < CIN * 16 * CCH; i += 256) {
    int cc = i % CCH;
    int tap = i / CCH;
    wl[tap][cc] = w[(size_t)(co0 + cc) * (CIN * 16) + tap];
  }

  int t = threadIdx.x;
  int sx = t & 31;
  int sy0 = t >> 5;
  int ix0 = 2 * sx - 1;

  float acc[4][CCH];
#pragma unroll
  for (int j = 0; j < 4; j++)
#pragma unroll
    for (int c = 0; c < CCH; c++) acc[j][c] = 0.f;

  const float* xn = x + (size_t)n * CIN * 4096;

  for (int ci = 0; ci < CIN; ci++) {
    __syncthreads();
#pragma unroll
    for (int k = 0; k < 4; k++)
      *(float4*)(xs + k * 1024 + t * 4) =
          *(const float4*)(xn + (size_t)ci * 4096 + k * 1024 + t * 4);
    __syncthreads();

#pragma unroll
    for (int ky = 0; ky < 4; ky++) {
#pragma unroll
      for (int kx = 0; kx < 4; kx++) {
        int ix = ix0 + kx;
        bool xok = (unsigned)ix < 64;
        float xv[4];
#pragma unroll
        for (int j = 0; j < 4; j++) {
          int iy = 2 * (sy0 + j * 8) - 1 + ky;
          bool ok = xok && ((unsigned)iy < 64);
          float v = xs[ok ? iy * 64 + ix : 0];
          xv[j] = ok ? v : 0.f;
        }
        const float* wr = &wl[ci * 16 + ky * 4 + kx][0];
#pragma unroll
        for (int c = 0; c < CCH; c += 4) {
          float4 wv = *(const float4*)(wr + c);
#pragma unroll
          for (int j = 0; j < 4; j++) {
            acc[j][c + 0] = fmaf(xv[j], wv.x, acc[j][c + 0]);
            acc[j][c + 1] = fmaf(xv[j], wv.y, acc[j][c + 1]);
            acc[j][c + 2] = fmaf(xv[j], wv.z, acc[j][c + 2]);
            acc[j][c + 3] = fmaf(xv[j], wv.w, acc[j][c + 3]);
          }
        }
      }
    }
  }

#pragma unroll
  for (int j = 0; j < 4; j++) {
    int sy = sy0 + j * 8;
    float* op = out + (((size_t)n * COUT + co0) * 32 + sy) * 32 + sx;
#pragma unroll
    for (int c = 0; c < CCH; c++) {
      float v = acc[j][c] + bias[co0 + c];
      v = fmaxf(v, 0.f);
      op[(size_t)c * 1024] = v;
    }
  }
}

// ---------------------------------------------------------------------------
// conv3/dec1: 3x3 s=1 p=1 ReLU on 32x32 (round-8/9 proven; no spill).
// ---------------------------------------------------------------------------
template<int CIN, int COUT, int CCH>
__global__ __launch_bounds__(256, 4)
void conv3x3_cg(const float* __restrict__ x, const float* __restrict__ w,
                const float* __restrict__ bias, float* __restrict__ out) {
  constexpr int NCH = COUT / CCH;
  int bid = blockIdx.x;
  int cchunk = bid % NCH;
  int n = bid / NCH;
  int co0 = cchunk * CCH;

  __shared__ float xs[4 * 1024];
  __shared__ float wl[4 * 9][CCH];

  int t = threadIdx.x;
  int sx = t & 31;
  int rg = t >> 5;

  float acc[4][CCH];
#pragma unroll
  for (int j = 0; j < 4; j++)
#pragma unroll
    for (int c = 0; c < CCH; c++) acc[j][c] = 0.f;

  const float* xn = x + (size_t)n * CIN * 1024;

  for (int cg = 0; cg < CIN / 4; cg++) {
    __syncthreads();
#pragma unroll
    for (int k = 0; k < 4; k++)
      *(float4*)(xs + k * 1024 + t * 4) =
          *(const float4*)(xn + (size_t)(cg * 4 + k) * 1024 + t * 4);
    for (int i = t; i < 4 * 9 * CCH; i += 256) {
      int cc = i % CCH;
      int row = i / CCH;
      int c4 = row / 9, kk = row % 9;
      wl[row][cc] = w[(size_t)(co0 + cc) * (CIN * 9) + (cg * 4 + c4) * 9 + kk];
    }
    __syncthreads();

#pragma unroll
    for (int c4 = 0; c4 < 4; c4++) {
      const float* xc = xs + c4 * 1024;
      float xv[6][3];
#pragma unroll
      for (int r = 0; r < 6; r++) {
        int iy = 4 * rg - 1 + r;
        bool yok = (unsigned)iy < 32;
#pragma unroll
        for (int cx = 0; cx < 3; cx++) {
          int ix = sx - 1 + cx;
          bool ok = yok && ((unsigned)ix < 32);
          float v = xc[ok ? iy * 32 + ix : 0];
          xv[r][cx] = ok ? v : 0.f;
        }
      }
#pragma unroll
      for (int ky = 0; ky < 3; ky++) {
#pragma unroll
        for (int kx = 0; kx < 3; kx++) {
          const float* wr = &wl[c4 * 9 + ky * 3 + kx][0];
#pragma unroll
          for (int c = 0; c < CCH; c += 4) {
            float4 wv = *(const float4*)(wr + c);
#pragma unroll
            for (int j = 0; j < 4; j++) {
              float xx = xv[j + ky][kx];
              acc[j][c + 0] = fmaf(xx, wv.x, acc[j][c + 0]);
              acc[j][c + 1] = fmaf(xx, wv.y, acc[j][c + 1]);
              acc[j][c + 2] = fmaf(xx, wv.z, acc[j][c + 2]);
              acc[j][c + 3] = fmaf(xx, wv.w, acc[j][c + 3]);
            }
          }
        }
      }
    }
  }

#pragma unroll
  for (int j = 0; j < 4; j++) {
    int sy = 4 * rg + j;
    float* op = out + (((size_t)n * COUT + co0) * 32 + sy) * 32 + sx;
#pragma unroll
    for (int c = 0; c < CCH; c++) {
      float v = acc[j][c] + bias[co0 + c];
      v = fmaxf(v, 0.f);
      op[(size_t)c * 1024] = v;
    }
  }
}

// ---------------------------------------------------------------------------
// dect1 QUAD v2: tconv k=4 s=2 p=1 ReLU, in [n,64,32,32] -> out [n,32,64,64].
// CCH=8 with TWO input positions/thread (rows syl, syl+8 of a 16-row tile):
// weight ds_reads per FMA halved vs round-9 (32 reads / 256 FMA per c4).
// acc[2][2][2][8] = 64 floats (same budget). Chain order per output
// (cg -> c4 -> kyi -> kxi) identical to round-9 -> bitwise-same d2.
// grid = NB * 2 tiles * (COUT/CCH=4).
// ---------------------------------------------------------------------------
template<int CIN, int COUT, int CCH>
__global__ __launch_bounds__(256, 4)
void convt_quad2(const float* __restrict__ x, const float* __restrict__ w,
                 const float* __restrict__ bias, float* __restrict__ out) {
  constexpr int NCH = COUT / CCH;     // 4
  int bid = blockIdx.x;
  int cchunk = bid % NCH;
  int tile = (bid / NCH) & 1;
  int n = bid / (NCH * 2);
  int co0 = cchunk * CCH;
  int y0 = tile * 16;                 // input rows y0..y0+15

  __shared__ float xs[4][18 * 32];    // rows y0-1..y0+16
  __shared__ float wl[4 * 16][CCH];

  int t = threadIdx.x;
  int sx = t & 31;
  int syl = t >> 5;                   // positions: rows y0+syl, y0+syl+8

  float acc[2][2][2][CCH];            // [pos][py][px][c]
#pragma unroll
  for (int p = 0; p < 2; p++)
#pragma unroll
    for (int py = 0; py < 2; py++)
#pragma unroll
      for (int px = 0; px < 2; px++)
#pragma unroll
        for (int c = 0; c < CCH; c++) acc[p][py][px][c] = 0.f;

  const float* xn = x + (size_t)n * CIN * 1024;

  for (int cg = 0; cg < CIN / 4; cg++) {
    __syncthreads();
    for (int idx = t; idx < 4 * 576; idx += 256) {
      int ch = idx / 576;
      int rem = idx % 576;
      int gy = y0 - 1 + rem / 32;
      int col = rem & 31;
      bool ok = (unsigned)gy < 32;
      xs[ch][rem] = ok ? xn[(size_t)(cg * 4 + ch) * 1024 + gy * 32 + col] : 0.f;
    }
    for (int idx = t; idx < 4 * 16 * CCH; idx += 256) {
      int c = idx % CCH;
      int row = idx / CCH;            // c4*16 + kk
      int c4 = row >> 4, kk = row & 15;
      wl[row][c] = w[((size_t)(cg * 4 + c4) * COUT + (co0 + c)) * 16 + kk];
    }
    __syncthreads();

#pragma unroll
    for (int c4 = 0; c4 < 4; c4++) {
      // xv[p][r][cx]: input rows (y0+syl+8p-1+r) -> xs rows (syl+8p+r)
      float xv[2][3][3];
#pragma unroll
      for (int p = 0; p < 2; p++) {
        int rb = syl + p * 8;
#pragma unroll
        for (int r = 0; r < 3; r++) {
#pragma unroll
          for (int cx = 0; cx < 3; cx++) {
            int ix = sx - 1 + cx;
            bool ok = (unsigned)ix < 32;
            float v = xs[c4][(rb + r) * 32 + (ok ? ix : 0)];
            xv[p][r][cx] = ok ? v : 0.f;
          }
        }
      }
#pragma unroll
      for (int py = 0; py < 2; py++) {
        int ky0 = (py + 1) & 1;
        int ay = (py + 1 - ky0) >> 1;
#pragma unroll
        for (int px = 0; px < 2; px++) {
          int kx0 = (px + 1) & 1;
          int ax = (px + 1 - kx0) >> 1;
#pragma unroll
          for (int kyi = 0; kyi < 2; kyi++) {
#pragma unroll
            for (int kxi = 0; kxi < 2; kxi++) {
              int kk = (ky0 + 2 * kyi) * 4 + (kx0 + 2 * kxi);
              const float* wr = &wl[c4 * 16 + kk][0];
              int ri = ay - kyi + 1, ci = ax - kxi + 1;
              float x0 = xv[0][ri][ci];
              float x1 = xv[1][ri][ci];
#pragma unroll
              for (int c = 0; c < CCH; c += 4) {
                float4 wv = *(const float4*)(wr + c);
                acc[0][py][px][c + 0] = fmaf(x0, wv.x, acc[0][py][px][c + 0]);
                acc[0][py][px][c + 1] = fmaf(x0, wv.y, acc[0][py][px][c + 1]);
                acc[0][py][px][c + 2] = fmaf(x0, wv.z, acc[0][py][px][c + 2]);
                acc[0][py][px][c + 3] = fmaf(x0, wv.w, acc[0][py][px][c + 3]);
                acc[1][py][px][c + 0] = fmaf(x1, wv.x, acc[1][py][px][c + 0]);
                acc[1][py][px][c + 1] = fmaf(x1, wv.y, acc[1][py][px][c + 1]);
                acc[1][py][px][c + 2] = fmaf(x1, wv.z, acc[1][py][px][c + 2]);
                acc[1][py][px][c + 3] = fmaf(x1, wv.w, acc[1][py][px][c + 3]);
              }
            }
          }
        }
      }
    }
  }

#pragma unroll
  for (int p = 0; p < 2; p++) {
    int sy = y0 + syl + p * 8;
#pragma unroll
    for (int py = 0; py < 2; py++) {
      int oy = 2 * sy + py;
#pragma unroll
      for (int c = 0; c < CCH; c++) {
        float b = bias[co0 + c];
        float2 o;
        o.x = fmaxf(acc[p][py][0][c] + b, 0.f);
        o.y = fmaxf(acc[p][py][1][c] + b, 0.f);
        *(float2*)(out + ((size_t)(n * COUT + co0 + c) * 64 + oy) * 64 + 2 * sx) = o;
      }
    }
  }
}

// ---------------------------------------------------------------------------
// dect2: tconv k=4 s=2 p=1, CIN=32, COUT=1, sigmoid; all 4 parities per
// thread. CSTG=8 (36.9KB LDS, 4 blocks/CU) -> 4 barrier rounds (was 8).
// grid = NB * 4 row-tiles. in 64x64 -> out 128x128.
// ---------------------------------------------------------------------------
__global__ __launch_bounds__(256, 4)
void dect2_full(const float* __restrict__ x, const float* __restrict__ w,
                const float* __restrict__ bias, float* __restrict__ out) {
  int ptile = blockIdx.x & 3;
  int n = blockIdx.x >> 2;
  int y0 = ptile * 16;

  __shared__ float xs[8][1152];      // rows y0-1..y0+16 (18) x 64 cols
  int t = threadIdx.x;
  int sx = t & 63;
  int r4 = t >> 6;

  float acc[4][4];
#pragma unroll
  for (int j = 0; j < 4; j++)
#pragma unroll
    for (int p = 0; p < 4; p++) acc[j][p] = 0.f;

  const float* xn = x + (size_t)n * 32 * 4096;

  for (int cg = 0; cg < 4; cg++) {   // 8 channels per round
    __syncthreads();
    for (int idx = t; idx < 8 * 1152; idx += 256) {
      int ch = idx / 1152;
      int rem = idx % 1152;
      int iy = y0 - 1 + rem / 64;
      int ix = rem & 63;
      bool ok = (unsigned)iy < 64;
      xs[ch][rem] = ok ? xn[(size_t)(cg * 8 + ch) * 4096 + iy * 64 + ix] : 0.f;
    }
    __syncthreads();

#pragma unroll
    for (int c4 = 0; c4 < 8; c4++) {
      int ci = cg * 8 + c4;
      const float* xc = &xs[c4][0];
      float xv[6][3];
#pragma unroll
      for (int r = 0; r < 6; r++) {
        int srow = 4 * r4 + r;
#pragma unroll
        for (int cx = 0; cx < 3; cx++) {
          int ix = sx - 1 + cx;
          bool ok = (unsigned)ix < 64;
          float v = xc[ok ? srow * 64 + ix : 0];
          xv[r][cx] = ok ? v : 0.f;
        }
      }
      float w16[16];
#pragma unroll
      for (int q = 0; q < 4; q++) {
        float4 ww = *(const float4*)(w + ci * 16 + 4 * q);
        w16[4 * q + 0] = ww.x; w16[4 * q + 1] = ww.y;
        w16[4 * q + 2] = ww.z; w16[4 * q + 3] = ww.w;
      }
#pragma unroll
      for (int py = 0; py < 2; py++) {
#pragma unroll
        for (int px = 0; px < 2; px++) {
          int par = py * 2 + px;
          int ky0 = (py + 1) & 1, kx0 = (px + 1) & 1;
          int ay = (py + 1 - ky0) >> 1;
          int ax = (px + 1 - kx0) >> 1;
#pragma unroll
          for (int kyi = 0; kyi < 2; kyi++) {
#pragma unroll
            for (int kxi = 0; kxi < 2; kxi++) {
              float wv = w16[(ky0 + 2 * kyi) * 4 + (kx0 + 2 * kxi)];
#pragma unroll
              for (int j = 0; j < 4; j++) {
                float xx = xv[j + ay + 1 - kyi][ax + 1 - kxi];
                acc[j][par] = fmaf(xx, wv, acc[j][par]);
              }
            }
          }
        }
      }
    }
  }

  float b0 = bias[0];
#pragma unroll
  for (int j = 0; j < 4; j++) {
    int iy = y0 + 4 * r4 + j;
#pragma unroll
    for (int py = 0; py < 2; py++) {
      float v0 = acc[j][py * 2 + 0] + b0;
      float v1 = acc[j][py * 2 + 1] + b0;
      float2 o;
      o.x = 1.f / (1.f + expf(-v0));
      o.y = 1.f / (1.f + expf(-v1));
      int oy = 2 * iy + py;
      *(float2*)(out + (size_t)n * 16384 + oy * 128 + 2 * sx) = o;
    }
  }
}

// ---------------------------------------------------------------------------
__global__ void cbn_prep(const float* __restrict__ cb, float* __restrict__ cbn) {
#pragma clang fp contract(off)
  int k = blockIdx.x * 256 + threadIdx.x;
  if (k < 512) {
    float m[32];
#pragma unroll
    for (int d = 0; d < 32; d++) {
      float c = cb[k * 32 + d];
      m[d] = c * c;
    }
    float r[8];
#pragma unroll
    for (int j = 0; j < 8; j++)
      r[j] = ((m[j] + m[8 + j]) + m[16 + j]) + m[24 + j];
    cbn[k] = ((r[0] + r[1]) + (r[2] + r[3])) + ((r[4] + r[5]) + (r[6] + r[7]));
  }
}

// ---------------------------------------------------------------------------
// VQ: np-exact arithmetic, 1 px/thread, wave-uniform codebook loads.
// ---------------------------------------------------------------------------
__global__ __launch_bounds__(256)
void vq_kernel(const float* __restrict__ z, const float* __restrict__ cb,
               const float* __restrict__ cbn, float* __restrict__ qz,
               float* __restrict__ loss) {
  int tid = threadIdx.x;
  int n = blockIdx.x >> 2;
  int p = (blockIdx.x & 3) * 256 + tid;
  const float* zn = z + (size_t)n * 32768;

  float zv[32];
#pragma unroll
  for (int d = 0; d < 32; d++) zv[d] = zn[(size_t)d * 1024 + p];

  float zz;
  {
#pragma clang fp contract(off)
    float m[32];
#pragma unroll
    for (int d = 0; d < 32; d++) m[d] = zv[d] * zv[d];
    float r[8];
#pragma unroll
    for (int j = 0; j < 8; j++)
      r[j] = ((m[j] + m[8 + j]) + m[16 + j]) + m[24 + j];
    zz = ((r[0] + r[1]) + (r[2] + r[3])) + ((r[4] + r[5]) + (r[6] + r[7]));
  }

  float best = 3.4e38f;
  int bk = 0;
  for (int k4 = 0; k4 < 512; k4 += 4) {
    float4 cn = *(const float4*)(cbn + k4);
    float da[4];
#pragma unroll
    for (int u = 0; u < 4; u++) da[u] = 0.f;
#pragma unroll
    for (int d = 0; d < 32; d += 4) {
#pragma unroll
      for (int u = 0; u < 4; u++) {
        float4 c = *(const float4*)(cb + (size_t)(k4 + u) * 32 + d);
        float a = da[u];
        a = fmaf(zv[d + 0], c.x, a);
        a = fmaf(zv[d + 1], c.y, a);
        a = fmaf(zv[d + 2], c.z, a);
        a = fmaf(zv[d + 3], c.w, a);
        da[u] = a;
      }
    }
#pragma unroll
    for (int u = 0; u < 4; u++) {
      float cnu = (u == 0) ? cn.x : (u == 1) ? cn.y : (u == 2) ? cn.z : cn.w;
      float s;
      {
#pragma clang fp contract(off)
        s = (zz + cnu) - 2.f * da[u];
      }
      int k = k4 + u;
      if (s < best) { best = s; bk = k; }
    }
  }

  float lsum = 0.f;
  float* qn = qz + (size_t)n * 32768;
#pragma unroll
  for (int d = 0; d < 32; d += 4) {
#pragma clang fp contract(off)
    float4 q = *(const float4*)(cb + (size_t)bk * 32 + d);
    float e;
    e = q.x - zv[d + 0]; lsum = fmaf(e, e, lsum);
    e = q.y - zv[d + 1]; lsum = fmaf(e, e, lsum);
    e = q.z - zv[d + 2]; lsum = fmaf(e, e, lsum);
    e = q.w - zv[d + 3]; lsum = fmaf(e, e, lsum);
    qn[(size_t)(d + 0) * 1024 + p] = zv[d + 0] + (q.x - zv[d + 0]);
    qn[(size_t)(d + 1) * 1024 + p] = zv[d + 1] + (q.y - zv[d + 1]);
    qn[(size_t)(d + 2) * 1024 + p] = zv[d + 2] + (q.z - zv[d + 2]);
    qn[(size_t)(d + 3) * 1024 + p] = zv[d + 3] + (q.w - zv[d + 3]);
  }

#pragma unroll
  for (int off = 32; off; off >>= 1) lsum += __shfl_down(lsum, off, 64);
  if ((tid & 63) == 0) atomicAdd(loss, lsum);
}

__global__ void finalize_loss(const float* __restrict__ loss, float* __restrict__ out) {
  if (threadIdx.x == 0) {
    float m = loss[0] / 8388608.f;
    out[0] = m + 0.26f * m;
  }
}

// ---------------------------------------------------------------------------
// Workspace (floats): A = chunk*131072, B = chunk*65536, cbn 512, loss 1.
// Full batch = 201.3 MB; chunk count from ws_size (constant -> graph-safe).
// ---------------------------------------------------------------------------
extern "C" void kernel_launch(void* const* d_in, const int* in_sizes, int n_in,
                              void* d_out, int out_size, void* d_ws, size_t ws_size,
                              hipStream_t stream) {
  (void)in_sizes; (void)n_in; (void)out_size;
  const float* x   = (const float*)d_in[0];
  const float* ew1 = (const float*)d_in[1];
  const float* eb1 = (const float*)d_in[2];
  const float* ew2 = (const float*)d_in[3];
  const float* eb2 = (const float*)d_in[4];
  const float* ew3 = (const float*)d_in[5];
  const float* eb3 = (const float*)d_in[6];
  const float* ew4 = (const float*)d_in[7];
  const float* eb4 = (const float*)d_in[8];
  const float* cb  = (const float*)d_in[9];
  const float* dw1 = (const float*)d_in[10];
  const float* db1 = (const float*)d_in[11];
  const float* tw1 = (const float*)d_in[12];
  const float* tb1 = (const float*)d_in[13];
  const float* tw2 = (const float*)d_in[14];
  const float* tb2 = (const float*)d_in[15];
  float* out = (float*)d_out;

  auto need = [](size_t c) -> size_t { return (c * 196608 + 513) * 4; };
  int nchunks = 4;
  if (ws_size >= need(256)) nchunks = 1;
  else if (ws_size >= need(128)) nchunks = 2;
  int chunk = 256 / nchunks;

  float* ws = (float*)d_ws;
  float* A = ws;
  float* B = A + (size_t)chunk * 131072;
  float* cbn = B + (size_t)chunk * 65536;
  float* lossacc = cbn + 512;

  float* h1 = A;
  float* h2 = B;
  float* h3 = A;
  float* z  = A + (size_t)chunk * 65536;
  float* qz = A + (size_t)chunk * 98304;
  float* d1 = B;
  float* d2 = A;

  cbn_prep<<<2, 256, 0, stream>>>(cb, cbn);
  (void)hipMemsetAsync(lossacc, 0, 4, stream);

  for (int c = 0; c < nchunks; c++) {
    const float* xc = x + (size_t)c * chunk * 128 * 128;
    float* outc = out + (size_t)c * chunk * 128 * 128;

    conv1_lds<<<chunk * 8, 256, 0, stream>>>(xc, ew1, eb1, h1);
    conv4x4s2_lds<32, 64, 16>
        <<<chunk * 4, 256, 0, stream>>>(h1, ew2, eb2, h2);
    conv3x3_cg<64, 64, 16>
        <<<chunk * 4, 256, 0, stream>>>(h2, ew3, eb3, h3);
    conv_fwd<64, 32, 1, 1, 0, 32, 32, 32, 32, false, 16>
        <<<chunk * 2, 256, 0, stream>>>(h3, ew4, eb4, z);

    vq_kernel<<<chunk * 4, 256, 0, stream>>>(z, cb, cbn, qz, lossacc);

    conv3x3_cg<32, 64, 16>
        <<<chunk * 4, 256, 0, stream>>>(qz, dw1, db1, d1);
    convt_quad2<64, 32, 8>
        <<<chunk * 8, 256, 0, stream>>>(d1, tw1, tb1, d2);
    dect2_full<<<chunk * 4, 256, 0, stream>>>(d2, tw2, tb2, outc);
  }

  finalize_loss<<<1, 64, 0, stream>>>(lossacc, out + 4194304);
}

// Round 11
// 1373.887 us; speedup vs baseline: 2.1724x; 1.0008x over previous
//
#include <hip/hip_runtime.h>
#include <math.h>

// ---------------------------------------------------------------------------
// conv1: 4x4 s=2 p=1 ReLU, CIN=1, 128x128 -> 64x64, 32 ch. Single barrier:
// stage 34-row input slab (17.4KB) + all 16x16 weights (1KB) once.
// Chain order ky -> kx identical to legacy conv_fwd -> h1 bitwise-identical.
// (256,3): VGPR cap ~170 so the 64-float acc never spills.
// grid = NB * 4 row-tiles * 2 co-chunks.
// ---------------------------------------------------------------------------
__global__ __launch_bounds__(256, 3)
void conv1_lds(const float* __restrict__ x, const float* __restrict__ w,
               const float* __restrict__ bias, float* __restrict__ out) {
  int bid = blockIdx.x;
  int cchunk = bid & 1;
  int t4 = (bid >> 1) & 3;
  int n = bid >> 3;
  int co0 = cchunk * 16;
  int y0 = t4 * 16;               // out rows y0..y0+15
  int yi0 = 2 * y0 - 1;           // first input row staged

  __shared__ float xs[34 * 128];
  __shared__ float wl[16][16];    // [tap][co]

  int t = threadIdx.x;
  for (int idx = t; idx < 34 * 128; idx += 256) {
    int gy = yi0 + (idx >> 7);
    int gx = idx & 127;
    bool ok = (unsigned)gy < 128;
    xs[idx] = ok ? x[(size_t)n * 16384 + gy * 128 + gx] : 0.f;
  }
  {
    int cc = t & 15;
    int tap = t >> 4;
    if (t < 256) wl[tap][cc] = w[(size_t)(co0 + cc) * 16 + tap];
  }
  __syncthreads();

  int sx = t & 63;
  int rg = t >> 6;                // rows y0 + 4*rg + j

  float acc[4][16];
#pragma unroll
  for (int j = 0; j < 4; j++)
#pragma unroll
    for (int c = 0; c < 16; c++) acc[j][c] = 0.f;

  int ix0 = 2 * sx - 1;
#pragma unroll
  for (int ky = 0; ky < 4; ky++) {
#pragma unroll
    for (int kx = 0; kx < 4; kx++) {
      int ix = ix0 + kx;
      bool xok = (unsigned)ix < 128;
      float xv[4];
#pragma unroll
      for (int j = 0; j < 4; j++) {
        int lrow = 2 * (4 * rg + j) + ky;   // = (2*oy-1+ky) - yi0
        float v = xs[lrow * 128 + (xok ? ix : 0)];
        xv[j] = xok ? v : 0.f;
      }
      const float* wr = &wl[ky * 4 + kx][0];
#pragma unroll
      for (int c = 0; c < 16; c += 4) {
        float4 wv = *(const float4*)(wr + c);
#pragma unroll
        for (int j = 0; j < 4; j++) {
          acc[j][c + 0] = fmaf(xv[j], wv.x, acc[j][c + 0]);
          acc[j][c + 1] = fmaf(xv[j], wv.y, acc[j][c + 1]);
          acc[j][c + 2] = fmaf(xv[j], wv.z, acc[j][c + 2]);
          acc[j][c + 3] = fmaf(xv[j], wv.w, acc[j][c + 3]);
        }
      }
    }
  }

#pragma unroll
  for (int j = 0; j < 4; j++) {
    int oy = y0 + 4 * rg + j;
    float* op = out + (((size_t)n * 32 + co0) * 64 + oy) * 64 + sx;
#pragma unroll
    for (int c = 0; c < 16; c++) {
      float v = acc[j][c] + bias[co0 + c];
      op[(size_t)c * 4096] = fmaxf(v, 0.f);
    }
  }
}

// ---------------------------------------------------------------------------
// conv2: 4x4 s=2 p=1 ReLU, 64x64 -> 32x32 (round-5/9 proven structure).
// ALL weights staged once (32KB) + 1 input channel per round; (256,3).
// ---------------------------------------------------------------------------
template<int CIN, int COUT, int CCH>
__global__ __launch_bounds__(256, 3)
void conv4x4s2_lds(const float* __restrict__ x, const float* __restrict__ w,
                   const float* __restrict__ bias, float* __restrict__ out) {
  constexpr int NCH = COUT / CCH;
  int bid = blockIdx.x;
  int cchunk = bid % NCH;
  int n = bid / NCH;
  int co0 = cchunk * CCH;

  __shared__ float wl[CIN * 16][CCH];
  __shared__ float xs[4096];
  for (int i = threadIdx.x; i < CIN * 16 * CCH; i += 256) {
    int cc = i % CCH;
    int tap = i / CCH;
    wl[tap][cc] = w[(size_t)(co0 + cc) * (CIN * 16) + tap];
  }

  int t = threadIdx.x;
  int sx = t & 31;
  int sy0 = t >> 5;
  int ix0 = 2 * sx - 1;

  float acc[4][CCH];
#pragma unroll
  for (int j = 0; j < 4; j++)
#pragma unroll
    for (int c = 0; c < CCH; c++) acc[j][c] = 0.f;

  const float* xn = x + (size_t)n * CIN * 4096;

  for (int ci = 0; ci < CIN; ci++) {
    __syncthreads();
#pragma unroll
    for (int k = 0; k < 4; k++)
      *(float4*)(xs + k * 1024 + t * 4) =
          *(const float4*)(xn + (size_t)ci * 4096 + k * 1024 + t * 4);
    __syncthreads();

#pragma unroll
    for (int ky = 0; ky < 4; ky++) {
#pragma unroll
      for (int kx = 0; kx < 4; kx++) {
        int ix = ix0 + kx;
        bool xok = (unsigned)ix < 64;
        float xv[4];
#pragma unroll
        for (int j = 0; j < 4; j++) {
          int iy = 2 * (sy0 + j * 8) - 1 + ky;
          bool ok = xok && ((unsigned)iy < 64);
          float v = xs[ok ? iy * 64 + ix : 0];
          xv[j] = ok ? v : 0.f;
        }
        const float* wr = &wl[ci * 16 + ky * 4 + kx][0];
#pragma unroll
        for (int c = 0; c < CCH; c += 4) {
          float4 wv = *(const float4*)(wr + c);
#pragma unroll
          for (int j = 0; j < 4; j++) {
            acc[j][c + 0] = fmaf(xv[j], wv.x, acc[j][c + 0]);
            acc[j][c + 1] = fmaf(xv[j], wv.y, acc[j][c + 1]);
            acc[j][c + 2] = fmaf(xv[j], wv.z, acc[j][c + 2]);
            acc[j][c + 3] = fmaf(xv[j], wv.w, acc[j][c + 3]);
          }
        }
      }
    }
  }

#pragma unroll
  for (int j = 0; j < 4; j++) {
    int sy = sy0 + j * 8;
    float* op = out + (((size_t)n * COUT + co0) * 32 + sy) * 32 + sx;
#pragma unroll
    for (int c = 0; c < CCH; c++) {
      float v = acc[j][c] + bias[co0 + c];
      v = fmaxf(v, 0.f);
      op[(size_t)c * 1024] = v;
    }
  }
}

// ---------------------------------------------------------------------------
// conv3/dec1: 3x3 s=1 p=1 ReLU on 32x32. 4 input channels (16KB) + weight
// slice (2.25KB) per barrier round. (256,3): VGPR cap ~170 — the (256,4)
// cap of 128 appears to spill the 64-float acc (VGPR_Count 64 + ~10x FETCH
// in round-9/10 counters).
// ---------------------------------------------------------------------------
template<int CIN, int COUT, int CCH>
__global__ __launch_bounds__(256, 3)
void conv3x3_cg(const float* __restrict__ x, const float* __restrict__ w,
                const float* __restrict__ bias, float* __restrict__ out) {
  constexpr int NCH = COUT / CCH;
  int bid = blockIdx.x;
  int cchunk = bid % NCH;
  int n = bid / NCH;
  int co0 = cchunk * CCH;

  __shared__ float xs[4 * 1024];
  __shared__ float wl[4 * 9][CCH];

  int t = threadIdx.x;
  int sx = t & 31;
  int rg = t >> 5;

  float acc[4][CCH];
#pragma unroll
  for (int j = 0; j < 4; j++)
#pragma unroll
    for (int c = 0; c < CCH; c++) acc[j][c] = 0.f;

  const float* xn = x + (size_t)n * CIN * 1024;

  for (int cg = 0; cg < CIN / 4; cg++) {
    __syncthreads();
#pragma unroll
    for (int k = 0; k < 4; k++)
      *(float4*)(xs + k * 1024 + t * 4) =
          *(const float4*)(xn + (size_t)(cg * 4 + k) * 1024 + t * 4);
    for (int i = t; i < 4 * 9 * CCH; i += 256) {
      int cc = i % CCH;
      int row = i / CCH;
      int c4 = row / 9, kk = row % 9;
      wl[row][cc] = w[(size_t)(co0 + cc) * (CIN * 9) + (cg * 4 + c4) * 9 + kk];
    }
    __syncthreads();

#pragma unroll
    for (int c4 = 0; c4 < 4; c4++) {
      const float* xc = xs + c4 * 1024;
      float xv[6][3];
#pragma unroll
      for (int r = 0; r < 6; r++) {
        int iy = 4 * rg - 1 + r;
        bool yok = (unsigned)iy < 32;
#pragma unroll
        for (int cx = 0; cx < 3; cx++) {
          int ix = sx - 1 + cx;
          bool ok = yok && ((unsigned)ix < 32);
          float v = xc[ok ? iy * 32 + ix : 0];
          xv[r][cx] = ok ? v : 0.f;
        }
      }
#pragma unroll
      for (int ky = 0; ky < 3; ky++) {
#pragma unroll
        for (int kx = 0; kx < 3; kx++) {
          const float* wr = &wl[c4 * 9 + ky * 3 + kx][0];
#pragma unroll
          for (int c = 0; c < CCH; c += 4) {
            float4 wv = *(const float4*)(wr + c);
#pragma unroll
            for (int j = 0; j < 4; j++) {
              float xx = xv[j + ky][kx];
              acc[j][c + 0] = fmaf(xx, wv.x, acc[j][c + 0]);
              acc[j][c + 1] = fmaf(xx, wv.y, acc[j][c + 1]);
              acc[j][c + 2] = fmaf(xx, wv.z, acc[j][c + 2]);
              acc[j][c + 3] = fmaf(xx, wv.w, acc[j][c + 3]);
            }
          }
        }
      }
    }
  }

#pragma unroll
  for (int j = 0; j < 4; j++) {
    int sy = 4 * rg + j;
    float* op = out + (((size_t)n * COUT + co0) * 32 + sy) * 32 + sx;
#pragma unroll
    for (int c = 0; c < CCH; c++) {
      float v = acc[j][c] + bias[co0 + c];
      v = fmaxf(v, 0.f);
      op[(size_t)c * 1024] = v;
    }
  }
}

// ---------------------------------------------------------------------------
// dect1 QUAD v2: tconv k=4 s=2 p=1 ReLU, in [n,64,32,32] -> out [n,32,64,64].
// CCH=8, two input positions/thread. (256,3): see spill note above — WRITE
// was 2x output at (256,4).
// grid = NB * 2 tiles * (COUT/CCH=4).
// ---------------------------------------------------------------------------
template<int CIN, int COUT, int CCH>
__global__ __launch_bounds__(256, 3)
void convt_quad2(const float* __restrict__ x, const float* __restrict__ w,
                 const float* __restrict__ bias, float* __restrict__ out) {
  constexpr int NCH = COUT / CCH;     // 4
  int bid = blockIdx.x;
  int cchunk = bid % NCH;
  int tile = (bid / NCH) & 1;
  int n = bid / (NCH * 2);
  int co0 = cchunk * CCH;
  int y0 = tile * 16;                 // input rows y0..y0+15

  __shared__ float xs[4][18 * 32];    // rows y0-1..y0+16
  __shared__ float wl[4 * 16][CCH];

  int t = threadIdx.x;
  int sx = t & 31;
  int syl = t >> 5;                   // positions: rows y0+syl, y0+syl+8

  float acc[2][2][2][CCH];            // [pos][py][px][c]
#pragma unroll
  for (int p = 0; p < 2; p++)
#pragma unroll
    for (int py = 0; py < 2; py++)
#pragma unroll
      for (int px = 0; px < 2; px++)
#pragma unroll
        for (int c = 0; c < CCH; c++) acc[p][py][px][c] = 0.f;

  const float* xn = x + (size_t)n * CIN * 1024;

  for (int cg = 0; cg < CIN / 4; cg++) {
    __syncthreads();
    for (int idx = t; idx < 4 * 576; idx += 256) {
      int ch = idx / 576;
      int rem = idx % 576;
      int gy = y0 - 1 + rem / 32;
      int col = rem & 31;
      bool ok = (unsigned)gy < 32;
      xs[ch][rem] = ok ? xn[(size_t)(cg * 4 + ch) * 1024 + gy * 32 + col] : 0.f;
    }
    for (int idx = t; idx < 4 * 16 * CCH; idx += 256) {
      int c = idx % CCH;
      int row = idx / CCH;            // c4*16 + kk
      int c4 = row >> 4, kk = row & 15;
      wl[row][c] = w[((size_t)(cg * 4 + c4) * COUT + (co0 + c)) * 16 + kk];
    }
    __syncthreads();

#pragma unroll
    for (int c4 = 0; c4 < 4; c4++) {
      float xv[2][3][3];
#pragma unroll
      for (int p = 0; p < 2; p++) {
        int rb = syl + p * 8;
#pragma unroll
        for (int r = 0; r < 3; r++) {
#pragma unroll
          for (int cx = 0; cx < 3; cx++) {
            int ix = sx - 1 + cx;
            bool ok = (unsigned)ix < 32;
            float v = xs[c4][(rb + r) * 32 + (ok ? ix : 0)];
            xv[p][r][cx] = ok ? v : 0.f;
          }
        }
      }
#pragma unroll
      for (int py = 0; py < 2; py++) {
        int ky0 = (py + 1) & 1;
        int ay = (py + 1 - ky0) >> 1;
#pragma unroll
        for (int px = 0; px < 2; px++) {
          int kx0 = (px + 1) & 1;
          int ax = (px + 1 - kx0) >> 1;
#pragma unroll
          for (int kyi = 0; kyi < 2; kyi++) {
#pragma unroll
            for (int kxi = 0; kxi < 2; kxi++) {
              int kk = (ky0 + 2 * kyi) * 4 + (kx0 + 2 * kxi);
              const float* wr = &wl[c4 * 16 + kk][0];
              int ri = ay - kyi + 1, ci = ax - kxi + 1;
              float x0 = xv[0][ri][ci];
              float x1 = xv[1][ri][ci];
#pragma unroll
              for (int c = 0; c < CCH; c += 4) {
                float4 wv = *(const float4*)(wr + c);
                acc[0][py][px][c + 0] = fmaf(x0, wv.x, acc[0][py][px][c + 0]);
                acc[0][py][px][c + 1] = fmaf(x0, wv.y, acc[0][py][px][c + 1]);
                acc[0][py][px][c + 2] = fmaf(x0, wv.z, acc[0][py][px][c + 2]);
                acc[0][py][px][c + 3] = fmaf(x0, wv.w, acc[0][py][px][c + 3]);
                acc[1][py][px][c + 0] = fmaf(x1, wv.x, acc[1][py][px][c + 0]);
                acc[1][py][px][c + 1] = fmaf(x1, wv.y, acc[1][py][px][c + 1]);
                acc[1][py][px][c + 2] = fmaf(x1, wv.z, acc[1][py][px][c + 2]);
                acc[1][py][px][c + 3] = fmaf(x1, wv.w, acc[1][py][px][c + 3]);
              }
            }
          }
        }
      }
    }
  }

#pragma unroll
  for (int p = 0; p < 2; p++) {
    int sy = y0 + syl + p * 8;
#pragma unroll
    for (int py = 0; py < 2; py++) {
      int oy = 2 * sy + py;
#pragma unroll
      for (int c = 0; c < CCH; c++) {
        float b = bias[co0 + c];
        float2 o;
        o.x = fmaxf(acc[p][py][0][c] + b, 0.f);
        o.y = fmaxf(acc[p][py][1][c] + b, 0.f);
        *(float2*)(out + ((size_t)(n * COUT + co0 + c) * 64 + oy) * 64 + 2 * sx) = o;
      }
    }
  }
}

// ---------------------------------------------------------------------------
// dect2: tconv k=4 s=2 p=1, CIN=32, COUT=1, sigmoid; all 4 parities per
// thread. CSTG=8 (36.9KB LDS). grid = NB * 4 row-tiles. 64x64 -> 128x128.
// ---------------------------------------------------------------------------
__global__ __launch_bounds__(256, 4)
void dect2_full(const float* __restrict__ x, const float* __restrict__ w,
                const float* __restrict__ bias, float* __restrict__ out) {
  int ptile = blockIdx.x & 3;
  int n = blockIdx.x >> 2;
  int y0 = ptile * 16;

  __shared__ float xs[8][1152];      // rows y0-1..y0+16 (18) x 64 cols
  int t = threadIdx.x;
  int sx = t & 63;
  int r4 = t >> 6;

  float acc[4][4];
#pragma unroll
  for (int j = 0; j < 4; j++)
#pragma unroll
    for (int p = 0; p < 4; p++) acc[j][p] = 0.f;

  const float* xn = x + (size_t)n * 32 * 4096;

  for (int cg = 0; cg < 4; cg++) {   // 8 channels per round
    __syncthreads();
    for (int idx = t; idx < 8 * 1152; idx += 256) {
      int ch = idx / 1152;
      int rem = idx % 1152;
      int iy = y0 - 1 + rem / 64;
      int ix = rem & 63;
      bool ok = (unsigned)iy < 64;
      xs[ch][rem] = ok ? xn[(size_t)(cg * 8 + ch) * 4096 + iy * 64 + ix] : 0.f;
    }
    __syncthreads();

#pragma unroll
    for (int c4 = 0; c4 < 8; c4++) {
      int ci = cg * 8 + c4;
      const float* xc = &xs[c4][0];
      float xv[6][3];
#pragma unroll
      for (int r = 0; r < 6; r++) {
        int srow = 4 * r4 + r;
#pragma unroll
        for (int cx = 0; cx < 3; cx++) {
          int ix = sx - 1 + cx;
          bool ok = (unsigned)ix < 64;
          float v = xc[ok ? srow * 64 + ix : 0];
          xv[r][cx] = ok ? v : 0.f;
        }
      }
      float w16[16];
#pragma unroll
      for (int q = 0; q < 4; q++) {
        float4 ww = *(const float4*)(w + ci * 16 + 4 * q);
        w16[4 * q + 0] = ww.x; w16[4 * q + 1] = ww.y;
        w16[4 * q + 2] = ww.z; w16[4 * q + 3] = ww.w;
      }
#pragma unroll
      for (int py = 0; py < 2; py++) {
#pragma unroll
        for (int px = 0; px < 2; px++) {
          int par = py * 2 + px;
          int ky0 = (py + 1) & 1, kx0 = (px + 1) & 1;
          int ay = (py + 1 - ky0) >> 1;
          int ax = (px + 1 - kx0) >> 1;
#pragma unroll
          for (int kyi = 0; kyi < 2; kyi++) {
#pragma unroll
            for (int kxi = 0; kxi < 2; kxi++) {
              float wv = w16[(ky0 + 2 * kyi) * 4 + (kx0 + 2 * kxi)];
#pragma unroll
              for (int j = 0; j < 4; j++) {
                float xx = xv[j + ay + 1 - kyi][ax + 1 - kxi];
                acc[j][par] = fmaf(xx, wv, acc[j][par]);
              }
            }
          }
        }
      }
    }
  }

  float b0 = bias[0];
#pragma unroll
  for (int j = 0; j < 4; j++) {
    int iy = y0 + 4 * r4 + j;
#pragma unroll
    for (int py = 0; py < 2; py++) {
      float v0 = acc[j][py * 2 + 0] + b0;
      float v1 = acc[j][py * 2 + 1] + b0;
      float2 o;
      o.x = 1.f / (1.f + expf(-v0));
      o.y = 1.f / (1.f + expf(-v1));
      int oy = 2 * iy + py;
      *(float2*)(out + (size_t)n * 16384 + oy * 128 + 2 * sx) = o;
    }
  }
}

// ---------------------------------------------------------------------------
__global__ void cbn_prep(const float* __restrict__ cb, float* __restrict__ cbn) {
#pragma clang fp contract(off)
  int k = blockIdx.x * 256 + threadIdx.x;
  if (k < 512) {
    float m[32];
#pragma unroll
    for (int d = 0; d < 32; d++) {
      float c = cb[k * 32 + d];
      m[d] = c * c;
    }
    float r[8];
#pragma unroll
    for (int j = 0; j < 8; j++)
      r[j] = ((m[j] + m[8 + j]) + m[16 + j]) + m[24 + j];
    cbn[k] = ((r[0] + r[1]) + (r[2] + r[3])) + ((r[4] + r[5]) + (r[6] + r[7]));
  }
}

// ---------------------------------------------------------------------------
// FUSED conv4 (1x1, 64->32, no relu) + VQ. z computed in registers with the
// EXACT legacy conv_fwd chain (ci -> c, one fmaf per (ci,c); bias add last)
// -> bitwise-identical z -> VQ argmin unchanged. Saves the 67MB z
// round-trip and one launch. VQ part identical to the proven vq_kernel.
// grid = NB * 4; block 256 (1 pixel/thread).
// ---------------------------------------------------------------------------
__global__ __launch_bounds__(256)
void vq_fused(const float* __restrict__ h3, const float* __restrict__ w4,
              const float* __restrict__ b4, const float* __restrict__ cb,
              const float* __restrict__ cbn, float* __restrict__ qz,
              float* __restrict__ loss) {
  __shared__ float wl[64][32];         // [ci][co]
  int tid = threadIdx.x;
  for (int i = tid; i < 2048; i += 256) {
    int co = i & 31;
    int ci = i >> 5;
    wl[ci][co] = w4[(size_t)co * 64 + ci];
  }
  __syncthreads();

  int n = blockIdx.x >> 2;
  int p = (blockIdx.x & 3) * 256 + tid;
  const float* hn = h3 + (size_t)n * 65536;

  // 1x1 conv: z[c] = sum_ci h3[ci] * w[c][ci]  (chain order: ci -> c)
  float zv[32];
#pragma unroll
  for (int c = 0; c < 32; c++) zv[c] = 0.f;
  for (int ci = 0; ci < 64; ci++) {
    float xv = hn[(size_t)ci * 1024 + p];
#pragma unroll
    for (int c = 0; c < 32; c += 4) {
      float4 wv = *(const float4*)&wl[ci][c];
      zv[c + 0] = fmaf(xv, wv.x, zv[c + 0]);
      zv[c + 1] = fmaf(xv, wv.y, zv[c + 1]);
      zv[c + 2] = fmaf(xv, wv.z, zv[c + 2]);
      zv[c + 3] = fmaf(xv, wv.w, zv[c + 3]);
    }
  }
#pragma unroll
  for (int c = 0; c < 32; c++) zv[c] = zv[c] + b4[c];

  // ||z||^2 in numpy pairwise order
  float zz;
  {
#pragma clang fp contract(off)
    float m[32];
#pragma unroll
    for (int d = 0; d < 32; d++) m[d] = zv[d] * zv[d];
    float r[8];
#pragma unroll
    for (int j = 0; j < 8; j++)
      r[j] = ((m[j] + m[8 + j]) + m[16 + j]) + m[24 + j];
    zz = ((r[0] + r[1]) + (r[2] + r[3])) + ((r[4] + r[5]) + (r[6] + r[7]));
  }

  float best = 3.4e38f;
  int bk = 0;
  for (int k4 = 0; k4 < 512; k4 += 4) {
    float4 cn = *(const float4*)(cbn + k4);
    float da[4];
#pragma unroll
    for (int u = 0; u < 4; u++) da[u] = 0.f;
#pragma unroll
    for (int d = 0; d < 32; d += 4) {
#pragma unroll
      for (int u = 0; u < 4; u++) {
        float4 c = *(const float4*)(cb + (size_t)(k4 + u) * 32 + d);
        float a = da[u];
        a = fmaf(zv[d + 0], c.x, a);
        a = fmaf(zv[d + 1], c.y, a);
        a = fmaf(zv[d + 2], c.z, a);
        a = fmaf(zv[d + 3], c.w, a);
        da[u] = a;
      }
    }
#pragma unroll
    for (int u = 0; u < 4; u++) {
      float cnu = (u == 0) ? cn.x : (u == 1) ? cn.y : (u == 2) ? cn.z : cn.w;
      float s;
      {
#pragma clang fp contract(off)
        s = (zz + cnu) - 2.f * da[u];
      }
      int k = k4 + u;
      if (s < best) { best = s; bk = k; }
    }
  }

  float lsum = 0.f;
  float* qn = qz + (size_t)n * 32768;
#pragma unroll
  for (int d = 0; d < 32; d += 4) {
#pragma clang fp contract(off)
    float4 q = *(const float4*)(cb + (size_t)bk * 32 + d);
    float e;
    e = q.x - zv[d + 0]; lsum = fmaf(e, e, lsum);
    e = q.y - zv[d + 1]; lsum = fmaf(e, e, lsum);
    e = q.z - zv[d + 2]; lsum = fmaf(e, e, lsum);
    e = q.w - zv[d + 3]; lsum = fmaf(e, e, lsum);
    qn[(size_t)(d + 0) * 1024 + p] = zv[d + 0] + (q.x - zv[d + 0]);
    qn[(size_t)(d + 1) * 1024 + p] = zv[d + 1] + (q.y - zv[d + 1]);
    qn[(size_t)(d + 2) * 1024 + p] = zv[d + 2] + (q.z - zv[d + 2]);
    qn[(size_t)(d + 3) * 1024 + p] = zv[d + 3] + (q.w - zv[d + 3]);
  }

#pragma unroll
  for (int off = 32; off; off >>= 1) lsum += __shfl_down(lsum, off, 64);
  if ((tid & 63) == 0) atomicAdd(loss, lsum);
}

__global__ void finalize_loss(const float* __restrict__ loss, float* __restrict__ out) {
  if (threadIdx.x == 0) {
    float m = loss[0] / 8388608.f;
    out[0] = m + 0.26f * m;
  }
}

// ---------------------------------------------------------------------------
// Workspace (floats): A = chunk*131072, B = chunk*65536, cbn 512, loss 1.
// Full batch = 201.3 MB; chunk count from ws_size (constant -> graph-safe).
// ---------------------------------------------------------------------------
extern "C" void kernel_launch(void* const* d_in, const int* in_sizes, int n_in,
                              void* d_out, int out_size, void* d_ws, size_t ws_size,
                              hipStream_t stream) {
  (void)in_sizes; (void)n_in; (void)out_size;
  const float* x   = (const float*)d_in[0];
  const float* ew1 = (const float*)d_in[1];
  const float* eb1 = (const float*)d_in[2];
  const float* ew2 = (const float*)d_in[3];
  const float* eb2 = (const float*)d_in[4];
  const float* ew3 = (const float*)d_in[5];
  const float* eb3 = (const float*)d_in[6];
  const float* ew4 = (const float*)d_in[7];
  const float* eb4 = (const float*)d_in[8];
  const float* cb  = (const float*)d_in[9];
  const float* dw1 = (const float*)d_in[10];
  const float* db1 = (const float*)d_in[11];
  const float* tw1 = (const float*)d_in[12];
  const float* tb1 = (const float*)d_in[13];
  const float* tw2 = (const float*)d_in[14];
  const float* tb2 = (const float*)d_in[15];
  float* out = (float*)d_out;

  auto need = [](size_t c) -> size_t { return (c * 196608 + 513) * 4; };
  int nchunks = 4;
  if (ws_size >= need(256)) nchunks = 1;
  else if (ws_size >= need(128)) nchunks = 2;
  int chunk = 256 / nchunks;

  float* ws = (float*)d_ws;
  float* A = ws;
  float* B = A + (size_t)chunk * 131072;
  float* cbn = B + (size_t)chunk * 65536;
  float* lossacc = cbn + 512;

  float* h1 = A;
  float* h2 = B;
  float* h3 = A;
  float* qz = A + (size_t)chunk * 98304;
  float* d1 = B;
  float* d2 = A;

  cbn_prep<<<2, 256, 0, stream>>>(cb, cbn);
  (void)hipMemsetAsync(lossacc, 0, 4, stream);

  for (int c = 0; c < nchunks; c++) {
    const float* xc = x + (size_t)c * chunk * 128 * 128;
    float* outc = out + (size_t)c * chunk * 128 * 128;

    conv1_lds<<<chunk * 8, 256, 0, stream>>>(xc, ew1, eb1, h1);
    conv4x4s2_lds<32, 64, 16>
        <<<chunk * 4, 256, 0, stream>>>(h1, ew2, eb2, h2);
    conv3x3_cg<64, 64, 16>
        <<<chunk * 4, 256, 0, stream>>>(h2, ew3, eb3, h3);

    vq_fused<<<chunk * 4, 256, 0, stream>>>(h3, ew4, eb4, cb, cbn, qz, lossacc);

    conv3x3_cg<32, 64, 16>
        <<<chunk * 4, 256, 0, stream>>>(qz, dw1, db1, d1);
    convt_quad2<64, 32, 8>
        <<<chunk * 8, 256, 0, stream>>>(d1, tw1, tb1, d2);
    dect2_full<<<chunk * 4, 256, 0, stream>>>(d2, tw2, tb2, outc);
  }

  finalize_loss<<<1, 64, 0, stream>>>(lossacc, out + 4194304);
}

// Round 12
// 1174.962 us; speedup vs baseline: 2.5402x; 1.1693x over previous
//
#include <hip/hip_runtime.h>
#include <math.h>

typedef __attribute__((ext_vector_type(8))) short short8;
typedef __attribute__((ext_vector_type(4))) float f32x4;

__device__ inline unsigned short f2bf(float f) {
  unsigned u = __float_as_uint(f);
  u = (u + 0x7fffu + ((u >> 16) & 1u)) >> 16;
  return (unsigned short)u;
}

// ---------------------------------------------------------------------------
// conv1: 4x4 s=2 p=1 ReLU, CIN=1, 128x128 -> 64x64, 32 ch. Single barrier.
// ---------------------------------------------------------------------------
__global__ __launch_bounds__(256, 3)
void conv1_lds(const float* __restrict__ x, const float* __restrict__ w,
               const float* __restrict__ bias, float* __restrict__ out) {
  int bid = blockIdx.x;
  int cchunk = bid & 1;
  int t4 = (bid >> 1) & 3;
  int n = bid >> 3;
  int co0 = cchunk * 16;
  int y0 = t4 * 16;
  int yi0 = 2 * y0 - 1;

  __shared__ float xs[34 * 128];
  __shared__ float wl[16][16];

  int t = threadIdx.x;
  for (int idx = t; idx < 34 * 128; idx += 256) {
    int gy = yi0 + (idx >> 7);
    int gx = idx & 127;
    bool ok = (unsigned)gy < 128;
    xs[idx] = ok ? x[(size_t)n * 16384 + gy * 128 + gx] : 0.f;
  }
  {
    int cc = t & 15;
    int tap = t >> 4;
    if (t < 256) wl[tap][cc] = w[(size_t)(co0 + cc) * 16 + tap];
  }
  __syncthreads();

  int sx = t & 63;
  int rg = t >> 6;

  float acc[4][16];
#pragma unroll
  for (int j = 0; j < 4; j++)
#pragma unroll
    for (int c = 0; c < 16; c++) acc[j][c] = 0.f;

  int ix0 = 2 * sx - 1;
#pragma unroll
  for (int ky = 0; ky < 4; ky++) {
#pragma unroll
    for (int kx = 0; kx < 4; kx++) {
      int ix = ix0 + kx;
      bool xok = (unsigned)ix < 128;
      float xv[4];
#pragma unroll
      for (int j = 0; j < 4; j++) {
        int lrow = 2 * (4 * rg + j) + ky;
        float v = xs[lrow * 128 + (xok ? ix : 0)];
        xv[j] = xok ? v : 0.f;
      }
      const float* wr = &wl[ky * 4 + kx][0];
#pragma unroll
      for (int c = 0; c < 16; c += 4) {
        float4 wv = *(const float4*)(wr + c);
#pragma unroll
        for (int j = 0; j < 4; j++) {
          acc[j][c + 0] = fmaf(xv[j], wv.x, acc[j][c + 0]);
          acc[j][c + 1] = fmaf(xv[j], wv.y, acc[j][c + 1]);
          acc[j][c + 2] = fmaf(xv[j], wv.z, acc[j][c + 2]);
          acc[j][c + 3] = fmaf(xv[j], wv.w, acc[j][c + 3]);
        }
      }
    }
  }

#pragma unroll
  for (int j = 0; j < 4; j++) {
    int oy = y0 + 4 * rg + j;
    float* op = out + (((size_t)n * 32 + co0) * 64 + oy) * 64 + sx;
#pragma unroll
    for (int c = 0; c < 16; c++) {
      float v = acc[j][c] + bias[co0 + c];
      op[(size_t)c * 4096] = fmaxf(v, 0.f);
    }
  }
}

// ---------------------------------------------------------------------------
// conv2: 4x4 s=2 p=1 ReLU, 64x64 -> 32x32 (proven structure).
// ---------------------------------------------------------------------------
template<int CIN, int COUT, int CCH>
__global__ __launch_bounds__(256, 3)
void conv4x4s2_lds(const float* __restrict__ x, const float* __restrict__ w,
                   const float* __restrict__ bias, float* __restrict__ out) {
  constexpr int NCH = COUT / CCH;
  int bid = blockIdx.x;
  int cchunk = bid % NCH;
  int n = bid / NCH;
  int co0 = cchunk * CCH;

  __shared__ float wl[CIN * 16][CCH];
  __shared__ float xs[4096];
  for (int i = threadIdx.x; i < CIN * 16 * CCH; i += 256) {
    int cc = i % CCH;
    int tap = i / CCH;
    wl[tap][cc] = w[(size_t)(co0 + cc) * (CIN * 16) + tap];
  }

  int t = threadIdx.x;
  int sx = t & 31;
  int sy0 = t >> 5;
  int ix0 = 2 * sx - 1;

  float acc[4][CCH];
#pragma unroll
  for (int j = 0; j < 4; j++)
#pragma unroll
    for (int c = 0; c < CCH; c++) acc[j][c] = 0.f;

  const float* xn = x + (size_t)n * CIN * 4096;

  for (int ci = 0; ci < CIN; ci++) {
    __syncthreads();
#pragma unroll
    for (int k = 0; k < 4; k++)
      *(float4*)(xs + k * 1024 + t * 4) =
          *(const float4*)(xn + (size_t)ci * 4096 + k * 1024 + t * 4);
    __syncthreads();

#pragma unroll
    for (int ky = 0; ky < 4; ky++) {
#pragma unroll
      for (int kx = 0; kx < 4; kx++) {
        int ix = ix0 + kx;
        bool xok = (unsigned)ix < 64;
        float xv[4];
#pragma unroll
        for (int j = 0; j < 4; j++) {
          int iy = 2 * (sy0 + j * 8) - 1 + ky;
          bool ok = xok && ((unsigned)iy < 64);
          float v = xs[ok ? iy * 64 + ix : 0];
          xv[j] = ok ? v : 0.f;
        }
        const float* wr = &wl[ci * 16 + ky * 4 + kx][0];
#pragma unroll
        for (int c = 0; c < CCH; c += 4) {
          float4 wv = *(const float4*)(wr + c);
#pragma unroll
          for (int j = 0; j < 4; j++) {
            acc[j][c + 0] = fmaf(xv[j], wv.x, acc[j][c + 0]);
            acc[j][c + 1] = fmaf(xv[j], wv.y, acc[j][c + 1]);
            acc[j][c + 2] = fmaf(xv[j], wv.z, acc[j][c + 2]);
            acc[j][c + 3] = fmaf(xv[j], wv.w, acc[j][c + 3]);
          }
        }
      }
    }
  }

#pragma unroll
  for (int j = 0; j < 4; j++) {
    int sy = sy0 + j * 8;
    float* op = out + (((size_t)n * COUT + co0) * 32 + sy) * 32 + sx;
#pragma unroll
    for (int c = 0; c < CCH; c++) {
      float v = acc[j][c] + bias[co0 + c];
      v = fmaxf(v, 0.f);
      op[(size_t)c * 1024] = v;
    }
  }
}

// ---------------------------------------------------------------------------
// conv3/dec1: 3x3 s=1 p=1 ReLU on 32x32 (proven; (256,3) no-spill).
// ---------------------------------------------------------------------------
template<int CIN, int COUT, int CCH>
__global__ __launch_bounds__(256, 3)
void conv3x3_cg(const float* __restrict__ x, const float* __restrict__ w,
                const float* __restrict__ bias, float* __restrict__ out) {
  constexpr int NCH = COUT / CCH;
  int bid = blockIdx.x;
  int cchunk = bid % NCH;
  int n = bid / NCH;
  int co0 = cchunk * CCH;

  __shared__ float xs[4 * 1024];
  __shared__ float wl[4 * 9][CCH];

  int t = threadIdx.x;
  int sx = t & 31;
  int rg = t >> 5;

  float acc[4][CCH];
#pragma unroll
  for (int j = 0; j < 4; j++)
#pragma unroll
    for (int c = 0; c < CCH; c++) acc[j][c] = 0.f;

  const float* xn = x + (size_t)n * CIN * 1024;

  for (int cg = 0; cg < CIN / 4; cg++) {
    __syncthreads();
#pragma unroll
    for (int k = 0; k < 4; k++)
      *(float4*)(xs + k * 1024 + t * 4) =
          *(const float4*)(xn + (size_t)(cg * 4 + k) * 1024 + t * 4);
    for (int i = t; i < 4 * 9 * CCH; i += 256) {
      int cc = i % CCH;
      int row = i / CCH;
      int c4 = row / 9, kk = row % 9;
      wl[row][cc] = w[(size_t)(co0 + cc) * (CIN * 9) + (cg * 4 + c4) * 9 + kk];
    }
    __syncthreads();

#pragma unroll
    for (int c4 = 0; c4 < 4; c4++) {
      const float* xc = xs + c4 * 1024;
      float xv[6][3];
#pragma unroll
      for (int r = 0; r < 6; r++) {
        int iy = 4 * rg - 1 + r;
        bool yok = (unsigned)iy < 32;
#pragma unroll
        for (int cx = 0; cx < 3; cx++) {
          int ix = sx - 1 + cx;
          bool ok = yok && ((unsigned)ix < 32);
          float v = xc[ok ? iy * 32 + ix : 0];
          xv[r][cx] = ok ? v : 0.f;
        }
      }
#pragma unroll
      for (int ky = 0; ky < 3; ky++) {
#pragma unroll
        for (int kx = 0; kx < 3; kx++) {
          const float* wr = &wl[c4 * 9 + ky * 3 + kx][0];
#pragma unroll
          for (int c = 0; c < CCH; c += 4) {
            float4 wv = *(const float4*)(wr + c);
#pragma unroll
            for (int j = 0; j < 4; j++) {
              float xx = xv[j + ky][kx];
              acc[j][c + 0] = fmaf(xx, wv.x, acc[j][c + 0]);
              acc[j][c + 1] = fmaf(xx, wv.y, acc[j][c + 1]);
              acc[j][c + 2] = fmaf(xx, wv.z, acc[j][c + 2]);
              acc[j][c + 3] = fmaf(xx, wv.w, acc[j][c + 3]);
            }
          }
        }
      }
    }
  }

#pragma unroll
  for (int j = 0; j < 4; j++) {
    int sy = 4 * rg + j;
    float* op = out + (((size_t)n * COUT + co0) * 32 + sy) * 32 + sx;
#pragma unroll
    for (int c = 0; c < CCH; c++) {
      float v = acc[j][c] + bias[co0 + c];
      v = fmaxf(v, 0.f);
      op[(size_t)c * 1024] = v;
    }
  }
}

// ---------------------------------------------------------------------------
// Weight prep for MFMA dect1: tw1 [ci=64][co=32][4][4] fp32 ->
// Bws bf16 [par=4][tap=4][co=32][ci=64]; tap=(kyi,kxi), ky=ky0+2kyi etc.
// ---------------------------------------------------------------------------
__global__ void wprep_dect1(const float* __restrict__ tw1,
                            unsigned short* __restrict__ Bws) {
  int i = blockIdx.x * 256 + threadIdx.x;
  if (i < 32768) {
    int ci = i & 63;
    int co = (i >> 6) & 31;
    int tap = (i >> 11) & 3;
    int par = i >> 13;
    int py = par >> 1, px = par & 1;
    int ky0 = (py + 1) & 1, kx0 = (px + 1) & 1;
    int kyi = tap >> 1, kxi = tap & 1;
    int ky = ky0 + 2 * kyi, kx = kx0 + 2 * kxi;
    Bws[i] = f2bf(tw1[(((size_t)ci * 32 + co) * 4 + ky) * 4 + kx]);
  }
}

// ---------------------------------------------------------------------------
// dect1 via MFMA (bf16 in, fp32 acc): tconv k=4 s=2 p=1 ReLU,
// d1 [smp][64ci][32][32] fp32 -> d2 [smp][32co][64][64] fp32.
// Per parity: GEMM D[m=pos][n=co] = sum_{tap,ci} A[m+shift][ci] * B[k][n].
// A staged in LDS as [row4][col34][ci(72 pad)] bf16 (halo zero-padded, 16B-
// aligned b128 frags). B from L2-hot prepacked Bws (16B global loads).
// Frag layouts (guide-verified): A[m=lane&15][k=(lane>>4)*8+j],
// B[n=lane&15][k=...], D col=lane&15 row=(lane>>4)*4+reg.
// Block = 256 thr = 4 waves: sample smp, row-pair rp (rows 2rp,2rp+1);
// wave w: positions row 2rp+(w>>1), cols (w&1)*16 .. +15. grid = NB*16.
// ---------------------------------------------------------------------------
__global__ __launch_bounds__(256, 3)
void convt_mfma(const float* __restrict__ d1,
                const unsigned short* __restrict__ Bws,
                const float* __restrict__ bias, float* __restrict__ d2) {
  constexpr int CP = 72;             // padded ci stride (144B = 9*16B)
  int bid = blockIdx.x;
  int rp = bid & 15;
  int smp = bid >> 4;

  __shared__ __align__(16) unsigned short xt[4 * 34 * CP];

  int t = threadIdx.x;

  // stage: rows 2rp-1..2rp+2, cols -1..32, all 64 ci (bf16, packed pairs)
  for (int idx = t; idx < 32 * 4 * 34; idx += 256) {
    int cc = idx % 34;
    int tmp = idx / 34;
    int rr = tmp & 3;
    int pp = tmp >> 2;                // ci pair 0..31
    int gy = 2 * rp - 1 + rr;
    int gx = cc - 1;
    bool ok = ((unsigned)gy < 32) && ((unsigned)gx < 32);
    const float* p = d1 + ((size_t)smp * 64 + 2 * pp) * 1024 + gy * 32 + gx;
    float v0 = ok ? p[0] : 0.f;
    float v1 = ok ? p[1024] : 0.f;
    unsigned pk = (unsigned)f2bf(v0) | ((unsigned)f2bf(v1) << 16);
    *(unsigned*)(&xt[(rr * 34 + cc) * CP + 2 * pp]) = pk;
  }
  __syncthreads();

  int lane = t & 63;
  int wv = t >> 6;
  int row2 = wv >> 1;                // 0/1
  int c0 = (wv & 1) * 16;
  int mlo = lane & 15;               // m for A / n for B / col for D
  int khi = lane >> 4;               // quad

  f32x4 acc[4][2];
#pragma unroll
  for (int par = 0; par < 4; par++)
#pragma unroll
    for (int nt = 0; nt < 2; nt++) {
      f32x4 z = {0.f, 0.f, 0.f, 0.f};
      acc[par][nt] = z;
    }

#pragma unroll
  for (int par = 0; par < 4; par++) {
    int py = par >> 1, px = par & 1;
    int ky0 = (py + 1) & 1, kx0 = (px + 1) & 1;
    int ay = (py + 1 - ky0) >> 1;
    int ax = (px + 1 - kx0) >> 1;
#pragma unroll
    for (int tap = 0; tap < 4; tap++) {
      int kyi = tap >> 1, kxi = tap & 1;
      int rrp = row2 + 1 + (ay - kyi);          // 0..3
      int ccb = c0 + 1 + (ax - kxi);            // + mlo per lane
#pragma unroll
      for (int kc = 0; kc < 2; kc++) {
        const unsigned short* ap =
            xt + ((rrp * 34) + ccb + mlo) * CP + kc * 32 + khi * 8;
        short8 a = *(const short8*)ap;
#pragma unroll
        for (int nt = 0; nt < 2; nt++) {
          const unsigned short* bp =
              Bws + (((size_t)(par * 4 + tap) * 32 + nt * 16 + mlo) * 64) +
              kc * 32 + khi * 8;
          short8 b = *(const short8*)bp;
          acc[par][nt] =
              __builtin_amdgcn_mfma_f32_16x16x32_bf16(a, b, acc[par][nt], 0, 0, 0);
        }
      }
    }
  }

  int sy = 2 * rp + row2;
#pragma unroll
  for (int par = 0; par < 4; par++) {
    int py = par >> 1, px = par & 1;
    int oy = 2 * sy + py;
#pragma unroll
    for (int nt = 0; nt < 2; nt++) {
      int co = nt * 16 + mlo;
      float b = bias[co];
      float* op = d2 + (((size_t)smp * 32 + co) * 64 + oy) * 64;
#pragma unroll
      for (int r = 0; r < 4; r++) {
        int sx = c0 + khi * 4 + r;
        int ox = 2 * sx + px;
        op[ox] = fmaxf(acc[par][nt][r] + b, 0.f);
      }
    }
  }
}

// ---------------------------------------------------------------------------
// dect2: tconv k=4 s=2 p=1, CIN=32, COUT=1, sigmoid; all 4 parities per
// thread. CSTG=8 (36.9KB LDS). grid = NB * 4 row-tiles. 64x64 -> 128x128.
// ---------------------------------------------------------------------------
__global__ __launch_bounds__(256, 4)
void dect2_full(const float* __restrict__ x, const float* __restrict__ w,
                const float* __restrict__ bias, float* __restrict__ out) {
  int ptile = blockIdx.x & 3;
  int n = blockIdx.x >> 2;
  int y0 = ptile * 16;

  __shared__ float xs[8][1152];
  int t = threadIdx.x;
  int sx = t & 63;
  int r4 = t >> 6;

  float acc[4][4];
#pragma unroll
  for (int j = 0; j < 4; j++)
#pragma unroll
    for (int p = 0; p < 4; p++) acc[j][p] = 0.f;

  const float* xn = x + (size_t)n * 32 * 4096;

  for (int cg = 0; cg < 4; cg++) {
    __syncthreads();
    for (int idx = t; idx < 8 * 1152; idx += 256) {
      int ch = idx / 1152;
      int rem = idx % 1152;
      int iy = y0 - 1 + rem / 64;
      int ix = rem & 63;
      bool ok = (unsigned)iy < 64;
      xs[ch][rem] = ok ? xn[(size_t)(cg * 8 + ch) * 4096 + iy * 64 + ix] : 0.f;
    }
    __syncthreads();

#pragma unroll
    for (int c4 = 0; c4 < 8; c4++) {
      int ci = cg * 8 + c4;
      const float* xc = &xs[c4][0];
      float xv[6][3];
#pragma unroll
      for (int r = 0; r < 6; r++) {
        int srow = 4 * r4 + r;
#pragma unroll
        for (int cx = 0; cx < 3; cx++) {
          int ix = sx - 1 + cx;
          bool ok = (unsigned)ix < 64;
          float v = xc[ok ? srow * 64 + ix : 0];
          xv[r][cx] = ok ? v : 0.f;
        }
      }
      float w16[16];
#pragma unroll
      for (int q = 0; q < 4; q++) {
        float4 ww = *(const float4*)(w + ci * 16 + 4 * q);
        w16[4 * q + 0] = ww.x; w16[4 * q + 1] = ww.y;
        w16[4 * q + 2] = ww.z; w16[4 * q + 3] = ww.w;
      }
#pragma unroll
      for (int py = 0; py < 2; py++) {
#pragma unroll
        for (int px = 0; px < 2; px++) {
          int par = py * 2 + px;
          int ky0 = (py + 1) & 1, kx0 = (px + 1) & 1;
          int ay = (py + 1 - ky0) >> 1;
          int ax = (px + 1 - kx0) >> 1;
#pragma unroll
          for (int kyi = 0; kyi < 2; kyi++) {
#pragma unroll
            for (int kxi = 0; kxi < 2; kxi++) {
              float wv = w16[(ky0 + 2 * kyi) * 4 + (kx0 + 2 * kxi)];
#pragma unroll
              for (int j = 0; j < 4; j++) {
                float xx = xv[j + ay + 1 - kyi][ax + 1 - kxi];
                acc[j][par] = fmaf(xx, wv, acc[j][par]);
              }
            }
          }
        }
      }
    }
  }

  float b0 = bias[0];
#pragma unroll
  for (int j = 0; j < 4; j++) {
    int iy = y0 + 4 * r4 + j;
#pragma unroll
    for (int py = 0; py < 2; py++) {
      float v0 = acc[j][py * 2 + 0] + b0;
      float v1 = acc[j][py * 2 + 1] + b0;
      float2 o;
      o.x = 1.f / (1.f + expf(-v0));
      o.y = 1.f / (1.f + expf(-v1));
      int oy = 2 * iy + py;
      *(float2*)(out + (size_t)n * 16384 + oy * 128 + 2 * sx) = o;
    }
  }
}

// ---------------------------------------------------------------------------
__global__ void cbn_prep(const float* __restrict__ cb, float* __restrict__ cbn) {
#pragma clang fp contract(off)
  int k = blockIdx.x * 256 + threadIdx.x;
  if (k < 512) {
    float m[32];
#pragma unroll
    for (int d = 0; d < 32; d++) {
      float c = cb[k * 32 + d];
      m[d] = c * c;
    }
    float r[8];
#pragma unroll
    for (int j = 0; j < 8; j++)
      r[j] = ((m[j] + m[8 + j]) + m[16 + j]) + m[24 + j];
    cbn[k] = ((r[0] + r[1]) + (r[2] + r[3])) + ((r[4] + r[5]) + (r[6] + r[7]));
  }
}

// ---------------------------------------------------------------------------
// FUSED conv4 (1x1) + VQ (np-exact arithmetic; proven).
// ---------------------------------------------------------------------------
__global__ __launch_bounds__(256)
void vq_fused(const float* __restrict__ h3, const float* __restrict__ w4,
              const float* __restrict__ b4, const float* __restrict__ cb,
              const float* __restrict__ cbn, float* __restrict__ qz,
              float* __restrict__ loss) {
  __shared__ float wl[64][32];
  int tid = threadIdx.x;
  for (int i = tid; i < 2048; i += 256) {
    int co = i & 31;
    int ci = i >> 5;
    wl[ci][co] = w4[(size_t)co * 64 + ci];
  }
  __syncthreads();

  int n = blockIdx.x >> 2;
  int p = (blockIdx.x & 3) * 256 + tid;
  const float* hn = h3 + (size_t)n * 65536;

  float zv[32];
#pragma unroll
  for (int c = 0; c < 32; c++) zv[c] = 0.f;
  for (int ci = 0; ci < 64; ci++) {
    float xv = hn[(size_t)ci * 1024 + p];
#pragma unroll
    for (int c = 0; c < 32; c += 4) {
      float4 wv = *(const float4*)&wl[ci][c];
      zv[c + 0] = fmaf(xv, wv.x, zv[c + 0]);
      zv[c + 1] = fmaf(xv, wv.y, zv[c + 1]);
      zv[c + 2] = fmaf(xv, wv.z, zv[c + 2]);
      zv[c + 3] = fmaf(xv, wv.w, zv[c + 3]);
    }
  }
#pragma unroll
  for (int c = 0; c < 32; c++) zv[c] = zv[c] + b4[c];

  float zz;
  {
#pragma clang fp contract(off)
    float m[32];
#pragma unroll
    for (int d = 0; d < 32; d++) m[d] = zv[d] * zv[d];
    float r[8];
#pragma unroll
    for (int j = 0; j < 8; j++)
      r[j] = ((m[j] + m[8 + j]) + m[16 + j]) + m[24 + j];
    zz = ((r[0] + r[1]) + (r[2] + r[3])) + ((r[4] + r[5]) + (r[6] + r[7]));
  }

  float best = 3.4e38f;
  int bk = 0;
  for (int k4 = 0; k4 < 512; k4 += 4) {
    float4 cn = *(const float4*)(cbn + k4);
    float da[4];
#pragma unroll
    for (int u = 0; u < 4; u++) da[u] = 0.f;
#pragma unroll
    for (int d = 0; d < 32; d += 4) {
#pragma unroll
      for (int u = 0; u < 4; u++) {
        float4 c = *(const float4*)(cb + (size_t)(k4 + u) * 32 + d);
        float a = da[u];
        a = fmaf(zv[d + 0], c.x, a);
        a = fmaf(zv[d + 1], c.y, a);
        a = fmaf(zv[d + 2], c.z, a);
        a = fmaf(zv[d + 3], c.w, a);
        da[u] = a;
      }
    }
#pragma unroll
    for (int u = 0; u < 4; u++) {
      float cnu = (u == 0) ? cn.x : (u == 1) ? cn.y : (u == 2) ? cn.z : cn.w;
      float s;
      {
#pragma clang fp contract(off)
        s = (zz + cnu) - 2.f * da[u];
      }
      int k = k4 + u;
      if (s < best) { best = s; bk = k; }
    }
  }

  float lsum = 0.f;
  float* qn = qz + (size_t)n * 32768;
#pragma unroll
  for (int d = 0; d < 32; d += 4) {
#pragma clang fp contract(off)
    float4 q = *(const float4*)(cb + (size_t)bk * 32 + d);
    float e;
    e = q.x - zv[d + 0]; lsum = fmaf(e, e, lsum);
    e = q.y - zv[d + 1]; lsum = fmaf(e, e, lsum);
    e = q.z - zv[d + 2]; lsum = fmaf(e, e, lsum);
    e = q.w - zv[d + 3]; lsum = fmaf(e, e, lsum);
    qn[(size_t)(d + 0) * 1024 + p] = zv[d + 0] + (q.x - zv[d + 0]);
    qn[(size_t)(d + 1) * 1024 + p] = zv[d + 1] + (q.y - zv[d + 1]);
    qn[(size_t)(d + 2) * 1024 + p] = zv[d + 2] + (q.z - zv[d + 2]);
    qn[(size_t)(d + 3) * 1024 + p] = zv[d + 3] + (q.w - zv[d + 3]);
  }

#pragma unroll
  for (int off = 32; off; off >>= 1) lsum += __shfl_down(lsum, off, 64);
  if ((tid & 63) == 0) atomicAdd(loss, lsum);
}

__global__ void finalize_loss(const float* __restrict__ loss, float* __restrict__ out) {
  if (threadIdx.x == 0) {
    float m = loss[0] / 8388608.f;
    out[0] = m + 0.26f * m;
  }
}

// ---------------------------------------------------------------------------
// Workspace (floats): A = chunk*131072, B = chunk*65536, cbn 512, loss 1,
// pad 3, Bws 16384 (64KB bf16 dect1 weights, 16B-aligned).
// ---------------------------------------------------------------------------
extern "C" void kernel_launch(void* const* d_in, const int* in_sizes, int n_in,
                              void* d_out, int out_size, void* d_ws, size_t ws_size,
                              hipStream_t stream) {
  (void)in_sizes; (void)n_in; (void)out_size;
  const float* x   = (const float*)d_in[0];
  const float* ew1 = (const float*)d_in[1];
  const float* eb1 = (const float*)d_in[2];
  const float* ew2 = (const float*)d_in[3];
  const float* eb2 = (const float*)d_in[4];
  const float* ew3 = (const float*)d_in[5];
  const float* eb3 = (const float*)d_in[6];
  const float* ew4 = (const float*)d_in[7];
  const float* eb4 = (const float*)d_in[8];
  const float* cb  = (const float*)d_in[9];
  const float* dw1 = (const float*)d_in[10];
  const float* db1 = (const float*)d_in[11];
  const float* tw1 = (const float*)d_in[12];
  const float* tb1 = (const float*)d_in[13];
  const float* tw2 = (const float*)d_in[14];
  const float* tb2 = (const float*)d_in[15];
  float* out = (float*)d_out;

  auto need = [](size_t c) -> size_t { return (c * 196608 + 516 + 16384) * 4; };
  int nchunks = 4;
  if (ws_size >= need(256)) nchunks = 1;
  else if (ws_size >= need(128)) nchunks = 2;
  int chunk = 256 / nchunks;

  float* ws = (float*)d_ws;
  float* A = ws;
  float* B = A + (size_t)chunk * 131072;
  float* cbn = B + (size_t)chunk * 65536;
  float* lossacc = cbn + 512;
  unsigned short* Bws = (unsigned short*)(cbn + 516);  // 16B-aligned

  float* h1 = A;
  float* h2 = B;
  float* h3 = A;
  float* qz = A + (size_t)chunk * 98304;
  float* d1 = B;
  float* d2 = A;

  cbn_prep<<<2, 256, 0, stream>>>(cb, cbn);
  wprep_dect1<<<128, 256, 0, stream>>>(tw1, Bws);
  (void)hipMemsetAsync(lossacc, 0, 4, stream);

  for (int c = 0; c < nchunks; c++) {
    const float* xc = x + (size_t)c * chunk * 128 * 128;
    float* outc = out + (size_t)c * chunk * 128 * 128;

    conv1_lds<<<chunk * 8, 256, 0, stream>>>(xc, ew1, eb1, h1);
    conv4x4s2_lds<32, 64, 16>
        <<<chunk * 4, 256, 0, stream>>>(h1, ew2, eb2, h2);
    conv3x3_cg<64, 64, 16>
        <<<chunk * 4, 256, 0, stream>>>(h2, ew3, eb3, h3);

    vq_fused<<<chunk * 4, 256, 0, stream>>>(h3, ew4, eb4, cb, cbn, qz, lossacc);

    conv3x3_cg<32, 64, 16>
        <<<chunk * 4, 256, 0, stream>>>(qz, dw1, db1, d1);
    convt_mfma<<<chunk * 16, 256, 0, stream>>>(d1, Bws, tb1, d2);
    dect2_full<<<chunk * 4, 256, 0, stream>>>(d2, tw2, tb2, outc);
  }

  finalize_loss<<<1, 64, 0, stream>>>(lossacc, out + 4194304);
}

// Round 13
// 1082.105 us; speedup vs baseline: 2.7581x; 1.0858x over previous
//
#include <hip/hip_runtime.h>
#include <math.h>

typedef __attribute__((ext_vector_type(8))) short short8;
typedef __attribute__((ext_vector_type(4))) float f32x4;

__device__ inline unsigned short f2bf(float f) {
  unsigned u = __float_as_uint(f);
  u = (u + 0x7fffu + ((u >> 16) & 1u)) >> 16;
  return (unsigned short)u;
}

// ---------------------------------------------------------------------------
// conv1: 4x4 s=2 p=1 ReLU, CIN=1, 128x128 -> 64x64, 32 ch. Single barrier.
// ---------------------------------------------------------------------------
__global__ __launch_bounds__(256, 3)
void conv1_lds(const float* __restrict__ x, const float* __restrict__ w,
               const float* __restrict__ bias, float* __restrict__ out) {
  int bid = blockIdx.x;
  int cchunk = bid & 1;
  int t4 = (bid >> 1) & 3;
  int n = bid >> 3;
  int co0 = cchunk * 16;
  int y0 = t4 * 16;
  int yi0 = 2 * y0 - 1;

  __shared__ float xs[34 * 128];
  __shared__ float wl[16][16];

  int t = threadIdx.x;
  for (int idx = t; idx < 34 * 128; idx += 256) {
    int gy = yi0 + (idx >> 7);
    int gx = idx & 127;
    bool ok = (unsigned)gy < 128;
    xs[idx] = ok ? x[(size_t)n * 16384 + gy * 128 + gx] : 0.f;
  }
  {
    int cc = t & 15;
    int tap = t >> 4;
    if (t < 256) wl[tap][cc] = w[(size_t)(co0 + cc) * 16 + tap];
  }
  __syncthreads();

  int sx = t & 63;
  int rg = t >> 6;

  float acc[4][16];
#pragma unroll
  for (int j = 0; j < 4; j++)
#pragma unroll
    for (int c = 0; c < 16; c++) acc[j][c] = 0.f;

  int ix0 = 2 * sx - 1;
#pragma unroll
  for (int ky = 0; ky < 4; ky++) {
#pragma unroll
    for (int kx = 0; kx < 4; kx++) {
      int ix = ix0 + kx;
      bool xok = (unsigned)ix < 128;
      float xv[4];
#pragma unroll
      for (int j = 0; j < 4; j++) {
        int lrow = 2 * (4 * rg + j) + ky;
        float v = xs[lrow * 128 + (xok ? ix : 0)];
        xv[j] = xok ? v : 0.f;
      }
      const float* wr = &wl[ky * 4 + kx][0];
#pragma unroll
      for (int c = 0; c < 16; c += 4) {
        float4 wv = *(const float4*)(wr + c);
#pragma unroll
        for (int j = 0; j < 4; j++) {
          acc[j][c + 0] = fmaf(xv[j], wv.x, acc[j][c + 0]);
          acc[j][c + 1] = fmaf(xv[j], wv.y, acc[j][c + 1]);
          acc[j][c + 2] = fmaf(xv[j], wv.z, acc[j][c + 2]);
          acc[j][c + 3] = fmaf(xv[j], wv.w, acc[j][c + 3]);
        }
      }
    }
  }

#pragma unroll
  for (int j = 0; j < 4; j++) {
    int oy = y0 + 4 * rg + j;
    float* op = out + (((size_t)n * 32 + co0) * 64 + oy) * 64 + sx;
#pragma unroll
    for (int c = 0; c < 16; c++) {
      float v = acc[j][c] + bias[co0 + c];
      op[(size_t)c * 4096] = fmaxf(v, 0.f);
    }
  }
}

// ---------------------------------------------------------------------------
// conv2: 4x4 s=2 p=1 ReLU, 64x64 -> 32x32 (proven structure).
// ---------------------------------------------------------------------------
template<int CIN, int COUT, int CCH>
__global__ __launch_bounds__(256, 3)
void conv4x4s2_lds(const float* __restrict__ x, const float* __restrict__ w,
                   const float* __restrict__ bias, float* __restrict__ out) {
  constexpr int NCH = COUT / CCH;
  int bid = blockIdx.x;
  int cchunk = bid % NCH;
  int n = bid / NCH;
  int co0 = cchunk * CCH;

  __shared__ float wl[CIN * 16][CCH];
  __shared__ float xs[4096];
  for (int i = threadIdx.x; i < CIN * 16 * CCH; i += 256) {
    int cc = i % CCH;
    int tap = i / CCH;
    wl[tap][cc] = w[(size_t)(co0 + cc) * (CIN * 16) + tap];
  }

  int t = threadIdx.x;
  int sx = t & 31;
  int sy0 = t >> 5;
  int ix0 = 2 * sx - 1;

  float acc[4][CCH];
#pragma unroll
  for (int j = 0; j < 4; j++)
#pragma unroll
    for (int c = 0; c < CCH; c++) acc[j][c] = 0.f;

  const float* xn = x + (size_t)n * CIN * 4096;

  for (int ci = 0; ci < CIN; ci++) {
    __syncthreads();
#pragma unroll
    for (int k = 0; k < 4; k++)
      *(float4*)(xs + k * 1024 + t * 4) =
          *(const float4*)(xn + (size_t)ci * 4096 + k * 1024 + t * 4);
    __syncthreads();

#pragma unroll
    for (int ky = 0; ky < 4; ky++) {
#pragma unroll
      for (int kx = 0; kx < 4; kx++) {
        int ix = ix0 + kx;
        bool xok = (unsigned)ix < 64;
        float xv[4];
#pragma unroll
        for (int j = 0; j < 4; j++) {
          int iy = 2 * (sy0 + j * 8) - 1 + ky;
          bool ok = xok && ((unsigned)iy < 64);
          float v = xs[ok ? iy * 64 + ix : 0];
          xv[j] = ok ? v : 0.f;
        }
        const float* wr = &wl[ci * 16 + ky * 4 + kx][0];
#pragma unroll
        for (int c = 0; c < CCH; c += 4) {
          float4 wv = *(const float4*)(wr + c);
#pragma unroll
          for (int j = 0; j < 4; j++) {
            acc[j][c + 0] = fmaf(xv[j], wv.x, acc[j][c + 0]);
            acc[j][c + 1] = fmaf(xv[j], wv.y, acc[j][c + 1]);
            acc[j][c + 2] = fmaf(xv[j], wv.z, acc[j][c + 2]);
            acc[j][c + 3] = fmaf(xv[j], wv.w, acc[j][c + 3]);
          }
        }
      }
    }
  }

#pragma unroll
  for (int j = 0; j < 4; j++) {
    int sy = sy0 + j * 8;
    float* op = out + (((size_t)n * COUT + co0) * 32 + sy) * 32 + sx;
#pragma unroll
    for (int c = 0; c < CCH; c++) {
      float v = acc[j][c] + bias[co0 + c];
      v = fmaxf(v, 0.f);
      op[(size_t)c * 1024] = v;
    }
  }
}

// ---------------------------------------------------------------------------
// conv3: 3x3 s=1 p=1 ReLU on 32x32, CIN=64 (ENCODER — must stay fp32-exact,
// feeds z -> argmin). Proven (256,3) no-spill structure.
// ---------------------------------------------------------------------------
template<int CIN, int COUT, int CCH>
__global__ __launch_bounds__(256, 3)
void conv3x3_cg(const float* __restrict__ x, const float* __restrict__ w,
                const float* __restrict__ bias, float* __restrict__ out) {
  constexpr int NCH = COUT / CCH;
  int bid = blockIdx.x;
  int cchunk = bid % NCH;
  int n = bid / NCH;
  int co0 = cchunk * CCH;

  __shared__ float xs[4 * 1024];
  __shared__ float wl[4 * 9][CCH];

  int t = threadIdx.x;
  int sx = t & 31;
  int rg = t >> 5;

  float acc[4][CCH];
#pragma unroll
  for (int j = 0; j < 4; j++)
#pragma unroll
    for (int c = 0; c < CCH; c++) acc[j][c] = 0.f;

  const float* xn = x + (size_t)n * CIN * 1024;

  for (int cg = 0; cg < CIN / 4; cg++) {
    __syncthreads();
#pragma unroll
    for (int k = 0; k < 4; k++)
      *(float4*)(xs + k * 1024 + t * 4) =
          *(const float4*)(xn + (size_t)(cg * 4 + k) * 1024 + t * 4);
    for (int i = t; i < 4 * 9 * CCH; i += 256) {
      int cc = i % CCH;
      int row = i / CCH;
      int c4 = row / 9, kk = row % 9;
      wl[row][cc] = w[(size_t)(co0 + cc) * (CIN * 9) + (cg * 4 + c4) * 9 + kk];
    }
    __syncthreads();

#pragma unroll
    for (int c4 = 0; c4 < 4; c4++) {
      const float* xc = xs + c4 * 1024;
      float xv[6][3];
#pragma unroll
      for (int r = 0; r < 6; r++) {
        int iy = 4 * rg - 1 + r;
        bool yok = (unsigned)iy < 32;
#pragma unroll
        for (int cx = 0; cx < 3; cx++) {
          int ix = sx - 1 + cx;
          bool ok = yok && ((unsigned)ix < 32);
          float v = xc[ok ? iy * 32 + ix : 0];
          xv[r][cx] = ok ? v : 0.f;
        }
      }
#pragma unroll
      for (int ky = 0; ky < 3; ky++) {
#pragma unroll
        for (int kx = 0; kx < 3; kx++) {
          const float* wr = &wl[c4 * 9 + ky * 3 + kx][0];
#pragma unroll
          for (int c = 0; c < CCH; c += 4) {
            float4 wv = *(const float4*)(wr + c);
#pragma unroll
            for (int j = 0; j < 4; j++) {
              float xx = xv[j + ky][kx];
              acc[j][c + 0] = fmaf(xx, wv.x, acc[j][c + 0]);
              acc[j][c + 1] = fmaf(xx, wv.y, acc[j][c + 1]);
              acc[j][c + 2] = fmaf(xx, wv.z, acc[j][c + 2]);
              acc[j][c + 3] = fmaf(xx, wv.w, acc[j][c + 3]);
            }
          }
        }
      }
    }
  }

#pragma unroll
  for (int j = 0; j < 4; j++) {
    int sy = 4 * rg + j;
    float* op = out + (((size_t)n * COUT + co0) * 32 + sy) * 32 + sx;
#pragma unroll
    for (int c = 0; c < CCH; c++) {
      float v = acc[j][c] + bias[co0 + c];
      v = fmaxf(v, 0.f);
      op[(size_t)c * 1024] = v;
    }
  }
}

// ---------------------------------------------------------------------------
// Weight prep for MFMA dect1: tw1 [ci=64][co=32][4][4] fp32 ->
// Bws bf16 [par=4][tap=4][co=32][ci=64].
// ---------------------------------------------------------------------------
__global__ void wprep_dect1(const float* __restrict__ tw1,
                            unsigned short* __restrict__ Bws) {
  int i = blockIdx.x * 256 + threadIdx.x;
  if (i < 32768) {
    int ci = i & 63;
    int co = (i >> 6) & 31;
    int tap = (i >> 11) & 3;
    int par = i >> 13;
    int py = par >> 1, px = par & 1;
    int ky0 = (py + 1) & 1, kx0 = (px + 1) & 1;
    int kyi = tap >> 1, kxi = tap & 1;
    int ky = ky0 + 2 * kyi, kx = kx0 + 2 * kxi;
    Bws[i] = f2bf(tw1[(((size_t)ci * 32 + co) * 4 + ky) * 4 + kx]);
  }
}

// ---------------------------------------------------------------------------
// Weight prep for MFMA dec1: dw1 [co=64][ci=32][3][3] fp32 ->
// Wd1 bf16 [co][tap=9][ci=32]  (row stride 288 shorts = 576B, 16B-aligned).
// ---------------------------------------------------------------------------
__global__ void wprep_dec1(const float* __restrict__ dw1,
                           unsigned short* __restrict__ Wd1) {
  int i = blockIdx.x * 256 + threadIdx.x;
  if (i < 18432) {
    int ci = i & 31;
    int tap = (i >> 5) % 9;
    int co = i / 288;
    Wd1[i] = f2bf(dw1[(size_t)(co * 32 + ci) * 9 + tap]);
  }
}

// ---------------------------------------------------------------------------
// dec1 via MFMA (bf16 in, fp32 acc): 3x3 s=1 p=1 ReLU,
// qz [smp][32ci][32][32] fp32 -> d1 [smp][64co][32][32] fp32.
// GEMM per 8-row strip: D[m=co][n=pos] = sum_{tap,ci} W[co][tap,ci]*X[pos+sh][ci].
// Operand roles: A = weights (m=co), B = acts (n=pos) -> D col = pos ->
// coalesced stores. A-frags (9 taps) loaded once/wave from prepacked Wd1.
// B-frags: ds_read_b128 from bf16 LDS tile [row10][col34][ci32] (ci stride
// 64B -> contiguous lane pattern, conflict-free).
// Block = 256 thr = 4 waves (wave = co-tile). grid = NB * 4 strips.
// ---------------------------------------------------------------------------
__global__ __launch_bounds__(256, 3)
void dec1_mfma(const float* __restrict__ qz,
               const unsigned short* __restrict__ Wd1,
               const float* __restrict__ bias, float* __restrict__ d1) {
  int strip = blockIdx.x & 3;
  int smp = blockIdx.x >> 2;
  int y0 = strip * 8;

  __shared__ __align__(16) unsigned short xt[10 * 34 * 32];

  int t = threadIdx.x;
  // stage rows y0-1..y0+8, cols -1..32, 32 ci (bf16 pairs)
  for (int idx = t; idx < 16 * 10 * 34; idx += 256) {
    int cc = idx % 34;
    int tmp = idx / 34;
    int rr = tmp % 10;
    int pp = tmp / 10;                 // ci pair 0..15
    int gy = y0 - 1 + rr;
    int gx = cc - 1;
    bool ok = ((unsigned)gy < 32) && ((unsigned)gx < 32);
    const float* p = qz + ((size_t)smp * 32 + 2 * pp) * 1024 + gy * 32 + gx;
    float v0 = ok ? p[0] : 0.f;
    float v1 = ok ? p[1024] : 0.f;
    unsigned pk = (unsigned)f2bf(v0) | ((unsigned)f2bf(v1) << 16);
    *(unsigned*)(&xt[(rr * 34 + cc) * 32 + 2 * pp]) = pk;
  }

  int lane = t & 63;
  int wv = t >> 6;                    // co-tile 0..3
  int mlo = lane & 15;
  int khi = lane >> 4;

  // A-frags: weights for co = wv*16+mlo, all 9 taps (global, L2-hot)
  short8 afr[9];
#pragma unroll
  for (int tap = 0; tap < 9; tap++)
    afr[tap] = *(const short8*)(Wd1 + (size_t)(wv * 16 + mlo) * 288 +
                                tap * 32 + khi * 8);
  float bb[4];
#pragma unroll
  for (int r = 0; r < 4; r++) bb[r] = bias[wv * 16 + khi * 4 + r];

  __syncthreads();

  for (int pt = 0; pt < 16; pt++) {
    int rl = pt >> 1;                 // row in strip 0..7
    int chf = pt & 1;                 // col half
    f32x4 acc = {0.f, 0.f, 0.f, 0.f};
#pragma unroll
    for (int tap = 0; tap < 9; tap++) {
      int ky = tap / 3, kx = tap % 3;
      const unsigned short* bp =
          xt + (((rl + ky) * 34) + chf * 16 + mlo + kx) * 32 + khi * 8;
      short8 b = *(const short8*)bp;
      acc = __builtin_amdgcn_mfma_f32_16x16x32_bf16(afr[tap], b, acc, 0, 0, 0);
    }
    int gyo = y0 + rl;
    int gxo = chf * 16 + mlo;
#pragma unroll
    for (int r = 0; r < 4; r++) {
      int co = wv * 16 + khi * 4 + r;
      d1[(((size_t)smp * 64 + co) * 32 + gyo) * 32 + gxo] =
          fmaxf(acc[r] + bb[r], 0.f);
    }
  }
}

// ---------------------------------------------------------------------------
// dect1 via MFMA (proven round-12): tconv k=4 s=2 p=1 ReLU,
// d1 [smp][64ci][32][32] fp32 -> d2 [smp][32co][64][64] fp32.
// ---------------------------------------------------------------------------
__global__ __launch_bounds__(256, 3)
void convt_mfma(const float* __restrict__ d1,
                const unsigned short* __restrict__ Bws,
                const float* __restrict__ bias, float* __restrict__ d2) {
  constexpr int CP = 72;
  int bid = blockIdx.x;
  int rp = bid & 15;
  int smp = bid >> 4;

  __shared__ __align__(16) unsigned short xt[4 * 34 * CP];

  int t = threadIdx.x;

  for (int idx = t; idx < 32 * 4 * 34; idx += 256) {
    int cc = idx % 34;
    int tmp = idx / 34;
    int rr = tmp & 3;
    int pp = tmp >> 2;
    int gy = 2 * rp - 1 + rr;
    int gx = cc - 1;
    bool ok = ((unsigned)gy < 32) && ((unsigned)gx < 32);
    const float* p = d1 + ((size_t)smp * 64 + 2 * pp) * 1024 + gy * 32 + gx;
    float v0 = ok ? p[0] : 0.f;
    float v1 = ok ? p[1024] : 0.f;
    unsigned pk = (unsigned)f2bf(v0) | ((unsigned)f2bf(v1) << 16);
    *(unsigned*)(&xt[(rr * 34 + cc) * CP + 2 * pp]) = pk;
  }
  __syncthreads();

  int lane = t & 63;
  int wv = t >> 6;
  int row2 = wv >> 1;
  int c0 = (wv & 1) * 16;
  int mlo = lane & 15;
  int khi = lane >> 4;

  f32x4 acc[4][2];
#pragma unroll
  for (int par = 0; par < 4; par++)
#pragma unroll
    for (int nt = 0; nt < 2; nt++) {
      f32x4 z = {0.f, 0.f, 0.f, 0.f};
      acc[par][nt] = z;
    }

#pragma unroll
  for (int par = 0; par < 4; par++) {
    int py = par >> 1, px = par & 1;
    int ky0 = (py + 1) & 1, kx0 = (px + 1) & 1;
    int ay = (py + 1 - ky0) >> 1;
    int ax = (px + 1 - kx0) >> 1;
#pragma unroll
    for (int tap = 0; tap < 4; tap++) {
      int kyi = tap >> 1, kxi = tap & 1;
      int rrp = row2 + 1 + (ay - kyi);
      int ccb = c0 + 1 + (ax - kxi);
#pragma unroll
      for (int kc = 0; kc < 2; kc++) {
        const unsigned short* ap =
            xt + ((rrp * 34) + ccb + mlo) * CP + kc * 32 + khi * 8;
        short8 a = *(const short8*)ap;
#pragma unroll
        for (int nt = 0; nt < 2; nt++) {
          const unsigned short* bp =
              Bws + (((size_t)(par * 4 + tap) * 32 + nt * 16 + mlo) * 64) +
              kc * 32 + khi * 8;
          short8 b = *(const short8*)bp;
          acc[par][nt] =
              __builtin_amdgcn_mfma_f32_16x16x32_bf16(a, b, acc[par][nt], 0, 0, 0);
        }
      }
    }
  }

  int sy = 2 * rp + row2;
#pragma unroll
  for (int par = 0; par < 4; par++) {
    int py = par >> 1, px = par & 1;
    int oy = 2 * sy + py;
#pragma unroll
    for (int nt = 0; nt < 2; nt++) {
      int co = nt * 16 + mlo;
      float b = bias[co];
      float* op = d2 + (((size_t)smp * 32 + co) * 64 + oy) * 64;
#pragma unroll
      for (int r = 0; r < 4; r++) {
        int sx = c0 + khi * 4 + r;
        int ox = 2 * sx + px;
        op[ox] = fmaxf(acc[par][nt][r] + b, 0.f);
      }
    }
  }
}

// ---------------------------------------------------------------------------
// dect2: tconv k=4 s=2 p=1, CIN=32, COUT=1, sigmoid; all 4 parities per
// thread. CSTG=8. grid = NB * 4 row-tiles. 64x64 -> 128x128.
// ---------------------------------------------------------------------------
__global__ __launch_bounds__(256, 4)
void dect2_full(const float* __restrict__ x, const float* __restrict__ w,
                const float* __restrict__ bias, float* __restrict__ out) {
  int ptile = blockIdx.x & 3;
  int n = blockIdx.x >> 2;
  int y0 = ptile * 16;

  __shared__ float xs[8][1152];
  int t = threadIdx.x;
  int sx = t & 63;
  int r4 = t >> 6;

  float acc[4][4];
#pragma unroll
  for (int j = 0; j < 4; j++)
#pragma unroll
    for (int p = 0; p < 4; p++) acc[j][p] = 0.f;

  const float* xn = x + (size_t)n * 32 * 4096;

  for (int cg = 0; cg < 4; cg++) {
    __syncthreads();
    for (int idx = t; idx < 8 * 1152; idx += 256) {
      int ch = idx / 1152;
      int rem = idx % 1152;
      int iy = y0 - 1 + rem / 64;
      int ix = rem & 63;
      bool ok = (unsigned)iy < 64;
      xs[ch][rem] = ok ? xn[(size_t)(cg * 8 + ch) * 4096 + iy * 64 + ix] : 0.f;
    }
    __syncthreads();

#pragma unroll
    for (int c4 = 0; c4 < 8; c4++) {
      int ci = cg * 8 + c4;
      const float* xc = &xs[c4][0];
      float xv[6][3];
#pragma unroll
      for (int r = 0; r < 6; r++) {
        int srow = 4 * r4 + r;
#pragma unroll
        for (int cx = 0; cx < 3; cx++) {
          int ix = sx - 1 + cx;
          bool ok = (unsigned)ix < 64;
          float v = xc[ok ? srow * 64 + ix : 0];
          xv[r][cx] = ok ? v : 0.f;
        }
      }
      float w16[16];
#pragma unroll
      for (int q = 0; q < 4; q++) {
        float4 ww = *(const float4*)(w + ci * 16 + 4 * q);
        w16[4 * q + 0] = ww.x; w16[4 * q + 1] = ww.y;
        w16[4 * q + 2] = ww.z; w16[4 * q + 3] = ww.w;
      }
#pragma unroll
      for (int py = 0; py < 2; py++) {
#pragma unroll
        for (int px = 0; px < 2; px++) {
          int par = py * 2 + px;
          int ky0 = (py + 1) & 1, kx0 = (px + 1) & 1;
          int ay = (py + 1 - ky0) >> 1;
          int ax = (px + 1 - kx0) >> 1;
#pragma unroll
          for (int kyi = 0; kyi < 2; kyi++) {
#pragma unroll
            for (int kxi = 0; kxi < 2; kxi++) {
              float wv = w16[(ky0 + 2 * kyi) * 4 + (kx0 + 2 * kxi)];
#pragma unroll
              for (int j = 0; j < 4; j++) {
                float xx = xv[j + ay + 1 - kyi][ax + 1 - kxi];
                acc[j][par] = fmaf(xx, wv, acc[j][par]);
              }
            }
          }
        }
      }
    }
  }

  float b0 = bias[0];
#pragma unroll
  for (int j = 0; j < 4; j++) {
    int iy = y0 + 4 * r4 + j;
#pragma unroll
    for (int py = 0; py < 2; py++) {
      float v0 = acc[j][py * 2 + 0] + b0;
      float v1 = acc[j][py * 2 + 1] + b0;
      float2 o;
      o.x = 1.f / (1.f + expf(-v0));
      o.y = 1.f / (1.f + expf(-v1));
      int oy = 2 * iy + py;
      *(float2*)(out + (size_t)n * 16384 + oy * 128 + 2 * sx) = o;
    }
  }
}

// ---------------------------------------------------------------------------
__global__ void cbn_prep(const float* __restrict__ cb, float* __restrict__ cbn) {
#pragma clang fp contract(off)
  int k = blockIdx.x * 256 + threadIdx.x;
  if (k < 512) {
    float m[32];
#pragma unroll
    for (int d = 0; d < 32; d++) {
      float c = cb[k * 32 + d];
      m[d] = c * c;
    }
    float r[8];
#pragma unroll
    for (int j = 0; j < 8; j++)
      r[j] = ((m[j] + m[8 + j]) + m[16 + j]) + m[24 + j];
    cbn[k] = ((r[0] + r[1]) + (r[2] + r[3])) + ((r[4] + r[5]) + (r[6] + r[7]));
  }
}

// ---------------------------------------------------------------------------
// FUSED conv4 (1x1) + VQ (np-exact arithmetic; proven).
// ---------------------------------------------------------------------------
__global__ __launch_bounds__(256)
void vq_fused(const float* __restrict__ h3, const float* __restrict__ w4,
              const float* __restrict__ b4, const float* __restrict__ cb,
              const float* __restrict__ cbn, float* __restrict__ qz,
              float* __restrict__ loss) {
  __shared__ float wl[64][32];
  int tid = threadIdx.x;
  for (int i = tid; i < 2048; i += 256) {
    int co = i & 31;
    int ci = i >> 5;
    wl[ci][co] = w4[(size_t)co * 64 + ci];
  }
  __syncthreads();

  int n = blockIdx.x >> 2;
  int p = (blockIdx.x & 3) * 256 + tid;
  const float* hn = h3 + (size_t)n * 65536;

  float zv[32];
#pragma unroll
  for (int c = 0; c < 32; c++) zv[c] = 0.f;
  for (int ci = 0; ci < 64; ci++) {
    float xv = hn[(size_t)ci * 1024 + p];
#pragma unroll
    for (int c = 0; c < 32; c += 4) {
      float4 wv = *(const float4*)&wl[ci][c];
      zv[c + 0] = fmaf(xv, wv.x, zv[c + 0]);
      zv[c + 1] = fmaf(xv, wv.y, zv[c + 1]);
      zv[c + 2] = fmaf(xv, wv.z, zv[c + 2]);
      zv[c + 3] = fmaf(xv, wv.w, zv[c + 3]);
    }
  }
#pragma unroll
  for (int c = 0; c < 32; c++) zv[c] = zv[c] + b4[c];

  float zz;
  {
#pragma clang fp contract(off)
    float m[32];
#pragma unroll
    for (int d = 0; d < 32; d++) m[d] = zv[d] * zv[d];
    float r[8];
#pragma unroll
    for (int j = 0; j < 8; j++)
      r[j] = ((m[j] + m[8 + j]) + m[16 + j]) + m[24 + j];
    zz = ((r[0] + r[1]) + (r[2] + r[3])) + ((r[4] + r[5]) + (r[6] + r[7]));
  }

  float best = 3.4e38f;
  int bk = 0;
  for (int k4 = 0; k4 < 512; k4 += 4) {
    float4 cn = *(const float4*)(cbn + k4);
    float da[4];
#pragma unroll
    for (int u = 0; u < 4; u++) da[u] = 0.f;
#pragma unroll
    for (int d = 0; d < 32; d += 4) {
#pragma unroll
      for (int u = 0; u < 4; u++) {
        float4 c = *(const float4*)(cb + (size_t)(k4 + u) * 32 + d);
        float a = da[u];
        a = fmaf(zv[d + 0], c.x, a);
        a = fmaf(zv[d + 1], c.y, a);
        a = fmaf(zv[d + 2], c.z, a);
        a = fmaf(zv[d + 3], c.w, a);
        da[u] = a;
      }
    }
#pragma unroll
    for (int u = 0; u < 4; u++) {
      float cnu = (u == 0) ? cn.x : (u == 1) ? cn.y : (u == 2) ? cn.z : cn.w;
      float s;
      {
#pragma clang fp contract(off)
        s = (zz + cnu) - 2.f * da[u];
      }
      int k = k4 + u;
      if (s < best) { best = s; bk = k; }
    }
  }

  float lsum = 0.f;
  float* qn = qz + (size_t)n * 32768;
#pragma unroll
  for (int d = 0; d < 32; d += 4) {
#pragma clang fp contract(off)
    float4 q = *(const float4*)(cb + (size_t)bk * 32 + d);
    float e;
    e = q.x - zv[d + 0]; lsum = fmaf(e, e, lsum);
    e = q.y - zv[d + 1]; lsum = fmaf(e, e, lsum);
    e = q.z - zv[d + 2]; lsum = fmaf(e, e, lsum);
    e = q.w - zv[d + 3]; lsum = fmaf(e, e, lsum);
    qn[(size_t)(d + 0) * 1024 + p] = zv[d + 0] + (q.x - zv[d + 0]);
    qn[(size_t)(d + 1) * 1024 + p] = zv[d + 1] + (q.y - zv[d + 1]);
    qn[(size_t)(d + 2) * 1024 + p] = zv[d + 2] + (q.z - zv[d + 2]);
    qn[(size_t)(d + 3) * 1024 + p] = zv[d + 3] + (q.w - zv[d + 3]);
  }

#pragma unroll
  for (int off = 32; off; off >>= 1) lsum += __shfl_down(lsum, off, 64);
  if ((tid & 63) == 0) atomicAdd(loss, lsum);
}

__global__ void finalize_loss(const float* __restrict__ loss, float* __restrict__ out) {
  if (threadIdx.x == 0) {
    float m = loss[0] / 8388608.f;
    out[0] = m + 0.26f * m;
  }
}

// ---------------------------------------------------------------------------
// Workspace (floats): A = chunk*131072, B = chunk*65536, cbn 512, loss 1,
// pad 3, Bws 32768 shorts (16384 fl), Wd1 18432 shorts (9216 fl).
// ---------------------------------------------------------------------------
extern "C" void kernel_launch(void* const* d_in, const int* in_sizes, int n_in,
                              void* d_out, int out_size, void* d_ws, size_t ws_size,
                              hipStream_t stream) {
  (void)in_sizes; (void)n_in; (void)out_size;
  const float* x   = (const float*)d_in[0];
  const float* ew1 = (const float*)d_in[1];
  const float* eb1 = (const float*)d_in[2];
  const float* ew2 = (const float*)d_in[3];
  const float* eb2 = (const float*)d_in[4];
  const float* ew3 = (const float*)d_in[5];
  const float* eb3 = (const float*)d_in[6];
  const float* ew4 = (const float*)d_in[7];
  const float* eb4 = (const float*)d_in[8];
  const float* cb  = (const float*)d_in[9];
  const float* dw1 = (const float*)d_in[10];
  const float* db1 = (const float*)d_in[11];
  const float* tw1 = (const float*)d_in[12];
  const float* tb1 = (const float*)d_in[13];
  const float* tw2 = (const float*)d_in[14];
  const float* tb2 = (const float*)d_in[15];
  float* out = (float*)d_out;

  auto need = [](size_t c) -> size_t {
    return (c * 196608 + 516 + 16384 + 9216) * 4;
  };
  int nchunks = 4;
  if (ws_size >= need(256)) nchunks = 1;
  else if (ws_size >= need(128)) nchunks = 2;
  int chunk = 256 / nchunks;

  float* ws = (float*)d_ws;
  float* A = ws;
  float* B = A + (size_t)chunk * 131072;
  float* cbn = B + (size_t)chunk * 65536;
  float* lossacc = cbn + 512;
  unsigned short* Bws = (unsigned short*)(cbn + 516);          // 16B-aligned
  unsigned short* Wd1 = (unsigned short*)(cbn + 516 + 16384);  // 16B-aligned

  float* h1 = A;
  float* h2 = B;
  float* h3 = A;
  float* qz = A + (size_t)chunk * 98304;
  float* d1 = B;
  float* d2 = A;

  cbn_prep<<<2, 256, 0, stream>>>(cb, cbn);
  wprep_dect1<<<128, 256, 0, stream>>>(tw1, Bws);
  wprep_dec1<<<72, 256, 0, stream>>>(dw1, Wd1);
  (void)hipMemsetAsync(lossacc, 0, 4, stream);

  for (int c = 0; c < nchunks; c++) {
    const float* xc = x + (size_t)c * chunk * 128 * 128;
    float* outc = out + (size_t)c * chunk * 128 * 128;

    conv1_lds<<<chunk * 8, 256, 0, stream>>>(xc, ew1, eb1, h1);
    conv4x4s2_lds<32, 64, 16>
        <<<chunk * 4, 256, 0, stream>>>(h1, ew2, eb2, h2);
    conv3x3_cg<64, 64, 16>
        <<<chunk * 4, 256, 0, stream>>>(h2, ew3, eb3, h3);

    vq_fused<<<chunk * 4, 256, 0, stream>>>(h3, ew4, eb4, cb, cbn, qz, lossacc);

    dec1_mfma<<<chunk * 4, 256, 0, stream>>>(qz, Wd1, db1, d1);
    convt_mfma<<<chunk * 16, 256, 0, stream>>>(d1, Bws, tb1, d2);
    dect2_full<<<chunk * 4, 256, 0, stream>>>(d2, tw2, tb2, outc);
  }

  finalize_loss<<<1, 64, 0, stream>>>(lossacc, out + 4194304);
}